// Round 6
// baseline (365.428 us; speedup 1.0000x reference)
//
#include <hip/hip_runtime.h>

typedef unsigned short u16;
typedef unsigned int u32;
typedef __attribute__((ext_vector_type(8))) short short8;
typedef __attribute__((ext_vector_type(4))) float f32x4;

constexpr int B = 2, L = 16, C = 64, S = 64, W = 128, R = 32, MH = 32;
constexpr int BL = B * L;        // 32
constexpr int SW = S * W;        // 8192
constexpr int CR = C * R;        // 2048
constexpr int F2 = C * R * 2;    // 4096

__device__ __forceinline__ float us2f(u16 h) { return __uint_as_float(((u32)h) << 16); }
__device__ __forceinline__ float bf_lo(u32 u) { return __uint_as_float(u << 16); }
__device__ __forceinline__ float bf_hi(u32 u) { return __uint_as_float(u & 0xffff0000u); }
__device__ __forceinline__ u16 f2bu(float f) {
  u32 u = __float_as_uint(f);
  u32 r = (u + 0x7fffu + ((u >> 16) & 1u)) >> 16;
  return (u16)r;
}
__device__ __forceinline__ u32 pack2(float lo, float hi) {
  return (u32)f2bu(lo) | ((u32)f2bu(hi) << 16);
}

// ---------------- prep: lam, gamma ----------------
__global__ void k_prep(const float* __restrict__ nu_log, const float* __restrict__ th_log,
                       const float* __restrict__ dnu, const float* __restrict__ dth,
                       float* __restrict__ lamr, float* __restrict__ lami,
                       float* __restrict__ gam) {
  int i = blockIdx.x * 256 + threadIdx.x;
  if (i >= CR) return;
  float nu = expf(nu_log[i] + dnu[i]);
  float th = expf(th_log[i] + dth[i]);
  float mag = expf(-nu);
  lamr[i] = mag * cosf(th);
  lami[i] = mag * sinf(th);
  gam[i] = sqrtf(fmaxf(1.0f - mag * mag, 1e-6f));
}

// ---------------- prep: effective conv kernel (fuse folded), MFMA-A-swizzled bf16 ----------------
__global__ void k_keff(const float* __restrict__ fuse_k, const float* __restrict__ fuse_b,
                       const float* __restrict__ convr_k, const float* __restrict__ convr_b,
                       const float* __restrict__ convi_k, const float* __restrict__ convi_b,
                       u16* __restrict__ keff_bf, float* __restrict__ biaseff) {
  int i = blockIdx.x * 256 + threadIdx.x;
  if (i < C * 2 * C * 9) {
    int o = i / (2 * C * 9);
    int rem = i - o * (2 * C * 9);
    int cin2 = rem / 9;
    int seg = rem - cin2 * 9;
    const float* ck = (cin2 < C) ? convr_k : convi_k;
    int cin = cin2 & (C - 1);
    int fbase = o * 2 * C + ((cin2 < C) ? 0 : C);
    float acc = 0.f;
    for (int m = 0; m < C; ++m)
      acc += fuse_k[fbase + m] * ck[(m * C + cin) * 9 + seg];
    int kstep = cin2 >> 5;
    int kk = cin2 & 31;
    int lane = (o & 15) | ((kk >> 3) << 4);
    int j = kk & 7;
    int m_tile = o >> 4;
    keff_bf[((((seg * 4 + kstep) * 4 + m_tile) * 64 + lane) << 3) + j] = f2bu(acc);
  } else if (i < C * 2 * C * 9 + C) {
    int o = i - C * 2 * C * 9;
    float acc = fuse_b[o];
    for (int m = 0; m < C; ++m) {
      acc += fuse_k[o * 2 * C + m] * convr_b[m];
      acc += fuse_k[o * 2 * C + C + m] * convi_b[m];
    }
    biaseff[o] = acc;
  }
}

// ---------------- prep: projection matrix real-stacked bf16 [m=128][k=128] ----------------
__global__ void k_apack(const float* __restrict__ pWr, const float* __restrict__ pWi,
                        u16* __restrict__ aproj) {
  int i = blockIdx.x * 256 + threadIdx.x;
  if (i >= 128 * 128) return;
  int m = i >> 7, k = i & 127;
  int c = k >> 1, im = k & 1;
  int o = m & 63;
  float v;
  if (m < 64) v = im ? -pWi[o * 64 + c] : pWr[o * 64 + c];
  else        v = im ?  pWr[o * 64 + c] : pWi[o * 64 + c];
  aproj[i] = f2bu(v);
}

// ---------------- MLP -> forcing ----------------
// grid = BL * 16: w2 tile (32x256) staged in LDS; hidden layer recomputed per
// block. (Old 32-block version was latency-serialized at 1.4% occupancy, 96us.)
__global__ __launch_bounds__(256) void k_mlp(
    const float* __restrict__ ctx, const float* __restrict__ w1, const float* __restrict__ b1,
    const float* __restrict__ w2, const float* __restrict__ b2, const float* __restrict__ fscale,
    float* __restrict__ forcing) {
  int bl = blockIdx.x >> 4;
  int kt = blockIdx.x & 15;
  int k0 = kt * 256;
  __shared__ float cv[C];
  __shared__ float hid[MH];
  __shared__ float lw2[MH * 256];
  int t = threadIdx.x;
  if (t < C) cv[t] = ctx[bl * C + t];
  for (int i = t; i < MH * 64; i += 256) {
    int j = i >> 6, q = i & 63;
    ((float4*)lw2)[i] = ((const float4*)(w2 + (size_t)j * F2 + k0))[q];
  }
  __syncthreads();
  if (t < MH) {
    float a = b1[t];
    for (int c2 = 0; c2 < C; ++c2) a += cv[c2] * w1[c2 * MH + t];
    hid[t] = tanhf(a);
  }
  __syncthreads();
  float scale = fscale[0];
  float a = b2[k0 + t];
#pragma unroll
  for (int j = 0; j < MH; ++j) a += hid[j] * lw2[j * 256 + t];
  forcing[(size_t)bl * F2 + k0 + t] = scale * a;
}

// ---------------- MFMA encode (+ ctx fused): per (b,l,c) block ----------------
__global__ __launch_bounds__(256) void k_enc(
    const float* __restrict__ x,
    const float* __restrict__ Vr, const float* __restrict__ Vi,
    const float* __restrict__ Ur, const float* __restrict__ Ui,
    float* __restrict__ ctx, float* __restrict__ u) {
  int blc = blockIdx.x;
  int c = blc & (C - 1);
  __shared__ __align__(16) char smem[17408 * 2 + 16384 + 64];
  u16* xt = (u16*)smem;                    // [64][136] A = x[s][w] bf16
  u16* bt = (u16*)(smem + 17408);          // [64][136] B rows
  float* uldr = (float*)(smem + 34816);    // [2048] U real [s*32+r]
  float* uldi = uldr + 2048;               // [2048] U imag
  float* y1  = (float*)smem;               // alias xt: [64][65] f32
  float* part = (float*)(smem + 17408);    // alias bt: [8][64]
  float* red = (float*)(smem + 17408 * 2 + 16384);  // [16]
  int t = threadIdx.x;
  int lane = t & 63, wv = t >> 6;
  float sm = 0.f;
  {
    const float4* xp = (const float4*)(x + (size_t)blc * SW);
    for (int i = t; i < SW / 4; i += 256) {
      float4 v = xp[i];
      sm += v.x + v.y + v.z + v.w;
      int idx = i * 4, s = idx >> 7, w = idx & 127;
      u32* d = (u32*)&xt[s * 136 + w];
      d[0] = pack2(v.x, v.y);
      d[1] = pack2(v.z, v.w);
    }
  }
#pragma unroll
  for (int o = 32; o > 0; o >>= 1) sm += __shfl_down(sm, o, 64);
  if (lane == 0) red[wv] = sm;
  {
    const float* vrp = Vr + (size_t)c * 4096;
    const float* vip = Vi + (size_t)c * 4096;
    for (int i = t; i < 4096; i += 256) {
      int w = i >> 5, r = i & 31;
      bt[r * 136 + w]        = f2bu(vrp[i]);
      bt[(32 + r) * 136 + w] = f2bu(-vip[i]);
    }
  }
  {
    const float* urp = Ur + (size_t)c * 2048;
    const float* uip = Ui + (size_t)c * 2048;
    for (int i = t; i < 2048; i += 256) { uldr[i] = urp[i]; uldi[i] = uip[i]; }
  }
  __syncthreads();
  if (t == 0) ctx[blc] = (red[0] + red[1] + red[2] + red[3]) * (1.f / SW);
  int quad = lane >> 4, l15 = lane & 15;
  f32x4 zf = {0.f, 0.f, 0.f, 0.f};
  f32x4 acc[4] = {zf, zf, zf, zf};
#pragma unroll
  for (int ks = 0; ks < 4; ++ks) {
    int kofs = ks * 32 + quad * 8;
    short8 bf = *(const short8*)&bt[(wv * 16 + l15) * 136 + kofs];
#pragma unroll
    for (int mt = 0; mt < 4; ++mt) {
      short8 af = *(const short8*)&xt[(mt * 16 + l15) * 136 + kofs];
      acc[mt] = __builtin_amdgcn_mfma_f32_16x16x32_bf16(af, bf, acc[mt], 0, 0, 0);
    }
  }
  __syncthreads();
#pragma unroll
  for (int mt = 0; mt < 4; ++mt)
#pragma unroll
    for (int reg = 0; reg < 4; ++reg)
      y1[(mt * 16 + quad * 4 + reg) * 65 + wv * 16 + l15] = acc[mt][reg];
  __syncthreads();
  {
    int r = t & 31, sg = t >> 5;
    float pr = 0.f, pi = 0.f;
#pragma unroll
    for (int k = 0; k < 8; ++k) {
      int s = sg * 8 + k;
      float yr = y1[s * 65 + r], yi = y1[s * 65 + 32 + r];
      float ur = uldr[s * 32 + r], ui = uldi[s * 32 + r];
      pr += ur * yr + ui * yi;
      pi += ur * yi - ui * yr;
    }
    part[sg * 64 + r * 2]     = pr;
    part[sg * 64 + r * 2 + 1] = pi;
  }
  __syncthreads();
  if (t < 32) {
    float pr = 0.f, pi = 0.f;
#pragma unroll
    for (int sg = 0; sg < 8; ++sg) {
      pr += part[sg * 64 + t * 2];
      pi += part[sg * 64 + t * 2 + 1];
    }
    u[((size_t)blc * R + t) * 2]     = pr;
    u[((size_t)blc * R + t) * 2 + 1] = pi;
  }
}

// ---------------- diagonal scan over L (applies gamma*(1+forcing)) ----------------
__global__ void k_scan(const float* __restrict__ lamr, const float* __restrict__ lami,
                       const float* __restrict__ gam, const float* __restrict__ forcing,
                       const float* __restrict__ u, float* __restrict__ h) {
  int i = blockIdx.x * 256 + threadIdx.x;
  if (i >= B * CR) return;
  int b = i / CR;
  int cr = i - b * CR;
  float lr = lamr[cr], li = lami[cr], g = gam[cr];
  float hr = 0.f, hi = 0.f;
  for (int l = 0; l < L; ++l) {
    size_t off = ((size_t)(b * L + l) * CR + cr) * 2;
    float ur0 = u[off], ui0 = u[off + 1];
    float fr = forcing[off], fi = forcing[off + 1];
    float ofr = 1.f + fr;
    float ur = g * (ur0 * ofr - ui0 * fi);
    float ui = g * (ur0 * fi + ui0 * ofr);
    float nr = lr * hr - li * hi + ur;
    float ni = lr * hi + li * hr + ui;
    hr = nr; hi = ni;
    h[off] = hr; h[off + 1] = hi;
  }
}

// ---------------- MFMA decode: per (bl,c), Y[s,w] = (h*U)[s,:] x V[w,:]^T ----------------
__global__ __launch_bounds__(256) void k_decode(
    const float* __restrict__ h,
    const float* __restrict__ Ur, const float* __restrict__ Ui,
    const float* __restrict__ Vr, const float* __restrict__ Vi,
    u32* __restrict__ y_cm32, int bl_base) {
  int bid = blockIdx.x;
  int c = bid & 63;
  int blh = bid >> 6;
  int bl = bl_base + blh;
  __shared__ __align__(16) u16 ldA[64 * 72];
  __shared__ __align__(16) u16 ldBr[128 * 72];
  __shared__ __align__(16) u16 ldBi[128 * 72];
  int t = threadIdx.x;
  {
    const float* hp = h + ((size_t)(bl * C + c) * R) * 2;
    const float* urp = Ur + (size_t)c * (S * R);
    const float* uip = Ui + (size_t)c * (S * R);
    for (int p = t; p < S * R; p += 256) {
      int s = p >> 5, r = p & 31;
      float hr = hp[r * 2], hi = hp[r * 2 + 1];
      float ur = urp[p], ui = uip[p];
      ldA[s * 72 + r]      = f2bu(hr * ur - hi * ui);
      ldA[s * 72 + 32 + r] = f2bu(hr * ui + hi * ur);
    }
  }
  {
    const float* vrp = Vr + (size_t)c * (W * R);
    const float* vip = Vi + (size_t)c * (W * R);
    for (int p = t; p < W * R; p += 256) {
      int w = p >> 5, r = p & 31;
      float vr = vrp[p], vi = vip[p];
      ldBr[w * 72 + r]      = f2bu(vr);
      ldBr[w * 72 + 32 + r] = f2bu(-vi);
      ldBi[w * 72 + r]      = f2bu(vi);
      ldBi[w * 72 + 32 + r] = f2bu(vr);
    }
  }
  __syncthreads();
  int lane = t & 63, q = t >> 6;
  int quad = lane >> 4, l15 = lane & 15;
  f32x4 zf = {0.f, 0.f, 0.f, 0.f};
  f32x4 accr[4][2], acci[4][2];
#pragma unroll
  for (int mt = 0; mt < 4; ++mt)
#pragma unroll
    for (int nt = 0; nt < 2; ++nt) { accr[mt][nt] = zf; acci[mt][nt] = zf; }
#pragma unroll
  for (int ks = 0; ks < 2; ++ks) {
    int kofs = ks * 32 + quad * 8;
    short8 af[4];
#pragma unroll
    for (int mt = 0; mt < 4; ++mt)
      af[mt] = *(const short8*)&ldA[(mt * 16 + l15) * 72 + kofs];
#pragma unroll
    for (int nt = 0; nt < 2; ++nt) {
      int wrow = q * 32 + nt * 16 + l15;
      short8 br = *(const short8*)&ldBr[wrow * 72 + kofs];
      short8 bi = *(const short8*)&ldBi[wrow * 72 + kofs];
#pragma unroll
      for (int mt = 0; mt < 4; ++mt) {
        accr[mt][nt] = __builtin_amdgcn_mfma_f32_16x16x32_bf16(af[mt], br, accr[mt][nt], 0, 0, 0);
        acci[mt][nt] = __builtin_amdgcn_mfma_f32_16x16x32_bf16(af[mt], bi, acci[mt][nt], 0, 0, 0);
      }
    }
  }
  u32* dst = y_cm32 + ((size_t)(blh * 64 + c) << 13);
#pragma unroll
  for (int mt = 0; mt < 4; ++mt) {
#pragma unroll
    for (int nt = 0; nt < 2; ++nt) {
      int w = q * 32 + nt * 16 + l15;
#pragma unroll
      for (int reg = 0; reg < 4; ++reg) {
        int s = mt * 16 + quad * 4 + reg;
        dst[s * 128 + w] = pack2(accr[mt][nt][reg], acci[mt][nt][reg]);
      }
    }
  }
}

// ---------------- MFMA projection GEMM: M=128 ch_out, K=128, N=512/block -> NHWC ----------------
__global__ __launch_bounds__(256) void k_proj(
    const u32* __restrict__ y_cm32, const u16* __restrict__ aproj,
    const float* __restrict__ pbr, const float* __restrict__ pbi,
    u16* __restrict__ ynhwc, int bl_base) {
  int bid = blockIdx.x;
  int ntile = bid & 15;
  int blh = bid >> 4;
  int bl = bl_base + blh;
  __shared__ __align__(16) u16 lda[128 * 136];
  __shared__ __align__(16) u32 ldb[128 * 68];
  __shared__ float ldbias[128];
  int t = threadIdx.x;
  for (int i = t; i < 128 * 16; i += 256) {
    int m = i >> 4, qq = i & 15;
    ((uint4*)&lda[m * 136])[qq] = ((const uint4*)&aproj[m * 128])[qq];
  }
  if (t < 128) ldbias[t] = t < 64 ? pbr[t] : pbi[t - 64];

  int lane = t & 63, wv = t >> 6;
  int quad = lane >> 4, l15 = lane & 15;
  int cidx = t & 63, seg = t >> 6;
  f32x4 zf = {0.f, 0.f, 0.f, 0.f};

  for (int chunk = 0; chunk < 4; ++chunk) {
    int n0 = ntile * 512 + chunk * 128;
    __syncthreads();
    {
      const uint4* src = (const uint4*)(y_cm32 + (((size_t)(blh * 64 + cidx)) << 13) + n0 + seg * 32);
      u32 tmp[32];
#pragma unroll
      for (int qq = 0; qq < 8; ++qq) {
        uint4 v = src[qq];
        tmp[qq * 4] = v.x; tmp[qq * 4 + 1] = v.y; tmp[qq * 4 + 2] = v.z; tmp[qq * 4 + 3] = v.w;
      }
#pragma unroll
      for (int j = 0; j < 32; ++j)
        ldb[(seg * 32 + j) * 68 + cidx] = tmp[j];
    }
    __syncthreads();
    f32x4 acc[8][2];
#pragma unroll
    for (int mt = 0; mt < 8; ++mt) { acc[mt][0] = zf; acc[mt][1] = zf; }
    const u16* ldb16 = (const u16*)ldb;
#pragma unroll
    for (int ks = 0; ks < 4; ++ks) {
      int kofs = ks * 32 + quad * 8;
      short8 af[8];
#pragma unroll
      for (int mt = 0; mt < 8; ++mt)
        af[mt] = *(const short8*)&lda[(mt * 16 + l15) * 136 + kofs];
#pragma unroll
      for (int nt = 0; nt < 2; ++nt) {
        int nrow = wv * 32 + nt * 16 + l15;
        short8 bf = *(const short8*)&ldb16[nrow * 136 + kofs];
#pragma unroll
        for (int mt = 0; mt < 8; ++mt)
          acc[mt][nt] = __builtin_amdgcn_mfma_f32_16x16x32_bf16(af[mt], bf, acc[mt][nt], 0, 0, 0);
      }
    }
#pragma unroll
    for (int nt = 0; nt < 2; ++nt) {
      int n = n0 + wv * 32 + nt * 16 + l15;
      u16* drow = ynhwc + (((size_t)bl * SW + n) << 7);
#pragma unroll
      for (int mt = 0; mt < 8; ++mt) {
        int ch = mt * 16 + quad * 4;
        u32 lo = pack2(acc[mt][nt][0] + ldbias[ch],     acc[mt][nt][1] + ldbias[ch + 1]);
        u32 hi = pack2(acc[mt][nt][2] + ldbias[ch + 2], acc[mt][nt][3] + ldbias[ch + 3]);
        u32* dp = (u32*)(drow + ch);
        dp[0] = lo; dp[1] = hi;
      }
    }
  }
}

// ---------------- MFMA implicit-GEMM conv ----------------
// R6: wave-per-row, shared B. Evidence R2/R3/R4/R5 all ~64.5us regardless of
// tile: LDS-read pipe is the dominant term (73k of 154k cyc/CU) and HALF of
// those reads were duplicated across the old mp-split wave pairs (b0/b1
// depended only on np). Now: block = 4 output s-rows x 32 w; wave wv owns row
// s0+wv and computes ALL 4 m-tiles -> every B ds_read unique. Total
// ds_read_b128 halves (1.18M -> 0.59M), conflicts should halve (~2.4M),
// MFMA:ds_read = 4:1. ch-split staging: win[6][34][72] = 28.7 KB; VGPR cap
// 128 (launch_bounds(256,4)) -> 4 blk/CU, 16 waves (the proven-good point).
// A-dbuf at (seg,ks2)-step granularity: abuf[2][4] (prefetch next step's 4
// m-frags while 8 MFMAs run).
__global__ __launch_bounds__(256, 4) void k_conv(
    const u16* __restrict__ ynhwc, const u16* __restrict__ keff_bf,
    const float* __restrict__ biaseff, u16* __restrict__ fused) {
  int bid = blockIdx.x;
  int wt = bid & 3;          // 4 w-tiles of 32
  int st = (bid >> 2) & 15;  // 16 s-tiles of 4 rows
  int bl = bid >> 6;
  int s0 = st * 4;
  int w0 = wt * 32;
  __shared__ __align__(16) u16 win[6][34][72];   // [s-row][w-col][64ch + 8 pad]
  int t = threadIdx.x;
  int c_lo = (w0 == 0) ? 1 : 0;
  int c_hi = (w0 == 96) ? 33 : 34;
  uint4 z4 = make_uint4(0u, 0u, 0u, 0u);

  int lane = t & 63;
  int wv = t >> 6;          // wave owns output row s0+wv
  int quad = lane >> 4, l15 = lane & 15;
  int chq = quad * 8;

  f32x4 zf = {0.f, 0.f, 0.f, 0.f};
  f32x4 acc[4][2];  // [mt][nt]
#pragma unroll
  for (int mt = 0; mt < 4; ++mt) { acc[mt][0] = zf; acc[mt][1] = zf; }
  const short8* ap = (const short8*)keff_bf;
  short8 abuf[2][4];  // [parity][mt]

#pragma unroll
  for (int p = 0; p < 2; ++p) {
    if (p) __syncthreads();   // pass-0 LDS reads complete before restage
    // stage ch-half p: 6 s-rows x 34 cols x 64 ch
    for (int rr = 0; rr < 6; ++rr) {
      int rs = s0 - 1 + rr;
      if (rs < 0 || rs >= S) {
        for (int i = t; i < 34 * 8; i += 256) {
          int col = i >> 3, q = i & 7;
          ((uint4*)&win[rr][col][0])[q] = z4;
        }
      } else {
        if (w0 == 0 && t < 8) ((uint4*)&win[rr][0][0])[t] = z4;
        if (w0 == 96 && t < 8) ((uint4*)&win[rr][33][0])[t] = z4;
        const uint4* src = (const uint4*)(ynhwc +
            (((size_t)bl * S + rs) * W + (w0 - 1 + c_lo)) * 128 + p * 64);
        int n4 = (c_hi - c_lo) * 8;
        for (int i = t; i < n4; i += 256) {
          int col = i >> 3, q = i & 7;
          ((uint4*)&win[rr][c_lo + col][0])[q] = src[col * 16 + q];
        }
      }
    }
    __syncthreads();

    // prefetch step 0 (seg=0, ks2=0) A-fragments for this pass
#pragma unroll
    for (int mt = 0; mt < 4; ++mt)
      abuf[0][mt] = ap[((0 * 4 + p * 2 + 0) * 4 + mt) * 64 + lane];

    // 18 steps: step k -> seg = k>>1, ks2 = k&1
#pragma unroll
    for (int k = 0; k < 18; ++k) {
      const int cur = k & 1;
      const int nxt = cur ^ 1;
      if (k < 17) {
        const int k1 = k + 1;
        const int seg1 = k1 >> 1, ks21 = k1 & 1;
        const int ks1 = p * 2 + ks21;
#pragma unroll
        for (int mt = 0; mt < 4; ++mt)
          abuf[nxt][mt] = ap[((seg1 * 4 + ks1) * 4 + mt) * 64 + lane];
      }
      const int seg = k >> 1;
      const int ks2 = k & 1;
      const int dr = seg / 3;
      const int dc = seg - dr * 3;
      const u16* bbase = &win[wv + dr][l15 + dc][chq + ks2 * 32];
      short8 b0 = *(const short8*)bbase;
      short8 b1 = *(const short8*)(bbase + 16 * 72);
#pragma unroll
      for (int mt = 0; mt < 4; ++mt) {
        acc[mt][0] = __builtin_amdgcn_mfma_f32_16x16x32_bf16(abuf[cur][mt], b0, acc[mt][0], 0, 0, 0);
        acc[mt][1] = __builtin_amdgcn_mfma_f32_16x16x32_bf16(abuf[cur][mt], b1, acc[mt][1], 0, 0, 0);
      }
    }
  }

  int s_out = s0 + wv;
#pragma unroll
  for (int mt = 0; mt < 4; ++mt) {
#pragma unroll
    for (int reg = 0; reg < 4; ++reg) {
      int o = mt * 16 + quad * 4 + reg;
      float bias = biaseff[o];
      size_t rowoff = ((size_t)(bl * C + o) * S + s_out) * W;
      fused[rowoff + w0 + l15]      = f2bu(acc[mt][0][reg] + bias);
      fused[rowoff + w0 + 16 + l15] = f2bu(acc[mt][1][reg] + bias);
    }
  }
}

// ---------------- layernorm (stats in-kernel) + residual ----------------
__global__ __launch_bounds__(256) void k_ln(
    const u16* __restrict__ fused,
    const float* __restrict__ ln_g, const float* __restrict__ ln_b,
    const float* __restrict__ x, float* __restrict__ out) {
  int blc = blockIdx.x;
  __shared__ u16 fs[SW];
  __shared__ float red[12];
  int t = threadIdx.x;
  const uint4* fp = (const uint4*)(fused + (size_t)blc * SW);
  float sm = 0.f, sq = 0.f;
  for (int i = t; i < SW / 8; i += 256) {
    uint4 v = fp[i];
    ((uint4*)fs)[i] = v;
    float f0 = bf_lo(v.x), f1 = bf_hi(v.x), f2 = bf_lo(v.y), f3 = bf_hi(v.y);
    float f4 = bf_lo(v.z), f5 = bf_hi(v.z), f6 = bf_lo(v.w), f7 = bf_hi(v.w);
    sm += f0 + f1 + f2 + f3 + f4 + f5 + f6 + f7;
    sq += f0 * f0 + f1 * f1 + f2 * f2 + f3 * f3 + f4 * f4 + f5 * f5 + f6 * f6 + f7 * f7;
  }
#pragma unroll
  for (int off = 32; off > 0; off >>= 1) {
    sm += __shfl_down(sm, off, 64);
    sq += __shfl_down(sq, off, 64);
  }
  int lane = t & 63, wid = t >> 6;
  if (lane == 0) { red[wid * 2] = sm; red[wid * 2 + 1] = sq; }
  __syncthreads();
  if (t == 0) {
    float S1 = red[0] + red[2] + red[4] + red[6];
    float S2 = red[1] + red[3] + red[5] + red[7];
    float mu = S1 * (1.f / SW);
    float var = S2 * (1.f / SW) - mu * mu;
    red[8] = mu;
    red[9] = rsqrtf(var + 1e-5f);
  }
  __syncthreads();
  float mu = red[8], rstd = red[9];
  const float* xp = x + (size_t)blc * SW;
  float* op = out + (size_t)blc * SW;
  for (int i = t; i < SW; i += 256)
    op[i] = (us2f(fs[i]) - mu) * rstd * ln_g[i] + ln_b[i] + xp[i];
}

extern "C" void kernel_launch(void* const* d_in, const int* in_sizes, int n_in,
                              void* d_out, int out_size, void* d_ws, size_t ws_size,
                              hipStream_t stream) {
  (void)in_sizes; (void)n_in; (void)out_size; (void)ws_size;
  const float* x       = (const float*)d_in[0];
  const float* nu_log  = (const float*)d_in[1];
  const float* th_log  = (const float*)d_in[2];
  const float* dnu     = (const float*)d_in[3];
  const float* dth     = (const float*)d_in[4];
  const float* w1      = (const float*)d_in[5];
  const float* b1      = (const float*)d_in[6];
  const float* w2      = (const float*)d_in[7];
  const float* b2      = (const float*)d_in[8];
  const float* fscale  = (const float*)d_in[9];
  const float* Ur      = (const float*)d_in[10];
  const float* Ui      = (const float*)d_in[11];
  const float* Vr      = (const float*)d_in[12];
  const float* Vi      = (const float*)d_in[13];
  const float* pWr     = (const float*)d_in[14];
  const float* pWi     = (const float*)d_in[15];
  const float* pbr     = (const float*)d_in[16];
  const float* pbi     = (const float*)d_in[17];
  const float* convr_k = (const float*)d_in[18];
  const float* convr_b = (const float*)d_in[19];
  const float* convi_k = (const float*)d_in[20];
  const float* convi_b = (const float*)d_in[21];
  const float* fuse_k  = (const float*)d_in[22];
  const float* fuse_b  = (const float*)d_in[23];
  const float* ln_g    = (const float*)d_in[24];
  const float* ln_b    = (const float*)d_in[25];
  float* out = (float*)d_out;

  char* ws = (char*)d_ws;
  float* lamr    = (float*)ws;
  float* lami    = lamr + 2048;
  float* gam     = lami + 2048;
  float* biaseff = gam + 2048;        // 64
  float* ctx     = biaseff + 64;      // 2048
  float* forcing = ctx + 2048;        // 131072
  float* ubuf    = forcing + 131072;  // 131072
  float* hbuf    = ubuf + 131072;     // 131072
  u16* keff_bf   = (u16*)(hbuf + 131072);       // 73728 u16 (144 KB)
  u16* aproj     = keff_bf + 73728;             // 16384 u16 (32 KB)
  size_t off = ((size_t)((char*)(aproj + 16384) - ws) + 255) & ~(size_t)255;
  u32* y_cm32    = (u32*)(ws + off);            // 32 MB (half-batch)
  u16* fused     = (u16*)y_cm32;                // ALIAS: live only after y_cm32 dead
  u16* ynhwc     = (u16*)(ws + off + (size_t)32 * 1024 * 1024);  // 64 MB
  // total ws ~ 97.8 MB

  k_prep<<<8, 256, 0, stream>>>(nu_log, th_log, dnu, dth, lamr, lami, gam);
  k_keff<<<289, 256, 0, stream>>>(fuse_k, fuse_b, convr_k, convr_b, convi_k, convi_b,
                                  keff_bf, biaseff);
  k_apack<<<64, 256, 0, stream>>>(pWr, pWi, aproj);
  k_enc<<<BL * C, 256, 0, stream>>>(x, Vr, Vi, Ur, Ui, ctx, ubuf);
  k_mlp<<<BL * 16, 256, 0, stream>>>(ctx, w1, b1, w2, b2, fscale, forcing);
  k_scan<<<16, 256, 0, stream>>>(lamr, lami, gam, forcing, ubuf, hbuf);
  k_decode<<<1024, 256, 0, stream>>>(hbuf, Ur, Ui, Vr, Vi, y_cm32, 0);
  k_proj<<<256, 256, 0, stream>>>(y_cm32, aproj, pbr, pbi, ynhwc, 0);
  k_decode<<<1024, 256, 0, stream>>>(hbuf, Ur, Ui, Vr, Vi, y_cm32, 16);
  k_proj<<<256, 256, 0, stream>>>(y_cm32, aproj, pbr, pbi, ynhwc, 16);
  k_conv<<<2048, 256, 0, stream>>>(ynhwc, keff_bf, biaseff, fused);
  k_ln<<<BL * C, 256, 0, stream>>>(fused, ln_g, ln_b, x, out);
}

// Round 7
// 349.930 us; speedup vs baseline: 1.0443x; 1.0443x over previous
//
#include <hip/hip_runtime.h>

typedef unsigned short u16;
typedef unsigned int u32;
typedef __attribute__((ext_vector_type(8))) short short8;
typedef __attribute__((ext_vector_type(4))) float f32x4;

constexpr int B = 2, L = 16, C = 64, S = 64, W = 128, R = 32, MH = 32;
constexpr int BL = B * L;        // 32
constexpr int SW = S * W;        // 8192
constexpr int CR = C * R;        // 2048
constexpr int F2 = C * R * 2;    // 4096

__device__ __forceinline__ float us2f(u16 h) { return __uint_as_float(((u32)h) << 16); }
__device__ __forceinline__ float bf_lo(u32 u) { return __uint_as_float(u << 16); }
__device__ __forceinline__ float bf_hi(u32 u) { return __uint_as_float(u & 0xffff0000u); }
__device__ __forceinline__ u16 f2bu(float f) {
  u32 u = __float_as_uint(f);
  u32 r = (u + 0x7fffu + ((u >> 16) & 1u)) >> 16;
  return (u16)r;
}
__device__ __forceinline__ u32 pack2(float lo, float hi) {
  return (u32)f2bu(lo) | ((u32)f2bu(hi) << 16);
}

// ---------------- prep: lam, gamma ----------------
__global__ void k_prep(const float* __restrict__ nu_log, const float* __restrict__ th_log,
                       const float* __restrict__ dnu, const float* __restrict__ dth,
                       float* __restrict__ lamr, float* __restrict__ lami,
                       float* __restrict__ gam) {
  int i = blockIdx.x * 256 + threadIdx.x;
  if (i >= CR) return;
  float nu = expf(nu_log[i] + dnu[i]);
  float th = expf(th_log[i] + dth[i]);
  float mag = expf(-nu);
  lamr[i] = mag * cosf(th);
  lami[i] = mag * sinf(th);
  gam[i] = sqrtf(fmaxf(1.0f - mag * mag, 1e-6f));
}

// ---------------- prep: effective conv kernel (fuse folded), MFMA-A-swizzled bf16 ----------------
__global__ void k_keff(const float* __restrict__ fuse_k, const float* __restrict__ fuse_b,
                       const float* __restrict__ convr_k, const float* __restrict__ convr_b,
                       const float* __restrict__ convi_k, const float* __restrict__ convi_b,
                       u16* __restrict__ keff_bf, float* __restrict__ biaseff) {
  int i = blockIdx.x * 256 + threadIdx.x;
  if (i < C * 2 * C * 9) {
    int o = i / (2 * C * 9);
    int rem = i - o * (2 * C * 9);
    int cin2 = rem / 9;
    int seg = rem - cin2 * 9;
    const float* ck = (cin2 < C) ? convr_k : convi_k;
    int cin = cin2 & (C - 1);
    int fbase = o * 2 * C + ((cin2 < C) ? 0 : C);
    float acc = 0.f;
    for (int m = 0; m < C; ++m)
      acc += fuse_k[fbase + m] * ck[(m * C + cin) * 9 + seg];
    int kstep = cin2 >> 5;
    int kk = cin2 & 31;
    int lane = (o & 15) | ((kk >> 3) << 4);
    int j = kk & 7;
    int m_tile = o >> 4;
    keff_bf[((((seg * 4 + kstep) * 4 + m_tile) * 64 + lane) << 3) + j] = f2bu(acc);
  } else if (i < C * 2 * C * 9 + C) {
    int o = i - C * 2 * C * 9;
    float acc = fuse_b[o];
    for (int m = 0; m < C; ++m) {
      acc += fuse_k[o * 2 * C + m] * convr_b[m];
      acc += fuse_k[o * 2 * C + C + m] * convi_b[m];
    }
    biaseff[o] = acc;
  }
}

// ---------------- prep: projection matrix real-stacked bf16 [m=128][k=128] ----------------
__global__ void k_apack(const float* __restrict__ pWr, const float* __restrict__ pWi,
                        u16* __restrict__ aproj) {
  int i = blockIdx.x * 256 + threadIdx.x;
  if (i >= 128 * 128) return;
  int m = i >> 7, k = i & 127;
  int c = k >> 1, im = k & 1;
  int o = m & 63;
  float v;
  if (m < 64) v = im ? -pWi[o * 64 + c] : pWr[o * 64 + c];
  else        v = im ?  pWr[o * 64 + c] : pWi[o * 64 + c];
  aproj[i] = f2bu(v);
}

// ---------------- MLP -> forcing ----------------
// grid = BL * 16: w2 tile (32x256) staged in LDS; hidden layer recomputed per
// block. (Old 32-block version was latency-serialized at 1.4% occupancy, 96us.)
__global__ __launch_bounds__(256) void k_mlp(
    const float* __restrict__ ctx, const float* __restrict__ w1, const float* __restrict__ b1,
    const float* __restrict__ w2, const float* __restrict__ b2, const float* __restrict__ fscale,
    float* __restrict__ forcing) {
  int bl = blockIdx.x >> 4;
  int kt = blockIdx.x & 15;
  int k0 = kt * 256;
  __shared__ float cv[C];
  __shared__ float hid[MH];
  __shared__ float lw2[MH * 256];
  int t = threadIdx.x;
  if (t < C) cv[t] = ctx[bl * C + t];
  for (int i = t; i < MH * 64; i += 256) {
    int j = i >> 6, q = i & 63;
    ((float4*)lw2)[i] = ((const float4*)(w2 + (size_t)j * F2 + k0))[q];
  }
  __syncthreads();
  if (t < MH) {
    float a = b1[t];
    for (int c2 = 0; c2 < C; ++c2) a += cv[c2] * w1[c2 * MH + t];
    hid[t] = tanhf(a);
  }
  __syncthreads();
  float scale = fscale[0];
  float a = b2[k0 + t];
#pragma unroll
  for (int j = 0; j < MH; ++j) a += hid[j] * lw2[j * 256 + t];
  forcing[(size_t)bl * F2 + k0 + t] = scale * a;
}

// ---------------- MFMA encode (+ ctx fused): per (b,l,c) block ----------------
__global__ __launch_bounds__(256) void k_enc(
    const float* __restrict__ x,
    const float* __restrict__ Vr, const float* __restrict__ Vi,
    const float* __restrict__ Ur, const float* __restrict__ Ui,
    float* __restrict__ ctx, float* __restrict__ u) {
  int blc = blockIdx.x;
  int c = blc & (C - 1);
  __shared__ __align__(16) char smem[17408 * 2 + 16384 + 64];
  u16* xt = (u16*)smem;                    // [64][136] A = x[s][w] bf16
  u16* bt = (u16*)(smem + 17408);          // [64][136] B rows
  float* uldr = (float*)(smem + 34816);    // [2048] U real [s*32+r]
  float* uldi = uldr + 2048;               // [2048] U imag
  float* y1  = (float*)smem;               // alias xt: [64][65] f32
  float* part = (float*)(smem + 17408);    // alias bt: [8][64]
  float* red = (float*)(smem + 17408 * 2 + 16384);  // [16]
  int t = threadIdx.x;
  int lane = t & 63, wv = t >> 6;
  float sm = 0.f;
  {
    const float4* xp = (const float4*)(x + (size_t)blc * SW);
    for (int i = t; i < SW / 4; i += 256) {
      float4 v = xp[i];
      sm += v.x + v.y + v.z + v.w;
      int idx = i * 4, s = idx >> 7, w = idx & 127;
      u32* d = (u32*)&xt[s * 136 + w];
      d[0] = pack2(v.x, v.y);
      d[1] = pack2(v.z, v.w);
    }
  }
#pragma unroll
  for (int o = 32; o > 0; o >>= 1) sm += __shfl_down(sm, o, 64);
  if (lane == 0) red[wv] = sm;
  {
    const float* vrp = Vr + (size_t)c * 4096;
    const float* vip = Vi + (size_t)c * 4096;
    for (int i = t; i < 4096; i += 256) {
      int w = i >> 5, r = i & 31;
      bt[r * 136 + w]        = f2bu(vrp[i]);
      bt[(32 + r) * 136 + w] = f2bu(-vip[i]);
    }
  }
  {
    const float* urp = Ur + (size_t)c * 2048;
    const float* uip = Ui + (size_t)c * 2048;
    for (int i = t; i < 2048; i += 256) { uldr[i] = urp[i]; uldi[i] = uip[i]; }
  }
  __syncthreads();
  if (t == 0) ctx[blc] = (red[0] + red[1] + red[2] + red[3]) * (1.f / SW);
  int quad = lane >> 4, l15 = lane & 15;
  f32x4 zf = {0.f, 0.f, 0.f, 0.f};
  f32x4 acc[4] = {zf, zf, zf, zf};
#pragma unroll
  for (int ks = 0; ks < 4; ++ks) {
    int kofs = ks * 32 + quad * 8;
    short8 bf = *(const short8*)&bt[(wv * 16 + l15) * 136 + kofs];
#pragma unroll
    for (int mt = 0; mt < 4; ++mt) {
      short8 af = *(const short8*)&xt[(mt * 16 + l15) * 136 + kofs];
      acc[mt] = __builtin_amdgcn_mfma_f32_16x16x32_bf16(af, bf, acc[mt], 0, 0, 0);
    }
  }
  __syncthreads();
#pragma unroll
  for (int mt = 0; mt < 4; ++mt)
#pragma unroll
    for (int reg = 0; reg < 4; ++reg)
      y1[(mt * 16 + quad * 4 + reg) * 65 + wv * 16 + l15] = acc[mt][reg];
  __syncthreads();
  {
    int r = t & 31, sg = t >> 5;
    float pr = 0.f, pi = 0.f;
#pragma unroll
    for (int k = 0; k < 8; ++k) {
      int s = sg * 8 + k;
      float yr = y1[s * 65 + r], yi = y1[s * 65 + 32 + r];
      float ur = uldr[s * 32 + r], ui = uldi[s * 32 + r];
      pr += ur * yr + ui * yi;
      pi += ur * yi - ui * yr;
    }
    part[sg * 64 + r * 2]     = pr;
    part[sg * 64 + r * 2 + 1] = pi;
  }
  __syncthreads();
  if (t < 32) {
    float pr = 0.f, pi = 0.f;
#pragma unroll
    for (int sg = 0; sg < 8; ++sg) {
      pr += part[sg * 64 + t * 2];
      pi += part[sg * 64 + t * 2 + 1];
    }
    u[((size_t)blc * R + t) * 2]     = pr;
    u[((size_t)blc * R + t) * 2 + 1] = pi;
  }
}

// ---------------- diagonal scan over L (applies gamma*(1+forcing)) ----------------
__global__ void k_scan(const float* __restrict__ lamr, const float* __restrict__ lami,
                       const float* __restrict__ gam, const float* __restrict__ forcing,
                       const float* __restrict__ u, float* __restrict__ h) {
  int i = blockIdx.x * 256 + threadIdx.x;
  if (i >= B * CR) return;
  int b = i / CR;
  int cr = i - b * CR;
  float lr = lamr[cr], li = lami[cr], g = gam[cr];
  float hr = 0.f, hi = 0.f;
  for (int l = 0; l < L; ++l) {
    size_t off = ((size_t)(b * L + l) * CR + cr) * 2;
    float ur0 = u[off], ui0 = u[off + 1];
    float fr = forcing[off], fi = forcing[off + 1];
    float ofr = 1.f + fr;
    float ur = g * (ur0 * ofr - ui0 * fi);
    float ui = g * (ur0 * fi + ui0 * ofr);
    float nr = lr * hr - li * hi + ur;
    float ni = lr * hi + li * hr + ui;
    hr = nr; hi = ni;
    h[off] = hr; h[off + 1] = hi;
  }
}

// ---------------- MFMA decode: per (bl,c), Y[s,w] = (h*U)[s,:] x V[w,:]^T ----------------
__global__ __launch_bounds__(256) void k_decode(
    const float* __restrict__ h,
    const float* __restrict__ Ur, const float* __restrict__ Ui,
    const float* __restrict__ Vr, const float* __restrict__ Vi,
    u32* __restrict__ y_cm32, int bl_base) {
  int bid = blockIdx.x;
  int c = bid & 63;
  int blh = bid >> 6;
  int bl = bl_base + blh;
  __shared__ __align__(16) u16 ldA[64 * 72];
  __shared__ __align__(16) u16 ldBr[128 * 72];
  __shared__ __align__(16) u16 ldBi[128 * 72];
  int t = threadIdx.x;
  {
    const float* hp = h + ((size_t)(bl * C + c) * R) * 2;
    const float* urp = Ur + (size_t)c * (S * R);
    const float* uip = Ui + (size_t)c * (S * R);
    for (int p = t; p < S * R; p += 256) {
      int s = p >> 5, r = p & 31;
      float hr = hp[r * 2], hi = hp[r * 2 + 1];
      float ur = urp[p], ui = uip[p];
      ldA[s * 72 + r]      = f2bu(hr * ur - hi * ui);
      ldA[s * 72 + 32 + r] = f2bu(hr * ui + hi * ur);
    }
  }
  {
    const float* vrp = Vr + (size_t)c * (W * R);
    const float* vip = Vi + (size_t)c * (W * R);
    for (int p = t; p < W * R; p += 256) {
      int w = p >> 5, r = p & 31;
      float vr = vrp[p], vi = vip[p];
      ldBr[w * 72 + r]      = f2bu(vr);
      ldBr[w * 72 + 32 + r] = f2bu(-vi);
      ldBi[w * 72 + r]      = f2bu(vi);
      ldBi[w * 72 + 32 + r] = f2bu(vr);
    }
  }
  __syncthreads();
  int lane = t & 63, q = t >> 6;
  int quad = lane >> 4, l15 = lane & 15;
  f32x4 zf = {0.f, 0.f, 0.f, 0.f};
  f32x4 accr[4][2], acci[4][2];
#pragma unroll
  for (int mt = 0; mt < 4; ++mt)
#pragma unroll
    for (int nt = 0; nt < 2; ++nt) { accr[mt][nt] = zf; acci[mt][nt] = zf; }
#pragma unroll
  for (int ks = 0; ks < 2; ++ks) {
    int kofs = ks * 32 + quad * 8;
    short8 af[4];
#pragma unroll
    for (int mt = 0; mt < 4; ++mt)
      af[mt] = *(const short8*)&ldA[(mt * 16 + l15) * 72 + kofs];
#pragma unroll
    for (int nt = 0; nt < 2; ++nt) {
      int wrow = q * 32 + nt * 16 + l15;
      short8 br = *(const short8*)&ldBr[wrow * 72 + kofs];
      short8 bi = *(const short8*)&ldBi[wrow * 72 + kofs];
#pragma unroll
      for (int mt = 0; mt < 4; ++mt) {
        accr[mt][nt] = __builtin_amdgcn_mfma_f32_16x16x32_bf16(af[mt], br, accr[mt][nt], 0, 0, 0);
        acci[mt][nt] = __builtin_amdgcn_mfma_f32_16x16x32_bf16(af[mt], bi, acci[mt][nt], 0, 0, 0);
      }
    }
  }
  u32* dst = y_cm32 + ((size_t)(blh * 64 + c) << 13);
#pragma unroll
  for (int mt = 0; mt < 4; ++mt) {
#pragma unroll
    for (int nt = 0; nt < 2; ++nt) {
      int w = q * 32 + nt * 16 + l15;
#pragma unroll
      for (int reg = 0; reg < 4; ++reg) {
        int s = mt * 16 + quad * 4 + reg;
        dst[s * 128 + w] = pack2(accr[mt][nt][reg], acci[mt][nt][reg]);
      }
    }
  }
}

// ---------------- MFMA projection GEMM: M=128 ch_out, K=128, N=512/block -> NHWC ----------------
__global__ __launch_bounds__(256) void k_proj(
    const u32* __restrict__ y_cm32, const u16* __restrict__ aproj,
    const float* __restrict__ pbr, const float* __restrict__ pbi,
    u16* __restrict__ ynhwc, int bl_base) {
  int bid = blockIdx.x;
  int ntile = bid & 15;
  int blh = bid >> 4;
  int bl = bl_base + blh;
  __shared__ __align__(16) u16 lda[128 * 136];
  __shared__ __align__(16) u32 ldb[128 * 68];
  __shared__ float ldbias[128];
  int t = threadIdx.x;
  for (int i = t; i < 128 * 16; i += 256) {
    int m = i >> 4, qq = i & 15;
    ((uint4*)&lda[m * 136])[qq] = ((const uint4*)&aproj[m * 128])[qq];
  }
  if (t < 128) ldbias[t] = t < 64 ? pbr[t] : pbi[t - 64];

  int lane = t & 63, wv = t >> 6;
  int quad = lane >> 4, l15 = lane & 15;
  int cidx = t & 63, seg = t >> 6;
  f32x4 zf = {0.f, 0.f, 0.f, 0.f};

  for (int chunk = 0; chunk < 4; ++chunk) {
    int n0 = ntile * 512 + chunk * 128;
    __syncthreads();
    {
      const uint4* src = (const uint4*)(y_cm32 + (((size_t)(blh * 64 + cidx)) << 13) + n0 + seg * 32);
      u32 tmp[32];
#pragma unroll
      for (int qq = 0; qq < 8; ++qq) {
        uint4 v = src[qq];
        tmp[qq * 4] = v.x; tmp[qq * 4 + 1] = v.y; tmp[qq * 4 + 2] = v.z; tmp[qq * 4 + 3] = v.w;
      }
#pragma unroll
      for (int j = 0; j < 32; ++j)
        ldb[(seg * 32 + j) * 68 + cidx] = tmp[j];
    }
    __syncthreads();
    f32x4 acc[8][2];
#pragma unroll
    for (int mt = 0; mt < 8; ++mt) { acc[mt][0] = zf; acc[mt][1] = zf; }
    const u16* ldb16 = (const u16*)ldb;
#pragma unroll
    for (int ks = 0; ks < 4; ++ks) {
      int kofs = ks * 32 + quad * 8;
      short8 af[8];
#pragma unroll
      for (int mt = 0; mt < 8; ++mt)
        af[mt] = *(const short8*)&lda[(mt * 16 + l15) * 136 + kofs];
#pragma unroll
      for (int nt = 0; nt < 2; ++nt) {
        int nrow = wv * 32 + nt * 16 + l15;
        short8 bf = *(const short8*)&ldb16[nrow * 136 + kofs];
#pragma unroll
        for (int mt = 0; mt < 8; ++mt)
          acc[mt][nt] = __builtin_amdgcn_mfma_f32_16x16x32_bf16(af[mt], bf, acc[mt][nt], 0, 0, 0);
      }
    }
#pragma unroll
    for (int nt = 0; nt < 2; ++nt) {
      int n = n0 + wv * 32 + nt * 16 + l15;
      u16* drow = ynhwc + (((size_t)bl * SW + n) << 7);
#pragma unroll
      for (int mt = 0; mt < 8; ++mt) {
        int ch = mt * 16 + quad * 4;
        u32 lo = pack2(acc[mt][nt][0] + ldbias[ch],     acc[mt][nt][1] + ldbias[ch + 1]);
        u32 hi = pack2(acc[mt][nt][2] + ldbias[ch + 2], acc[mt][nt][3] + ldbias[ch + 3]);
        u32* dp = (u32*)(drow + ch);
        dp[0] = lo; dp[1] = hi;
      }
    }
  }
}

// ---------------- MFMA implicit-GEMM conv ----------------
// R7: REVERT to R5 (best measured: 64.4-64.9us, reproduced twice).
// Exploration ledger for this kernel family (do not re-try):
//   R1 JIT A-loads, w32x2row, 4blk/CU:           74.0us
//   R2 + A reg-dbuf:                             64.4us  <- tied best
//   R3 4-row tile, 2blk/CU (A-L2 halved):        67.9us  (occupancy loss)
//   R4 ch-split, 8blk/CU, VGPR=32, no dbuf:      81.8us  (ILP destroyed)
//   R5 w64 tile, ch-split, 4blk/CU, dbuf:        64.9us  <- tied best
//   R6 wave-per-row shared-B (ds_reads halved):  76.2us  (A-stream doubled)
// Conclusion: latency-structure floor ~64.5us; no pipe >50%; A-L2 traffic,
// LDS read count, occupancy, and conflicts all individually NOT binding.
__global__ __launch_bounds__(256, 4) void k_conv(
    const u16* __restrict__ ynhwc, const u16* __restrict__ keff_bf,
    const float* __restrict__ biaseff, u16* __restrict__ fused) {
  int bid = blockIdx.x;
  int wt = bid & 1;
  int st = (bid >> 1) & 31;
  int bl = bid >> 6;
  int s0 = st * 2;
  int w0 = wt * 64;
  __shared__ __align__(16) u16 win[4][66][72];   // [s-row][w-col][64ch + 8 pad]
  int t = threadIdx.x;
  // valid col range [c_lo, c_hi); wt=0: col0 = w=-1 (zero); wt=1: col65 = w=128 (zero)
  int c_lo = (wt == 0) ? 1 : 0;
  int c_hi = (wt == 0) ? 66 : 65;
  uint4 z4 = make_uint4(0u, 0u, 0u, 0u);

  int lane = t & 63;
  int wv = t >> 6;
  int mp = wv & 1;          // m-tile pair {2mp, 2mp+1}
  int np = wv >> 1;         // output s-row
  int quad = lane >> 4, l15 = lane & 15;
  int chq = quad * 8;

  f32x4 zf = {0.f, 0.f, 0.f, 0.f};
  f32x4 acc[2][4];  // [mi][nt]
#pragma unroll
  for (int mi = 0; mi < 2; ++mi)
#pragma unroll
    for (int nt = 0; nt < 4; ++nt) acc[mi][nt] = zf;
  const short8* ap = (const short8*)keff_bf;
  short8 abuf[2][2][2];  // [parity][mi][ks2]

#pragma unroll
  for (int p = 0; p < 2; ++p) {
    if (p) __syncthreads();   // pass-0 LDS reads complete before restage
    // stage ch-half p: 8 uint4 (64 ch) per (row, col)
    for (int rr = 0; rr < 4; ++rr) {
      int rs = s0 - 1 + rr;
      if (rs < 0 || rs >= S) {
        for (int i = t; i < 66 * 8; i += 256) {
          int col = i >> 3, q = i & 7;
          ((uint4*)&win[rr][col][0])[q] = z4;
        }
      } else {
        if (wt == 0 && t < 8) ((uint4*)&win[rr][0][0])[t] = z4;
        if (wt == 1 && t < 8) ((uint4*)&win[rr][65][0])[t] = z4;
        const uint4* src = (const uint4*)(ynhwc +
            (((size_t)bl * S + rs) * W + (w0 - 1 + c_lo)) * 128 + p * 64);
        int n4 = (c_hi - c_lo) * 8;   // 65*8 = 520
        for (int i = t; i < n4; i += 256) {
          int col = i >> 3, q = i & 7;
          ((uint4*)&win[rr][c_lo + col][0])[q] = src[col * 16 + q];
        }
      }
    }
    __syncthreads();

    // prefetch seg 0 A-fragments for this pass
#pragma unroll
    for (int ks2 = 0; ks2 < 2; ++ks2) {
      const int ks = p * 2 + ks2;
      abuf[0][0][ks2] = ap[((0 * 4 + ks) * 4 + 2 * mp) * 64 + lane];
      abuf[0][1][ks2] = ap[((0 * 4 + ks) * 4 + 2 * mp + 1) * 64 + lane];
    }

#pragma unroll
    for (int seg = 0; seg < 9; ++seg) {
      const int cur = seg & 1;
      const int nxt = cur ^ 1;
      if (seg < 8) {
#pragma unroll
        for (int ks2 = 0; ks2 < 2; ++ks2) {
          const int ks = p * 2 + ks2;
          abuf[nxt][0][ks2] = ap[(((seg + 1) * 4 + ks) * 4 + 2 * mp) * 64 + lane];
          abuf[nxt][1][ks2] = ap[(((seg + 1) * 4 + ks) * 4 + 2 * mp + 1) * 64 + lane];
        }
      }
      const int dr = seg / 3;
      const int dc = seg - dr * 3;
      const u16* rowbase = &win[np + dr][0][0];
#pragma unroll
      for (int ks2 = 0; ks2 < 2; ++ks2) {
#pragma unroll
        for (int nt = 0; nt < 4; ++nt) {
          short8 b = *(const short8*)(rowbase + (nt * 16 + l15 + dc) * 72 + chq + ks2 * 32);
          acc[0][nt] = __builtin_amdgcn_mfma_f32_16x16x32_bf16(abuf[cur][0][ks2], b, acc[0][nt], 0, 0, 0);
          acc[1][nt] = __builtin_amdgcn_mfma_f32_16x16x32_bf16(abuf[cur][1][ks2], b, acc[1][nt], 0, 0, 0);
        }
      }
    }
  }

  int s_out = s0 + np;
#pragma unroll
  for (int mi = 0; mi < 2; ++mi) {
#pragma unroll
    for (int reg = 0; reg < 4; ++reg) {
      int o = (2 * mp + mi) * 16 + quad * 4 + reg;
      float bias = biaseff[o];
      size_t rowoff = ((size_t)(bl * C + o) * S + s_out) * W;
#pragma unroll
      for (int nt = 0; nt < 4; ++nt)
        fused[rowoff + w0 + nt * 16 + l15] = f2bu(acc[mi][nt][reg] + bias);
    }
  }
}

// ---------------- layernorm (stats in-kernel) + residual ----------------
// R7: normalize loop vectorized (float4 x/g/b/out, uint2 fused-from-LDS):
// 32 scalar iters x 3 streams -> 8 iters at 16B/lane (G13).
__global__ __launch_bounds__(256) void k_ln(
    const u16* __restrict__ fused,
    const float* __restrict__ ln_g, const float* __restrict__ ln_b,
    const float* __restrict__ x, float* __restrict__ out) {
  int blc = blockIdx.x;
  __shared__ u16 fs[SW];
  __shared__ float red[12];
  int t = threadIdx.x;
  const uint4* fp = (const uint4*)(fused + (size_t)blc * SW);
  float sm = 0.f, sq = 0.f;
  for (int i = t; i < SW / 8; i += 256) {
    uint4 v = fp[i];
    ((uint4*)fs)[i] = v;
    float f0 = bf_lo(v.x), f1 = bf_hi(v.x), f2 = bf_lo(v.y), f3 = bf_hi(v.y);
    float f4 = bf_lo(v.z), f5 = bf_hi(v.z), f6 = bf_lo(v.w), f7 = bf_hi(v.w);
    sm += f0 + f1 + f2 + f3 + f4 + f5 + f6 + f7;
    sq += f0 * f0 + f1 * f1 + f2 * f2 + f3 * f3 + f4 * f4 + f5 * f5 + f6 * f6 + f7 * f7;
  }
#pragma unroll
  for (int off = 32; off > 0; off >>= 1) {
    sm += __shfl_down(sm, off, 64);
    sq += __shfl_down(sq, off, 64);
  }
  int lane = t & 63, wid = t >> 6;
  if (lane == 0) { red[wid * 2] = sm; red[wid * 2 + 1] = sq; }
  __syncthreads();
  if (t == 0) {
    float S1 = red[0] + red[2] + red[4] + red[6];
    float S2 = red[1] + red[3] + red[5] + red[7];
    float mu = S1 * (1.f / SW);
    float var = S2 * (1.f / SW) - mu * mu;
    red[8] = mu;
    red[9] = rsqrtf(var + 1e-5f);
  }
  __syncthreads();
  float mu = red[8], rstd = red[9];
  const float4* xp4 = (const float4*)(x + (size_t)blc * SW);
  float4* op4 = (float4*)(out + (size_t)blc * SW);
  const float4* g4 = (const float4*)ln_g;
  const float4* b4 = (const float4*)ln_b;
  const uint2* fs2 = (const uint2*)fs;
  for (int i = t; i < SW / 4; i += 256) {
    uint2 fv = fs2[i];
    float4 xv = xp4[i];
    float4 gv = g4[i];
    float4 bv = b4[i];
    float4 o;
    o.x = (bf_lo(fv.x) - mu) * rstd * gv.x + bv.x + xv.x;
    o.y = (bf_hi(fv.x) - mu) * rstd * gv.y + bv.y + xv.y;
    o.z = (bf_lo(fv.y) - mu) * rstd * gv.z + bv.z + xv.z;
    o.w = (bf_hi(fv.y) - mu) * rstd * gv.w + bv.w + xv.w;
    op4[i] = o;
  }
}

extern "C" void kernel_launch(void* const* d_in, const int* in_sizes, int n_in,
                              void* d_out, int out_size, void* d_ws, size_t ws_size,
                              hipStream_t stream) {
  (void)in_sizes; (void)n_in; (void)out_size; (void)ws_size;
  const float* x       = (const float*)d_in[0];
  const float* nu_log  = (const float*)d_in[1];
  const float* th_log  = (const float*)d_in[2];
  const float* dnu     = (const float*)d_in[3];
  const float* dth     = (const float*)d_in[4];
  const float* w1      = (const float*)d_in[5];
  const float* b1      = (const float*)d_in[6];
  const float* w2      = (const float*)d_in[7];
  const float* b2      = (const float*)d_in[8];
  const float* fscale  = (const float*)d_in[9];
  const float* Ur      = (const float*)d_in[10];
  const float* Ui      = (const float*)d_in[11];
  const float* Vr      = (const float*)d_in[12];
  const float* Vi      = (const float*)d_in[13];
  const float* pWr     = (const float*)d_in[14];
  const float* pWi     = (const float*)d_in[15];
  const float* pbr     = (const float*)d_in[16];
  const float* pbi     = (const float*)d_in[17];
  const float* convr_k = (const float*)d_in[18];
  const float* convr_b = (const float*)d_in[19];
  const float* convi_k = (const float*)d_in[20];
  const float* convi_b = (const float*)d_in[21];
  const float* fuse_k  = (const float*)d_in[22];
  const float* fuse_b  = (const float*)d_in[23];
  const float* ln_g    = (const float*)d_in[24];
  const float* ln_b    = (const float*)d_in[25];
  float* out = (float*)d_out;

  char* ws = (char*)d_ws;
  float* lamr    = (float*)ws;
  float* lami    = lamr + 2048;
  float* gam     = lami + 2048;
  float* biaseff = gam + 2048;        // 64
  float* ctx     = biaseff + 64;      // 2048
  float* forcing = ctx + 2048;        // 131072
  float* ubuf    = forcing + 131072;  // 131072
  float* hbuf    = ubuf + 131072;     // 131072
  u16* keff_bf   = (u16*)(hbuf + 131072);       // 73728 u16 (144 KB)
  u16* aproj     = keff_bf + 73728;             // 16384 u16 (32 KB)
  size_t off = ((size_t)((char*)(aproj + 16384) - ws) + 255) & ~(size_t)255;
  u32* y_cm32    = (u32*)(ws + off);            // 32 MB (half-batch)
  u16* fused     = (u16*)y_cm32;                // ALIAS: live only after y_cm32 dead
  u16* ynhwc     = (u16*)(ws + off + (size_t)32 * 1024 * 1024);  // 64 MB
  // total ws ~ 97.8 MB

  k_prep<<<8, 256, 0, stream>>>(nu_log, th_log, dnu, dth, lamr, lami, gam);
  k_keff<<<289, 256, 0, stream>>>(fuse_k, fuse_b, convr_k, convr_b, convi_k, convi_b,
                                  keff_bf, biaseff);
  k_apack<<<64, 256, 0, stream>>>(pWr, pWi, aproj);
  k_enc<<<BL * C, 256, 0, stream>>>(x, Vr, Vi, Ur, Ui, ctx, ubuf);
  k_mlp<<<BL * 16, 256, 0, stream>>>(ctx, w1, b1, w2, b2, fscale, forcing);
  k_scan<<<16, 256, 0, stream>>>(lamr, lami, gam, forcing, ubuf, hbuf);
  k_decode<<<1024, 256, 0, stream>>>(hbuf, Ur, Ui, Vr, Vi, y_cm32, 0);
  k_proj<<<256, 256, 0, stream>>>(y_cm32, aproj, pbr, pbi, ynhwc, 0);
  k_decode<<<1024, 256, 0, stream>>>(hbuf, Ur, Ui, Vr, Vi, y_cm32, 16);
  k_proj<<<256, 256, 0, stream>>>(y_cm32, aproj, pbr, pbi, ynhwc, 16);
  k_conv<<<2048, 256, 0, stream>>>(ynhwc, keff_bf, biaseff, fused);
  k_ln<<<BL * C, 256, 0, stream>>>(fused, ln_g, ln_b, x, out);
}

// Round 8
// 343.951 us; speedup vs baseline: 1.0624x; 1.0174x over previous
//
#include <hip/hip_runtime.h>

typedef unsigned short u16;
typedef unsigned int u32;
typedef __attribute__((ext_vector_type(8))) short short8;
typedef __attribute__((ext_vector_type(4))) float f32x4;
typedef __attribute__((ext_vector_type(16))) float f32x16;

constexpr int B = 2, L = 16, C = 64, S = 64, W = 128, R = 32, MH = 32;
constexpr int BL = B * L;        // 32
constexpr int SW = S * W;        // 8192
constexpr int CR = C * R;        // 2048
constexpr int F2 = C * R * 2;    // 4096

__device__ __forceinline__ float us2f(u16 h) { return __uint_as_float(((u32)h) << 16); }
__device__ __forceinline__ float bf_lo(u32 u) { return __uint_as_float(u << 16); }
__device__ __forceinline__ float bf_hi(u32 u) { return __uint_as_float(u & 0xffff0000u); }
__device__ __forceinline__ u16 f2bu(float f) {
  u32 u = __float_as_uint(f);
  u32 r = (u + 0x7fffu + ((u >> 16) & 1u)) >> 16;
  return (u16)r;
}
__device__ __forceinline__ u32 pack2(float lo, float hi) {
  return (u32)f2bu(lo) | ((u32)f2bu(hi) << 16);
}

// ---------------- prep: lam, gamma ----------------
__global__ void k_prep(const float* __restrict__ nu_log, const float* __restrict__ th_log,
                       const float* __restrict__ dnu, const float* __restrict__ dth,
                       float* __restrict__ lamr, float* __restrict__ lami,
                       float* __restrict__ gam) {
  int i = blockIdx.x * 256 + threadIdx.x;
  if (i >= CR) return;
  float nu = expf(nu_log[i] + dnu[i]);
  float th = expf(th_log[i] + dth[i]);
  float mag = expf(-nu);
  lamr[i] = mag * cosf(th);
  lami[i] = mag * sinf(th);
  gam[i] = sqrtf(fmaxf(1.0f - mag * mag, 1e-6f));
}

// ---------------- prep: effective conv kernel (fuse folded) ----------------
// R8: A-swizzle retargeted to mfma_f32_32x32x16_bf16 fragments.
// A frag (M=32, K=16): lane l holds A[row = l&31][k = (l>>5)*8 + j], j=0..7.
// Stream index: [seg(9)][kslice(8 = cin2>>4)][mt(2 = o>>5)][lane(64)][j(8)].
__global__ void k_keff(const float* __restrict__ fuse_k, const float* __restrict__ fuse_b,
                       const float* __restrict__ convr_k, const float* __restrict__ convr_b,
                       const float* __restrict__ convi_k, const float* __restrict__ convi_b,
                       u16* __restrict__ keff_bf, float* __restrict__ biaseff) {
  int i = blockIdx.x * 256 + threadIdx.x;
  if (i < C * 2 * C * 9) {
    int o = i / (2 * C * 9);
    int rem = i - o * (2 * C * 9);
    int cin2 = rem / 9;
    int seg = rem - cin2 * 9;
    const float* ck = (cin2 < C) ? convr_k : convi_k;
    int cin = cin2 & (C - 1);
    int fbase = o * 2 * C + ((cin2 < C) ? 0 : C);
    float acc = 0.f;
    for (int m = 0; m < C; ++m)
      acc += fuse_k[fbase + m] * ck[(m * C + cin) * 9 + seg];
    int kslice = cin2 >> 4;
    int kk = cin2 & 15;
    int lane = (o & 31) | ((kk >> 3) << 5);
    int j = kk & 7;
    int m_tile = o >> 5;
    keff_bf[((((seg * 8 + kslice) * 2 + m_tile) * 64 + lane) << 3) + j] = f2bu(acc);
  } else if (i < C * 2 * C * 9 + C) {
    int o = i - C * 2 * C * 9;
    float acc = fuse_b[o];
    for (int m = 0; m < C; ++m) {
      acc += fuse_k[o * 2 * C + m] * convr_b[m];
      acc += fuse_k[o * 2 * C + C + m] * convi_b[m];
    }
    biaseff[o] = acc;
  }
}

// ---------------- prep: projection matrix real-stacked bf16 [m=128][k=128] ----------------
__global__ void k_apack(const float* __restrict__ pWr, const float* __restrict__ pWi,
                        u16* __restrict__ aproj) {
  int i = blockIdx.x * 256 + threadIdx.x;
  if (i >= 128 * 128) return;
  int m = i >> 7, k = i & 127;
  int c = k >> 1, im = k & 1;
  int o = m & 63;
  float v;
  if (m < 64) v = im ? -pWi[o * 64 + c] : pWr[o * 64 + c];
  else        v = im ?  pWr[o * 64 + c] : pWi[o * 64 + c];
  aproj[i] = f2bu(v);
}

// ---------------- MLP -> forcing ----------------
// grid = BL * 16: w2 tile (32x256) staged in LDS; hidden layer recomputed per
// block. (Old 32-block version was latency-serialized at 1.4% occupancy, 96us.)
__global__ __launch_bounds__(256) void k_mlp(
    const float* __restrict__ ctx, const float* __restrict__ w1, const float* __restrict__ b1,
    const float* __restrict__ w2, const float* __restrict__ b2, const float* __restrict__ fscale,
    float* __restrict__ forcing) {
  int bl = blockIdx.x >> 4;
  int kt = blockIdx.x & 15;
  int k0 = kt * 256;
  __shared__ float cv[C];
  __shared__ float hid[MH];
  __shared__ float lw2[MH * 256];
  int t = threadIdx.x;
  if (t < C) cv[t] = ctx[bl * C + t];
  for (int i = t; i < MH * 64; i += 256) {
    int j = i >> 6, q = i & 63;
    ((float4*)lw2)[i] = ((const float4*)(w2 + (size_t)j * F2 + k0))[q];
  }
  __syncthreads();
  if (t < MH) {
    float a = b1[t];
    for (int c2 = 0; c2 < C; ++c2) a += cv[c2] * w1[c2 * MH + t];
    hid[t] = tanhf(a);
  }
  __syncthreads();
  float scale = fscale[0];
  float a = b2[k0 + t];
#pragma unroll
  for (int j = 0; j < MH; ++j) a += hid[j] * lw2[j * 256 + t];
  forcing[(size_t)bl * F2 + k0 + t] = scale * a;
}

// ---------------- MFMA encode (+ ctx fused): per (b,l,c) block ----------------
__global__ __launch_bounds__(256) void k_enc(
    const float* __restrict__ x,
    const float* __restrict__ Vr, const float* __restrict__ Vi,
    const float* __restrict__ Ur, const float* __restrict__ Ui,
    float* __restrict__ ctx, float* __restrict__ u) {
  int blc = blockIdx.x;
  int c = blc & (C - 1);
  __shared__ __align__(16) char smem[17408 * 2 + 16384 + 64];
  u16* xt = (u16*)smem;                    // [64][136] A = x[s][w] bf16
  u16* bt = (u16*)(smem + 17408);          // [64][136] B rows
  float* uldr = (float*)(smem + 34816);    // [2048] U real [s*32+r]
  float* uldi = uldr + 2048;               // [2048] U imag
  float* y1  = (float*)smem;               // alias xt: [64][65] f32
  float* part = (float*)(smem + 17408);    // alias bt: [8][64]
  float* red = (float*)(smem + 17408 * 2 + 16384);  // [16]
  int t = threadIdx.x;
  int lane = t & 63, wv = t >> 6;
  float sm = 0.f;
  {
    const float4* xp = (const float4*)(x + (size_t)blc * SW);
    for (int i = t; i < SW / 4; i += 256) {
      float4 v = xp[i];
      sm += v.x + v.y + v.z + v.w;
      int idx = i * 4, s = idx >> 7, w = idx & 127;
      u32* d = (u32*)&xt[s * 136 + w];
      d[0] = pack2(v.x, v.y);
      d[1] = pack2(v.z, v.w);
    }
  }
#pragma unroll
  for (int o = 32; o > 0; o >>= 1) sm += __shfl_down(sm, o, 64);
  if (lane == 0) red[wv] = sm;
  {
    const float* vrp = Vr + (size_t)c * 4096;
    const float* vip = Vi + (size_t)c * 4096;
    for (int i = t; i < 4096; i += 256) {
      int w = i >> 5, r = i & 31;
      bt[r * 136 + w]        = f2bu(vrp[i]);
      bt[(32 + r) * 136 + w] = f2bu(-vip[i]);
    }
  }
  {
    const float* urp = Ur + (size_t)c * 2048;
    const float* uip = Ui + (size_t)c * 2048;
    for (int i = t; i < 2048; i += 256) { uldr[i] = urp[i]; uldi[i] = uip[i]; }
  }
  __syncthreads();
  if (t == 0) ctx[blc] = (red[0] + red[1] + red[2] + red[3]) * (1.f / SW);
  int quad = lane >> 4, l15 = lane & 15;
  f32x4 zf = {0.f, 0.f, 0.f, 0.f};
  f32x4 acc[4] = {zf, zf, zf, zf};
#pragma unroll
  for (int ks = 0; ks < 4; ++ks) {
    int kofs = ks * 32 + quad * 8;
    short8 bf = *(const short8*)&bt[(wv * 16 + l15) * 136 + kofs];
#pragma unroll
    for (int mt = 0; mt < 4; ++mt) {
      short8 af = *(const short8*)&xt[(mt * 16 + l15) * 136 + kofs];
      acc[mt] = __builtin_amdgcn_mfma_f32_16x16x32_bf16(af, bf, acc[mt], 0, 0, 0);
    }
  }
  __syncthreads();
#pragma unroll
  for (int mt = 0; mt < 4; ++mt)
#pragma unroll
    for (int reg = 0; reg < 4; ++reg)
      y1[(mt * 16 + quad * 4 + reg) * 65 + wv * 16 + l15] = acc[mt][reg];
  __syncthreads();
  {
    int r = t & 31, sg = t >> 5;
    float pr = 0.f, pi = 0.f;
#pragma unroll
    for (int k = 0; k < 8; ++k) {
      int s = sg * 8 + k;
      float yr = y1[s * 65 + r], yi = y1[s * 65 + 32 + r];
      float ur = uldr[s * 32 + r], ui = uldi[s * 32 + r];
      pr += ur * yr + ui * yi;
      pi += ur * yi - ui * yr;
    }
    part[sg * 64 + r * 2]     = pr;
    part[sg * 64 + r * 2 + 1] = pi;
  }
  __syncthreads();
  if (t < 32) {
    float pr = 0.f, pi = 0.f;
#pragma unroll
    for (int sg = 0; sg < 8; ++sg) {
      pr += part[sg * 64 + t * 2];
      pi += part[sg * 64 + t * 2 + 1];
    }
    u[((size_t)blc * R + t) * 2]     = pr;
    u[((size_t)blc * R + t) * 2 + 1] = pi;
  }
}

// ---------------- diagonal scan over L (applies gamma*(1+forcing)) ----------------
__global__ void k_scan(const float* __restrict__ lamr, const float* __restrict__ lami,
                       const float* __restrict__ gam, const float* __restrict__ forcing,
                       const float* __restrict__ u, float* __restrict__ h) {
  int i = blockIdx.x * 256 + threadIdx.x;
  if (i >= B * CR) return;
  int b = i / CR;
  int cr = i - b * CR;
  float lr = lamr[cr], li = lami[cr], g = gam[cr];
  float hr = 0.f, hi = 0.f;
  for (int l = 0; l < L; ++l) {
    size_t off = ((size_t)(b * L + l) * CR + cr) * 2;
    float ur0 = u[off], ui0 = u[off + 1];
    float fr = forcing[off], fi = forcing[off + 1];
    float ofr = 1.f + fr;
    float ur = g * (ur0 * ofr - ui0 * fi);
    float ui = g * (ur0 * fi + ui0 * ofr);
    float nr = lr * hr - li * hi + ur;
    float ni = lr * hi + li * hr + ui;
    hr = nr; hi = ni;
    h[off] = hr; h[off + 1] = hi;
  }
}

// ---------------- MFMA decode: per (bl,c), Y[s,w] = (h*U)[s,:] x V[w,:]^T ----------------
__global__ __launch_bounds__(256) void k_decode(
    const float* __restrict__ h,
    const float* __restrict__ Ur, const float* __restrict__ Ui,
    const float* __restrict__ Vr, const float* __restrict__ Vi,
    u32* __restrict__ y_cm32, int bl_base) {
  int bid = blockIdx.x;
  int c = bid & 63;
  int blh = bid >> 6;
  int bl = bl_base + blh;
  __shared__ __align__(16) u16 ldA[64 * 72];
  __shared__ __align__(16) u16 ldBr[128 * 72];
  __shared__ __align__(16) u16 ldBi[128 * 72];
  int t = threadIdx.x;
  {
    const float* hp = h + ((size_t)(bl * C + c) * R) * 2;
    const float* urp = Ur + (size_t)c * (S * R);
    const float* uip = Ui + (size_t)c * (S * R);
    for (int p = t; p < S * R; p += 256) {
      int s = p >> 5, r = p & 31;
      float hr = hp[r * 2], hi = hp[r * 2 + 1];
      float ur = urp[p], ui = uip[p];
      ldA[s * 72 + r]      = f2bu(hr * ur - hi * ui);
      ldA[s * 72 + 32 + r] = f2bu(hr * ui + hi * ur);
    }
  }
  {
    const float* vrp = Vr + (size_t)c * (W * R);
    const float* vip = Vi + (size_t)c * (W * R);
    for (int p = t; p < W * R; p += 256) {
      int w = p >> 5, r = p & 31;
      float vr = vrp[p], vi = vip[p];
      ldBr[w * 72 + r]      = f2bu(vr);
      ldBr[w * 72 + 32 + r] = f2bu(-vi);
      ldBi[w * 72 + r]      = f2bu(vi);
      ldBi[w * 72 + 32 + r] = f2bu(vr);
    }
  }
  __syncthreads();
  int lane = t & 63, q = t >> 6;
  int quad = lane >> 4, l15 = lane & 15;
  f32x4 zf = {0.f, 0.f, 0.f, 0.f};
  f32x4 accr[4][2], acci[4][2];
#pragma unroll
  for (int mt = 0; mt < 4; ++mt)
#pragma unroll
    for (int nt = 0; nt < 2; ++nt) { accr[mt][nt] = zf; acci[mt][nt] = zf; }
#pragma unroll
  for (int ks = 0; ks < 2; ++ks) {
    int kofs = ks * 32 + quad * 8;
    short8 af[4];
#pragma unroll
    for (int mt = 0; mt < 4; ++mt)
      af[mt] = *(const short8*)&ldA[(mt * 16 + l15) * 72 + kofs];
#pragma unroll
    for (int nt = 0; nt < 2; ++nt) {
      int wrow = q * 32 + nt * 16 + l15;
      short8 br = *(const short8*)&ldBr[wrow * 72 + kofs];
      short8 bi = *(const short8*)&ldBi[wrow * 72 + kofs];
#pragma unroll
      for (int mt = 0; mt < 4; ++mt) {
        accr[mt][nt] = __builtin_amdgcn_mfma_f32_16x16x32_bf16(af[mt], br, accr[mt][nt], 0, 0, 0);
        acci[mt][nt] = __builtin_amdgcn_mfma_f32_16x16x32_bf16(af[mt], bi, acci[mt][nt], 0, 0, 0);
      }
    }
  }
  u32* dst = y_cm32 + ((size_t)(blh * 64 + c) << 13);
#pragma unroll
  for (int mt = 0; mt < 4; ++mt) {
#pragma unroll
    for (int nt = 0; nt < 2; ++nt) {
      int w = q * 32 + nt * 16 + l15;
#pragma unroll
      for (int reg = 0; reg < 4; ++reg) {
        int s = mt * 16 + quad * 4 + reg;
        dst[s * 128 + w] = pack2(accr[mt][nt][reg], acci[mt][nt][reg]);
      }
    }
  }
}

// ---------------- MFMA projection GEMM: M=128 ch_out, K=128, N=512/block -> NHWC ----------------
__global__ __launch_bounds__(256) void k_proj(
    const u32* __restrict__ y_cm32, const u16* __restrict__ aproj,
    const float* __restrict__ pbr, const float* __restrict__ pbi,
    u16* __restrict__ ynhwc, int bl_base) {
  int bid = blockIdx.x;
  int ntile = bid & 15;
  int blh = bid >> 4;
  int bl = bl_base + blh;
  __shared__ __align__(16) u16 lda[128 * 136];
  __shared__ __align__(16) u32 ldb[128 * 68];
  __shared__ float ldbias[128];
  int t = threadIdx.x;
  for (int i = t; i < 128 * 16; i += 256) {
    int m = i >> 4, qq = i & 15;
    ((uint4*)&lda[m * 136])[qq] = ((const uint4*)&aproj[m * 128])[qq];
  }
  if (t < 128) ldbias[t] = t < 64 ? pbr[t] : pbi[t - 64];

  int lane = t & 63, wv = t >> 6;
  int quad = lane >> 4, l15 = lane & 15;
  int cidx = t & 63, seg = t >> 6;
  f32x4 zf = {0.f, 0.f, 0.f, 0.f};

  for (int chunk = 0; chunk < 4; ++chunk) {
    int n0 = ntile * 512 + chunk * 128;
    __syncthreads();
    {
      const uint4* src = (const uint4*)(y_cm32 + (((size_t)(blh * 64 + cidx)) << 13) + n0 + seg * 32);
      u32 tmp[32];
#pragma unroll
      for (int qq = 0; qq < 8; ++qq) {
        uint4 v = src[qq];
        tmp[qq * 4] = v.x; tmp[qq * 4 + 1] = v.y; tmp[qq * 4 + 2] = v.z; tmp[qq * 4 + 3] = v.w;
      }
#pragma unroll
      for (int j = 0; j < 32; ++j)
        ldb[(seg * 32 + j) * 68 + cidx] = tmp[j];
    }
    __syncthreads();
    f32x4 acc[8][2];
#pragma unroll
    for (int mt = 0; mt < 8; ++mt) { acc[mt][0] = zf; acc[mt][1] = zf; }
    const u16* ldb16 = (const u16*)ldb;
#pragma unroll
    for (int ks = 0; ks < 4; ++ks) {
      int kofs = ks * 32 + quad * 8;
      short8 af[8];
#pragma unroll
      for (int mt = 0; mt < 8; ++mt)
        af[mt] = *(const short8*)&lda[(mt * 16 + l15) * 136 + kofs];
#pragma unroll
      for (int nt = 0; nt < 2; ++nt) {
        int nrow = wv * 32 + nt * 16 + l15;
        short8 bf = *(const short8*)&ldb16[nrow * 136 + kofs];
#pragma unroll
        for (int mt = 0; mt < 8; ++mt)
          acc[mt][nt] = __builtin_amdgcn_mfma_f32_16x16x32_bf16(af[mt], bf, acc[mt][nt], 0, 0, 0);
      }
    }
#pragma unroll
    for (int nt = 0; nt < 2; ++nt) {
      int n = n0 + wv * 32 + nt * 16 + l15;
      u16* drow = ynhwc + (((size_t)bl * SW + n) << 7);
#pragma unroll
      for (int mt = 0; mt < 8; ++mt) {
        int ch = mt * 16 + quad * 4;
        u32 lo = pack2(acc[mt][nt][0] + ldbias[ch],     acc[mt][nt][1] + ldbias[ch + 1]);
        u32 hi = pack2(acc[mt][nt][2] + ldbias[ch + 2], acc[mt][nt][3] + ldbias[ch + 3]);
        u32* dp = (u32*)(drow + ch);
        dp[0] = lo; dp[1] = hi;
      }
    }
  }
}

// ---------------- MFMA implicit-GEMM conv ----------------
// R8: 32x32x16 MFMA at the R5 operating point. Ledger:
//   R1 74.0 / R2 64.4 / R3 67.9 / R4 81.8 / R5 64.9(60.4@R7) / R6 76.2
// All 16x16x32 variants plateau ~60-65us with no pipe >50% -> issue/latency
// bound. This round holds EVERYTHING memory-side constant (grid 2048,
// win[4][66][72]=38KB, 4blk/CU, same A/B bytes, same ds_read count/pattern)
// and halves instruction count: per 65kFLOP {1A+2B+2MFMA} vs {1A+2B+4MFMA};
// matrix cycles -20% (8.07cyc/32kFLOP vs ~5cyc/16k).
// Wave wv=(sr,mt): sr=wv&1 (output s-row), mt=wv>>1 (32-ch m-tile).
// Frag layouts (convention verified by working 16x16 code + guide m74/m101):
//   A: row=l&31, k=(l>>5)*8+j ; B: col=l&31, k=(l>>5)*8+j ;
//   C/D: col=l&31, row=(reg&3)+8*(reg>>2)+4*(l>>5).
__global__ __launch_bounds__(256, 4) void k_conv(
    const u16* __restrict__ ynhwc, const u16* __restrict__ keff_bf,
    const float* __restrict__ biaseff, u16* __restrict__ fused) {
  int bid = blockIdx.x;
  int wt = bid & 1;
  int st = (bid >> 1) & 31;
  int bl = bid >> 6;
  int s0 = st * 2;
  int w0 = wt * 64;
  __shared__ __align__(16) u16 win[4][66][72];   // [s-row][w-col][64ch + 8 pad]
  int t = threadIdx.x;
  int c_lo = (wt == 0) ? 1 : 0;
  int c_hi = (wt == 0) ? 66 : 65;
  uint4 z4 = make_uint4(0u, 0u, 0u, 0u);

  int lane = t & 63;
  int wv = t >> 6;
  int sr = wv & 1;          // output s-row within block
  int mt = wv >> 1;         // m-tile (32 out-ch)
  int l31 = lane & 31, khalf = lane >> 5;

  f32x16 acc0, acc1;        // [nt=0], [nt=1]
#pragma unroll
  for (int i = 0; i < 16; ++i) { acc0[i] = 0.f; acc1[i] = 0.f; }
  const short8* ap = (const short8*)keff_bf;
  short8 abuf[2];

#pragma unroll
  for (int p = 0; p < 2; ++p) {
    if (p) __syncthreads();   // pass-0 LDS reads complete before restage
    // stage ch-half p: 8 uint4 (64 ch) per (row, col)
    for (int rr = 0; rr < 4; ++rr) {
      int rs = s0 - 1 + rr;
      if (rs < 0 || rs >= S) {
        for (int i = t; i < 66 * 8; i += 256) {
          int col = i >> 3, q = i & 7;
          ((uint4*)&win[rr][col][0])[q] = z4;
        }
      } else {
        if (wt == 0 && t < 8) ((uint4*)&win[rr][0][0])[t] = z4;
        if (wt == 1 && t < 8) ((uint4*)&win[rr][65][0])[t] = z4;
        const uint4* src = (const uint4*)(ynhwc +
            (((size_t)bl * S + rs) * W + (w0 - 1 + c_lo)) * 128 + p * 64);
        int n4 = (c_hi - c_lo) * 8;   // 65*8 = 520
        for (int i = t; i < n4; i += 256) {
          int col = i >> 3, q = i & 7;
          ((uint4*)&win[rr][c_lo + col][0])[q] = src[col * 16 + q];
        }
      }
    }
    __syncthreads();

    // prefetch step 0 (seg=0, k4=0): kslice = p*4
    abuf[0] = ap[((p * 4) * 2 + mt) * 64 + lane];

    // 36 steps: m -> seg = m>>2, k4 = m&3 (kslice = p*4 + k4)
#pragma unroll
    for (int m = 0; m < 36; ++m) {
      const int cur = m & 1;
      const int nxt = cur ^ 1;
      if (m < 35) {
        const int m1 = m + 1;
        abuf[nxt] = ap[((((m1 >> 2) * 8 + p * 4 + (m1 & 3)) * 2 + mt)) * 64 + lane];
      }
      const int seg = m >> 2;
      const int k4 = m & 3;
      const int dr = seg / 3;
      const int dc = seg - dr * 3;
      const u16* bb = &win[sr + dr][l31 + dc][k4 * 16 + khalf * 8];
      short8 b0 = *(const short8*)bb;
      short8 b1 = *(const short8*)(bb + 32 * 72);
      acc0 = __builtin_amdgcn_mfma_f32_32x32x16_bf16(abuf[cur], b0, acc0, 0, 0, 0);
      acc1 = __builtin_amdgcn_mfma_f32_32x32x16_bf16(abuf[cur], b1, acc1, 0, 0, 0);
    }
  }

  int s_out = s0 + sr;
#pragma unroll
  for (int reg = 0; reg < 16; ++reg) {
    int o = mt * 32 + (reg & 3) + 8 * (reg >> 2) + 4 * khalf;
    float bias = biaseff[o];
    size_t rowoff = ((size_t)(bl * C + o) * S + s_out) * W;
    fused[rowoff + w0 + l31]      = f2bu(acc0[reg] + bias);
    fused[rowoff + w0 + 32 + l31] = f2bu(acc1[reg] + bias);
  }
}

// ---------------- layernorm (stats in-kernel) + residual ----------------
// R7: normalize loop vectorized (float4 x/g/b/out, uint2 fused-from-LDS).
__global__ __launch_bounds__(256) void k_ln(
    const u16* __restrict__ fused,
    const float* __restrict__ ln_g, const float* __restrict__ ln_b,
    const float* __restrict__ x, float* __restrict__ out) {
  int blc = blockIdx.x;
  __shared__ u16 fs[SW];
  __shared__ float red[12];
  int t = threadIdx.x;
  const uint4* fp = (const uint4*)(fused + (size_t)blc * SW);
  float sm = 0.f, sq = 0.f;
  for (int i = t; i < SW / 8; i += 256) {
    uint4 v = fp[i];
    ((uint4*)fs)[i] = v;
    float f0 = bf_lo(v.x), f1 = bf_hi(v.x), f2 = bf_lo(v.y), f3 = bf_hi(v.y);
    float f4 = bf_lo(v.z), f5 = bf_hi(v.z), f6 = bf_lo(v.w), f7 = bf_hi(v.w);
    sm += f0 + f1 + f2 + f3 + f4 + f5 + f6 + f7;
    sq += f0 * f0 + f1 * f1 + f2 * f2 + f3 * f3 + f4 * f4 + f5 * f5 + f6 * f6 + f7 * f7;
  }
#pragma unroll
  for (int off = 32; off > 0; off >>= 1) {
    sm += __shfl_down(sm, off, 64);
    sq += __shfl_down(sq, off, 64);
  }
  int lane = t & 63, wid = t >> 6;
  if (lane == 0) { red[wid * 2] = sm; red[wid * 2 + 1] = sq; }
  __syncthreads();
  if (t == 0) {
    float S1 = red[0] + red[2] + red[4] + red[6];
    float S2 = red[1] + red[3] + red[5] + red[7];
    float mu = S1 * (1.f / SW);
    float var = S2 * (1.f / SW) - mu * mu;
    red[8] = mu;
    red[9] = rsqrtf(var + 1e-5f);
  }
  __syncthreads();
  float mu = red[8], rstd = red[9];
  const float4* xp4 = (const float4*)(x + (size_t)blc * SW);
  float4* op4 = (float4*)(out + (size_t)blc * SW);
  const float4* g4 = (const float4*)ln_g;
  const float4* b4 = (const float4*)ln_b;
  const uint2* fs2 = (const uint2*)fs;
  for (int i = t; i < SW / 4; i += 256) {
    uint2 fv = fs2[i];
    float4 xv = xp4[i];
    float4 gv = g4[i];
    float4 bv = b4[i];
    float4 o;
    o.x = (bf_lo(fv.x) - mu) * rstd * gv.x + bv.x + xv.x;
    o.y = (bf_hi(fv.x) - mu) * rstd * gv.y + bv.y + xv.y;
    o.z = (bf_lo(fv.y) - mu) * rstd * gv.z + bv.z + xv.z;
    o.w = (bf_hi(fv.y) - mu) * rstd * gv.w + bv.w + xv.w;
    op4[i] = o;
  }
}

extern "C" void kernel_launch(void* const* d_in, const int* in_sizes, int n_in,
                              void* d_out, int out_size, void* d_ws, size_t ws_size,
                              hipStream_t stream) {
  (void)in_sizes; (void)n_in; (void)out_size; (void)ws_size;
  const float* x       = (const float*)d_in[0];
  const float* nu_log  = (const float*)d_in[1];
  const float* th_log  = (const float*)d_in[2];
  const float* dnu     = (const float*)d_in[3];
  const float* dth     = (const float*)d_in[4];
  const float* w1      = (const float*)d_in[5];
  const float* b1      = (const float*)d_in[6];
  const float* w2      = (const float*)d_in[7];
  const float* b2      = (const float*)d_in[8];
  const float* fscale  = (const float*)d_in[9];
  const float* Ur      = (const float*)d_in[10];
  const float* Ui      = (const float*)d_in[11];
  const float* Vr      = (const float*)d_in[12];
  const float* Vi      = (const float*)d_in[13];
  const float* pWr     = (const float*)d_in[14];
  const float* pWi     = (const float*)d_in[15];
  const float* pbr     = (const float*)d_in[16];
  const float* pbi     = (const float*)d_in[17];
  const float* convr_k = (const float*)d_in[18];
  const float* convr_b = (const float*)d_in[19];
  const float* convi_k = (const float*)d_in[20];
  const float* convi_b = (const float*)d_in[21];
  const float* fuse_k  = (const float*)d_in[22];
  const float* fuse_b  = (const float*)d_in[23];
  const float* ln_g    = (const float*)d_in[24];
  const float* ln_b    = (const float*)d_in[25];
  float* out = (float*)d_out;

  char* ws = (char*)d_ws;
  float* lamr    = (float*)ws;
  float* lami    = lamr + 2048;
  float* gam     = lami + 2048;
  float* biaseff = gam + 2048;        // 64
  float* ctx     = biaseff + 64;      // 2048
  float* forcing = ctx + 2048;        // 131072
  float* ubuf    = forcing + 131072;  // 131072
  float* hbuf    = ubuf + 131072;     // 131072
  u16* keff_bf   = (u16*)(hbuf + 131072);       // 73728 u16 (144 KB)
  u16* aproj     = keff_bf + 73728;             // 16384 u16 (32 KB)
  size_t off = ((size_t)((char*)(aproj + 16384) - ws) + 255) & ~(size_t)255;
  u32* y_cm32    = (u32*)(ws + off);            // 32 MB (half-batch)
  u16* fused     = (u16*)y_cm32;                // ALIAS: live only after y_cm32 dead
  u16* ynhwc     = (u16*)(ws + off + (size_t)32 * 1024 * 1024);  // 64 MB
  // total ws ~ 97.8 MB

  k_prep<<<8, 256, 0, stream>>>(nu_log, th_log, dnu, dth, lamr, lami, gam);
  k_keff<<<289, 256, 0, stream>>>(fuse_k, fuse_b, convr_k, convr_b, convi_k, convi_b,
                                  keff_bf, biaseff);
  k_apack<<<64, 256, 0, stream>>>(pWr, pWi, aproj);
  k_enc<<<BL * C, 256, 0, stream>>>(x, Vr, Vi, Ur, Ui, ctx, ubuf);
  k_mlp<<<BL * 16, 256, 0, stream>>>(ctx, w1, b1, w2, b2, fscale, forcing);
  k_scan<<<16, 256, 0, stream>>>(lamr, lami, gam, forcing, ubuf, hbuf);
  k_decode<<<1024, 256, 0, stream>>>(hbuf, Ur, Ui, Vr, Vi, y_cm32, 0);
  k_proj<<<256, 256, 0, stream>>>(y_cm32, aproj, pbr, pbi, ynhwc, 0);
  k_decode<<<1024, 256, 0, stream>>>(hbuf, Ur, Ui, Vr, Vi, y_cm32, 16);
  k_proj<<<256, 256, 0, stream>>>(y_cm32, aproj, pbr, pbi, ynhwc, 16);
  k_conv<<<2048, 256, 0, stream>>>(ynhwc, keff_bf, biaseff, fused);
  k_ln<<<BL * C, 256, 0, stream>>>(fused, ln_g, ln_b, x, out);
}

// Round 9
// 338.802 us; speedup vs baseline: 1.0786x; 1.0152x over previous
//
#include <hip/hip_runtime.h>

typedef unsigned short u16;
typedef unsigned int u32;
typedef __attribute__((ext_vector_type(8))) short short8;
typedef __attribute__((ext_vector_type(4))) float f32x4;
typedef __attribute__((ext_vector_type(16))) float f32x16;

constexpr int B = 2, L = 16, C = 64, S = 64, W = 128, R = 32, MH = 32;
constexpr int BL = B * L;        // 32
constexpr int SW = S * W;        // 8192
constexpr int CR = C * R;        // 2048
constexpr int F2 = C * R * 2;    // 4096
constexpr int NVE = 64 * 4 * 4 * 64 * 8;   // 524288 (Venc elems)
constexpr int NVD = 64 * 8 * 2 * 64 * 8;   // 524288 (Vdec elems per matrix)

__device__ __forceinline__ float us2f(u16 h) { return __uint_as_float(((u32)h) << 16); }
__device__ __forceinline__ float bf_lo(u32 u) { return __uint_as_float(u << 16); }
__device__ __forceinline__ float bf_hi(u32 u) { return __uint_as_float(u & 0xffff0000u); }
__device__ __forceinline__ u16 f2bu(float f) {
  u32 u = __float_as_uint(f);
  u32 r = (u + 0x7fffu + ((u >> 16) & 1u)) >> 16;
  return (u16)r;
}
__device__ __forceinline__ u32 pack2(float lo, float hi) {
  return (u32)f2bu(lo) | ((u32)f2bu(hi) << 16);
}

// ---------------- prep: lam, gamma ----------------
__global__ void k_prep(const float* __restrict__ nu_log, const float* __restrict__ th_log,
                       const float* __restrict__ dnu, const float* __restrict__ dth,
                       float* __restrict__ lamr, float* __restrict__ lami,
                       float* __restrict__ gam) {
  int i = blockIdx.x * 256 + threadIdx.x;
  if (i >= CR) return;
  float nu = expf(nu_log[i] + dnu[i]);
  float th = expf(th_log[i] + dth[i]);
  float mag = expf(-nu);
  lamr[i] = mag * cosf(th);
  lami[i] = mag * sinf(th);
  gam[i] = sqrtf(fmaxf(1.0f - mag * mag, 1e-6f));
}

// ---------------- prep: effective conv kernel (fuse folded) ----------------
// 32x32x16 A-fragments: lane l holds A[row=l&31][k=(l>>5)*8+j].
// Stream index: [seg(9)][kslice(8)][mt(2)][lane(64)][j(8)].
__global__ void k_keff(const float* __restrict__ fuse_k, const float* __restrict__ fuse_b,
                       const float* __restrict__ convr_k, const float* __restrict__ convr_b,
                       const float* __restrict__ convi_k, const float* __restrict__ convi_b,
                       u16* __restrict__ keff_bf, float* __restrict__ biaseff) {
  int i = blockIdx.x * 256 + threadIdx.x;
  if (i < C * 2 * C * 9) {
    int o = i / (2 * C * 9);
    int rem = i - o * (2 * C * 9);
    int cin2 = rem / 9;
    int seg = rem - cin2 * 9;
    const float* ck = (cin2 < C) ? convr_k : convi_k;
    int cin = cin2 & (C - 1);
    int fbase = o * 2 * C + ((cin2 < C) ? 0 : C);
    float acc = 0.f;
    for (int m = 0; m < C; ++m)
      acc += fuse_k[fbase + m] * ck[(m * C + cin) * 9 + seg];
    int kslice = cin2 >> 4;
    int kk = cin2 & 15;
    int lane = (o & 31) | ((kk >> 3) << 5);
    int j = kk & 7;
    int m_tile = o >> 5;
    keff_bf[((((seg * 8 + kslice) * 2 + m_tile) * 64 + lane) << 3) + j] = f2bu(acc);
  } else if (i < C * 2 * C * 9 + C) {
    int o = i - C * 2 * C * 9;
    float acc = fuse_b[o];
    for (int m = 0; m < C; ++m) {
      acc += fuse_k[o * 2 * C + m] * convr_b[m];
      acc += fuse_k[o * 2 * C + C + m] * convi_b[m];
    }
    biaseff[o] = acc;
  }
}

// ---------------- prep: V pre-swizzled into MFMA B-fragment order ----------------
// R9: k_enc/k_decode previously transposed V into LDS per block (8-16K scalar
// f32 loads + f2bu + scattered 2B LDS writes at stride 136/72 -> 8-way
// conflicts), recomputed 2048x for CONSTANT data. Pack once:
//  Venc[c][wv(4)][ks(4)][lane(64)][j(8)]: B[n=wv*16+(l&15)][w=ks*32+(l>>4)*8+j]
//    where B[n][w] = n<32 ? Vr[c][w][n] : -Vi[c][w][n-32]
//  Vdec{r,i}[c][g(8)][ks(2)][lane][j]:  B[w=g*16+(l&15)][k=ks*32+(l>>4)*8+j]
//    B_r[w][k] = k<32 ? Vr[c][w][k] : -Vi[c][w][k-32]
//    B_i[w][k] = k<32 ? Vi[c][w][k] :  Vr[c][w][k-32]
__global__ void k_vpack(const float* __restrict__ Vr, const float* __restrict__ Vi,
                        u16* __restrict__ venc, u16* __restrict__ vdecr,
                        u16* __restrict__ vdeci) {
  int i = blockIdx.x * 256 + threadIdx.x;
  if (i < NVE) {
    int j = i & 7, lane = (i >> 3) & 63, ks = (i >> 9) & 3;
    int wv = (i >> 11) & 3, c = i >> 13;
    int n = wv * 16 + (lane & 15);
    int w = ks * 32 + ((lane >> 4) & 3) * 8 + j;
    float v = (n < 32) ? Vr[(size_t)c * 4096 + w * 32 + n]
                       : -Vi[(size_t)c * 4096 + w * 32 + (n - 32)];
    venc[i] = f2bu(v);
  } else if (i < NVE + 2 * NVD) {
    int ii = i - NVE;
    int isI = 0;
    if (ii >= NVD) { ii -= NVD; isI = 1; }
    int j = ii & 7, lane = (ii >> 3) & 63, ks = (ii >> 9) & 1;
    int g = (ii >> 10) & 7, c = ii >> 13;
    int w = g * 16 + (lane & 15);
    int k = ks * 32 + ((lane >> 4) & 3) * 8 + j;
    float v;
    if (!isI) v = (k < 32) ? Vr[(size_t)c * 4096 + w * 32 + k]
                           : -Vi[(size_t)c * 4096 + w * 32 + (k - 32)];
    else      v = (k < 32) ? Vi[(size_t)c * 4096 + w * 32 + k]
                           :  Vr[(size_t)c * 4096 + w * 32 + (k - 32)];
    (isI ? vdeci : vdecr)[ii] = f2bu(v);
  }
}

// ---------------- prep: projection matrix real-stacked bf16 [m=128][k=128] ----------------
__global__ void k_apack(const float* __restrict__ pWr, const float* __restrict__ pWi,
                        u16* __restrict__ aproj) {
  int i = blockIdx.x * 256 + threadIdx.x;
  if (i >= 128 * 128) return;
  int m = i >> 7, k = i & 127;
  int c = k >> 1, im = k & 1;
  int o = m & 63;
  float v;
  if (m < 64) v = im ? -pWi[o * 64 + c] : pWr[o * 64 + c];
  else        v = im ?  pWr[o * 64 + c] : pWi[o * 64 + c];
  aproj[i] = f2bu(v);
}

// ---------------- MLP -> forcing ----------------
__global__ __launch_bounds__(256) void k_mlp(
    const float* __restrict__ ctx, const float* __restrict__ w1, const float* __restrict__ b1,
    const float* __restrict__ w2, const float* __restrict__ b2, const float* __restrict__ fscale,
    float* __restrict__ forcing) {
  int bl = blockIdx.x >> 4;
  int kt = blockIdx.x & 15;
  int k0 = kt * 256;
  __shared__ float cv[C];
  __shared__ float hid[MH];
  __shared__ float lw2[MH * 256];
  int t = threadIdx.x;
  if (t < C) cv[t] = ctx[bl * C + t];
  for (int i = t; i < MH * 64; i += 256) {
    int j = i >> 6, q = i & 63;
    ((float4*)lw2)[i] = ((const float4*)(w2 + (size_t)j * F2 + k0))[q];
  }
  __syncthreads();
  if (t < MH) {
    float a = b1[t];
    for (int c2 = 0; c2 < C; ++c2) a += cv[c2] * w1[c2 * MH + t];
    hid[t] = tanhf(a);
  }
  __syncthreads();
  float scale = fscale[0];
  float a = b2[k0 + t];
#pragma unroll
  for (int j = 0; j < MH; ++j) a += hid[j] * lw2[j * 256 + t];
  forcing[(size_t)bl * F2 + k0 + t] = scale * a;
}

// ---------------- MFMA encode (+ ctx fused): per (b,l,c) block ----------------
// R9: B-fragments loaded directly from pre-swizzled venc (global, L2-resident,
// reused 32x across bl) -> no bt LDS array, no per-block V transpose.
// LDS 51->35 KB.
__global__ __launch_bounds__(256) void k_enc(
    const float* __restrict__ x, const u16* __restrict__ venc,
    const float* __restrict__ Ur, const float* __restrict__ Ui,
    float* __restrict__ ctx, float* __restrict__ u) {
  int blc = blockIdx.x;
  int c = blc & (C - 1);
  __shared__ __align__(16) char smem[35968];
  u16* xt = (u16*)smem;                    // [64][136] A = x[s][w] bf16
  float* uldr = (float*)(smem + 17408);    // [2048] U real [s*32+r]
  float* uldi = uldr + 2048;               // [2048] U imag
  float* y1  = (float*)smem;               // alias xt: [64][65] f32 (16640 B)
  float* part = (float*)(smem + 33792);    // [512]
  float* red = (float*)(smem + 35840);     // [16]
  int t = threadIdx.x;
  int lane = t & 63, wv = t >> 6;
  // B-fragments: direct global load (independent of LDS; issue early)
  short8 bf[4];
  {
    const short8* vep = (const short8*)venc + ((size_t)(c * 4 + wv) * 4) * 64 + lane;
#pragma unroll
    for (int ks = 0; ks < 4; ++ks) bf[ks] = vep[ks * 64];
  }
  // stage x (f32 -> bf16 LDS) + ctx sum
  float sm = 0.f;
  {
    const float4* xp = (const float4*)(x + (size_t)blc * SW);
    for (int i = t; i < SW / 4; i += 256) {
      float4 v = xp[i];
      sm += v.x + v.y + v.z + v.w;
      int idx = i * 4, s = idx >> 7, w = idx & 127;
      u32* d = (u32*)&xt[s * 136 + w];
      d[0] = pack2(v.x, v.y);
      d[1] = pack2(v.z, v.w);
    }
  }
#pragma unroll
  for (int o = 32; o > 0; o >>= 1) sm += __shfl_down(sm, o, 64);
  if (lane == 0) red[wv] = sm;
  // stage U f32
  {
    const float* urp = Ur + (size_t)c * 2048;
    const float* uip = Ui + (size_t)c * 2048;
    for (int i = t; i < 2048; i += 256) { uldr[i] = urp[i]; uldi[i] = uip[i]; }
  }
  __syncthreads();
  if (t == 0) ctx[blc] = (red[0] + red[1] + red[2] + red[3]) * (1.f / SW);
  int quad = lane >> 4, l15 = lane & 15;
  f32x4 zf = {0.f, 0.f, 0.f, 0.f};
  f32x4 acc[4] = {zf, zf, zf, zf};
#pragma unroll
  for (int ks = 0; ks < 4; ++ks) {
    int kofs = ks * 32 + quad * 8;
#pragma unroll
    for (int mt = 0; mt < 4; ++mt) {
      short8 af = *(const short8*)&xt[(mt * 16 + l15) * 136 + kofs];
      acc[mt] = __builtin_amdgcn_mfma_f32_16x16x32_bf16(af, bf[ks], acc[mt], 0, 0, 0);
    }
  }
  __syncthreads();   // xt reads done
  // write y1 C-frags: s = mt*16+quad*4+reg, n = wv*16+l15
#pragma unroll
  for (int mt = 0; mt < 4; ++mt)
#pragma unroll
    for (int reg = 0; reg < 4; ++reg)
      y1[(mt * 16 + quad * 4 + reg) * 65 + wv * 16 + l15] = acc[mt][reg];
  __syncthreads();
  // stage 2: u_raw[r] = sum_s conj(U[s,r]) * y1[s,r]
  {
    int r = t & 31, sg = t >> 5;
    float pr = 0.f, pi = 0.f;
#pragma unroll
    for (int k = 0; k < 8; ++k) {
      int s = sg * 8 + k;
      float yr = y1[s * 65 + r], yi = y1[s * 65 + 32 + r];
      float ur = uldr[s * 32 + r], ui = uldi[s * 32 + r];
      pr += ur * yr + ui * yi;
      pi += ur * yi - ui * yr;
    }
    part[sg * 64 + r * 2]     = pr;
    part[sg * 64 + r * 2 + 1] = pi;
  }
  __syncthreads();
  if (t < 32) {
    float pr = 0.f, pi = 0.f;
#pragma unroll
    for (int sg = 0; sg < 8; ++sg) {
      pr += part[sg * 64 + t * 2];
      pi += part[sg * 64 + t * 2 + 1];
    }
    u[((size_t)blc * R + t) * 2]     = pr;
    u[((size_t)blc * R + t) * 2 + 1] = pi;
  }
}

// ---------------- diagonal scan over L (applies gamma*(1+forcing)) ----------------
__global__ void k_scan(const float* __restrict__ lamr, const float* __restrict__ lami,
                       const float* __restrict__ gam, const float* __restrict__ forcing,
                       const float* __restrict__ u, float* __restrict__ h) {
  int i = blockIdx.x * 256 + threadIdx.x;
  if (i >= B * CR) return;
  int b = i / CR;
  int cr = i - b * CR;
  float lr = lamr[cr], li = lami[cr], g = gam[cr];
  float hr = 0.f, hi = 0.f;
  for (int l = 0; l < L; ++l) {
    size_t off = ((size_t)(b * L + l) * CR + cr) * 2;
    float ur0 = u[off], ui0 = u[off + 1];
    float fr = forcing[off], fi = forcing[off + 1];
    float ofr = 1.f + fr;
    float ur = g * (ur0 * ofr - ui0 * fi);
    float ui = g * (ur0 * fi + ui0 * ofr);
    float nr = lr * hr - li * hi + ur;
    float ni = lr * hi + li * hr + ui;
    hr = nr; hi = ni;
    h[off] = hr; h[off + 1] = hi;
  }
}

// ---------------- MFMA decode: per (bl,c), Y[s,w] = (h*U)[s,:] x V[w,:]^T ----------------
// R9: B-fragments (Vdec r/i) loaded directly from pre-swizzled global
// (L2-resident, reused 16x). Only the h-dependent A tile stays in LDS
// (staging for it is conflict-free). LDS 46->9 KB.
__global__ __launch_bounds__(256) void k_decode(
    const float* __restrict__ h,
    const float* __restrict__ Ur, const float* __restrict__ Ui,
    const u16* __restrict__ vdecr, const u16* __restrict__ vdeci,
    u32* __restrict__ y_cm32, int bl_base) {
  int bid = blockIdx.x;
  int c = bid & 63;
  int blh = bid >> 6;
  int bl = bl_base + blh;
  __shared__ __align__(16) u16 ldA[64 * 72];
  int t = threadIdx.x;
  {
    const float* hp = h + ((size_t)(bl * C + c) * R) * 2;
    const float* urp = Ur + (size_t)c * (S * R);
    const float* uip = Ui + (size_t)c * (S * R);
    for (int p = t; p < S * R; p += 256) {
      int s = p >> 5, r = p & 31;
      float hr = hp[r * 2], hi = hp[r * 2 + 1];
      float ur = urp[p], ui = uip[p];
      ldA[s * 72 + r]      = f2bu(hr * ur - hi * ui);
      ldA[s * 72 + 32 + r] = f2bu(hr * ui + hi * ur);
    }
  }
  __syncthreads();
  int lane = t & 63, q = t >> 6;
  int quad = lane >> 4, l15 = lane & 15;
  const short8* vdr = (const short8*)vdecr + (size_t)c * 16 * 64;
  const short8* vdi = (const short8*)vdeci + (size_t)c * 16 * 64;
  f32x4 zf = {0.f, 0.f, 0.f, 0.f};
  f32x4 accr[4][2], acci[4][2];
#pragma unroll
  for (int mt = 0; mt < 4; ++mt)
#pragma unroll
    for (int nt = 0; nt < 2; ++nt) { accr[mt][nt] = zf; acci[mt][nt] = zf; }
#pragma unroll
  for (int ks = 0; ks < 2; ++ks) {
    int kofs = ks * 32 + quad * 8;
    short8 af[4];
#pragma unroll
    for (int mt = 0; mt < 4; ++mt)
      af[mt] = *(const short8*)&ldA[(mt * 16 + l15) * 72 + kofs];
#pragma unroll
    for (int nt = 0; nt < 2; ++nt) {
      int g = q * 2 + nt;
      short8 br = vdr[(g * 2 + ks) * 64 + lane];
      short8 bi = vdi[(g * 2 + ks) * 64 + lane];
#pragma unroll
      for (int mt = 0; mt < 4; ++mt) {
        accr[mt][nt] = __builtin_amdgcn_mfma_f32_16x16x32_bf16(af[mt], br, accr[mt][nt], 0, 0, 0);
        acci[mt][nt] = __builtin_amdgcn_mfma_f32_16x16x32_bf16(af[mt], bi, acci[mt][nt], 0, 0, 0);
      }
    }
  }
  u32* dst = y_cm32 + ((size_t)(blh * 64 + c) << 13);
#pragma unroll
  for (int mt = 0; mt < 4; ++mt) {
#pragma unroll
    for (int nt = 0; nt < 2; ++nt) {
      int w = q * 32 + nt * 16 + l15;
#pragma unroll
      for (int reg = 0; reg < 4; ++reg) {
        int s = mt * 16 + quad * 4 + reg;
        dst[s * 128 + w] = pack2(accr[mt][nt][reg], acci[mt][nt][reg]);
      }
    }
  }
}

// ---------------- MFMA projection GEMM: M=128 ch_out, K=128, N=512/block -> NHWC ----------------
__global__ __launch_bounds__(256) void k_proj(
    const u32* __restrict__ y_cm32, const u16* __restrict__ aproj,
    const float* __restrict__ pbr, const float* __restrict__ pbi,
    u16* __restrict__ ynhwc, int bl_base) {
  int bid = blockIdx.x;
  int ntile = bid & 15;
  int blh = bid >> 4;
  int bl = bl_base + blh;
  __shared__ __align__(16) u16 lda[128 * 136];
  __shared__ __align__(16) u32 ldb[128 * 68];
  __shared__ float ldbias[128];
  int t = threadIdx.x;
  for (int i = t; i < 128 * 16; i += 256) {
    int m = i >> 4, qq = i & 15;
    ((uint4*)&lda[m * 136])[qq] = ((const uint4*)&aproj[m * 128])[qq];
  }
  if (t < 128) ldbias[t] = t < 64 ? pbr[t] : pbi[t - 64];

  int lane = t & 63, wv = t >> 6;
  int quad = lane >> 4, l15 = lane & 15;
  int cidx = t & 63, seg = t >> 6;
  f32x4 zf = {0.f, 0.f, 0.f, 0.f};

  for (int chunk = 0; chunk < 4; ++chunk) {
    int n0 = ntile * 512 + chunk * 128;
    __syncthreads();
    {
      const uint4* src = (const uint4*)(y_cm32 + (((size_t)(blh * 64 + cidx)) << 13) + n0 + seg * 32);
      u32 tmp[32];
#pragma unroll
      for (int qq = 0; qq < 8; ++qq) {
        uint4 v = src[qq];
        tmp[qq * 4] = v.x; tmp[qq * 4 + 1] = v.y; tmp[qq * 4 + 2] = v.z; tmp[qq * 4 + 3] = v.w;
      }
#pragma unroll
      for (int j = 0; j < 32; ++j)
        ldb[(seg * 32 + j) * 68 + cidx] = tmp[j];
    }
    __syncthreads();
    f32x4 acc[8][2];
#pragma unroll
    for (int mt = 0; mt < 8; ++mt) { acc[mt][0] = zf; acc[mt][1] = zf; }
    const u16* ldb16 = (const u16*)ldb;
#pragma unroll
    for (int ks = 0; ks < 4; ++ks) {
      int kofs = ks * 32 + quad * 8;
      short8 af[8];
#pragma unroll
      for (int mt = 0; mt < 8; ++mt)
        af[mt] = *(const short8*)&lda[(mt * 16 + l15) * 136 + kofs];
#pragma unroll
      for (int nt = 0; nt < 2; ++nt) {
        int nrow = wv * 32 + nt * 16 + l15;
        short8 bf = *(const short8*)&ldb16[nrow * 136 + kofs];
#pragma unroll
        for (int mt = 0; mt < 8; ++mt)
          acc[mt][nt] = __builtin_amdgcn_mfma_f32_16x16x32_bf16(af[mt], bf, acc[mt][nt], 0, 0, 0);
      }
    }
#pragma unroll
    for (int nt = 0; nt < 2; ++nt) {
      int n = n0 + wv * 32 + nt * 16 + l15;
      u16* drow = ynhwc + (((size_t)bl * SW + n) << 7);
#pragma unroll
      for (int mt = 0; mt < 8; ++mt) {
        int ch = mt * 16 + quad * 4;
        u32 lo = pack2(acc[mt][nt][0] + ldbias[ch],     acc[mt][nt][1] + ldbias[ch + 1]);
        u32 hi = pack2(acc[mt][nt][2] + ldbias[ch + 2], acc[mt][nt][3] + ldbias[ch + 3]);
        u32* dp = (u32*)(drow + ch);
        dp[0] = lo; dp[1] = hi;
      }
    }
  }
}

// ---------------- MFMA implicit-GEMM conv ----------------
// R8 final: 32x32x16 MFMA at the R5 operating point. 59.5us, conflicts=0.
// Ledger: R1 74.0 / R2 64.4 / R3 67.9 / R4 81.8 / R5 64.9 / R6 76.2 / R8 59.5.
__global__ __launch_bounds__(256, 4) void k_conv(
    const u16* __restrict__ ynhwc, const u16* __restrict__ keff_bf,
    const float* __restrict__ biaseff, u16* __restrict__ fused) {
  int bid = blockIdx.x;
  int wt = bid & 1;
  int st = (bid >> 1) & 31;
  int bl = bid >> 6;
  int s0 = st * 2;
  int w0 = wt * 64;
  __shared__ __align__(16) u16 win[4][66][72];   // [s-row][w-col][64ch + 8 pad]
  int t = threadIdx.x;
  int c_lo = (wt == 0) ? 1 : 0;
  int c_hi = (wt == 0) ? 66 : 65;
  uint4 z4 = make_uint4(0u, 0u, 0u, 0u);

  int lane = t & 63;
  int wv = t >> 6;
  int sr = wv & 1;          // output s-row within block
  int mt = wv >> 1;         // m-tile (32 out-ch)
  int l31 = lane & 31, khalf = lane >> 5;

  f32x16 acc0, acc1;        // [nt=0], [nt=1]
#pragma unroll
  for (int i = 0; i < 16; ++i) { acc0[i] = 0.f; acc1[i] = 0.f; }
  const short8* ap = (const short8*)keff_bf;
  short8 abuf[2];

#pragma unroll
  for (int p = 0; p < 2; ++p) {
    if (p) __syncthreads();   // pass-0 LDS reads complete before restage
    // stage ch-half p: 8 uint4 (64 ch) per (row, col)
    for (int rr = 0; rr < 4; ++rr) {
      int rs = s0 - 1 + rr;
      if (rs < 0 || rs >= S) {
        for (int i = t; i < 66 * 8; i += 256) {
          int col = i >> 3, q = i & 7;
          ((uint4*)&win[rr][col][0])[q] = z4;
        }
      } else {
        if (wt == 0 && t < 8) ((uint4*)&win[rr][0][0])[t] = z4;
        if (wt == 1 && t < 8) ((uint4*)&win[rr][65][0])[t] = z4;
        const uint4* src = (const uint4*)(ynhwc +
            (((size_t)bl * S + rs) * W + (w0 - 1 + c_lo)) * 128 + p * 64);
        int n4 = (c_hi - c_lo) * 8;   // 65*8 = 520
        for (int i = t; i < n4; i += 256) {
          int col = i >> 3, q = i & 7;
          ((uint4*)&win[rr][c_lo + col][0])[q] = src[col * 16 + q];
        }
      }
    }
    __syncthreads();

    // prefetch step 0 (seg=0, k4=0): kslice = p*4
    abuf[0] = ap[((p * 4) * 2 + mt) * 64 + lane];

    // 36 steps: m -> seg = m>>2, k4 = m&3 (kslice = p*4 + k4)
#pragma unroll
    for (int m = 0; m < 36; ++m) {
      const int cur = m & 1;
      const int nxt = cur ^ 1;
      if (m < 35) {
        const int m1 = m + 1;
        abuf[nxt] = ap[((((m1 >> 2) * 8 + p * 4 + (m1 & 3)) * 2 + mt)) * 64 + lane];
      }
      const int seg = m >> 2;
      const int k4 = m & 3;
      const int dr = seg / 3;
      const int dc = seg - dr * 3;
      const u16* bb = &win[sr + dr][l31 + dc][k4 * 16 + khalf * 8];
      short8 b0 = *(const short8*)bb;
      short8 b1 = *(const short8*)(bb + 32 * 72);
      acc0 = __builtin_amdgcn_mfma_f32_32x32x16_bf16(abuf[cur], b0, acc0, 0, 0, 0);
      acc1 = __builtin_amdgcn_mfma_f32_32x32x16_bf16(abuf[cur], b1, acc1, 0, 0, 0);
    }
  }

  int s_out = s0 + sr;
#pragma unroll
  for (int reg = 0; reg < 16; ++reg) {
    int o = mt * 32 + (reg & 3) + 8 * (reg >> 2) + 4 * khalf;
    float bias = biaseff[o];
    size_t rowoff = ((size_t)(bl * C + o) * S + s_out) * W;
    fused[rowoff + w0 + l31]      = f2bu(acc0[reg] + bias);
    fused[rowoff + w0 + 32 + l31] = f2bu(acc1[reg] + bias);
  }
}

// ---------------- layernorm (stats in-kernel) + residual ----------------
__global__ __launch_bounds__(256) void k_ln(
    const u16* __restrict__ fused,
    const float* __restrict__ ln_g, const float* __restrict__ ln_b,
    const float* __restrict__ x, float* __restrict__ out) {
  int blc = blockIdx.x;
  __shared__ u16 fs[SW];
  __shared__ float red[12];
  int t = threadIdx.x;
  const uint4* fp = (const uint4*)(fused + (size_t)blc * SW);
  float sm = 0.f, sq = 0.f;
  for (int i = t; i < SW / 8; i += 256) {
    uint4 v = fp[i];
    ((uint4*)fs)[i] = v;
    float f0 = bf_lo(v.x), f1 = bf_hi(v.x), f2 = bf_lo(v.y), f3 = bf_hi(v.y);
    float f4 = bf_lo(v.z), f5 = bf_hi(v.z), f6 = bf_lo(v.w), f7 = bf_hi(v.w);
    sm += f0 + f1 + f2 + f3 + f4 + f5 + f6 + f7;
    sq += f0 * f0 + f1 * f1 + f2 * f2 + f3 * f3 + f4 * f4 + f5 * f5 + f6 * f6 + f7 * f7;
  }
#pragma unroll
  for (int off = 32; off > 0; off >>= 1) {
    sm += __shfl_down(sm, off, 64);
    sq += __shfl_down(sq, off, 64);
  }
  int lane = t & 63, wid = t >> 6;
  if (lane == 0) { red[wid * 2] = sm; red[wid * 2 + 1] = sq; }
  __syncthreads();
  if (t == 0) {
    float S1 = red[0] + red[2] + red[4] + red[6];
    float S2 = red[1] + red[3] + red[5] + red[7];
    float mu = S1 * (1.f / SW);
    float var = S2 * (1.f / SW) - mu * mu;
    red[8] = mu;
    red[9] = rsqrtf(var + 1e-5f);
  }
  __syncthreads();
  float mu = red[8], rstd = red[9];
  const float4* xp4 = (const float4*)(x + (size_t)blc * SW);
  float4* op4 = (float4*)(out + (size_t)blc * SW);
  const float4* g4 = (const float4*)ln_g;
  const float4* b4 = (const float4*)ln_b;
  const uint2* fs2 = (const uint2*)fs;
  for (int i = t; i < SW / 4; i += 256) {
    uint2 fv = fs2[i];
    float4 xv = xp4[i];
    float4 gv = g4[i];
    float4 bv = b4[i];
    float4 o;
    o.x = (bf_lo(fv.x) - mu) * rstd * gv.x + bv.x + xv.x;
    o.y = (bf_hi(fv.x) - mu) * rstd * gv.y + bv.y + xv.y;
    o.z = (bf_lo(fv.y) - mu) * rstd * gv.z + bv.z + xv.z;
    o.w = (bf_hi(fv.y) - mu) * rstd * gv.w + bv.w + xv.w;
    op4[i] = o;
  }
}

extern "C" void kernel_launch(void* const* d_in, const int* in_sizes, int n_in,
                              void* d_out, int out_size, void* d_ws, size_t ws_size,
                              hipStream_t stream) {
  (void)in_sizes; (void)n_in; (void)out_size; (void)ws_size;
  const float* x       = (const float*)d_in[0];
  const float* nu_log  = (const float*)d_in[1];
  const float* th_log  = (const float*)d_in[2];
  const float* dnu     = (const float*)d_in[3];
  const float* dth     = (const float*)d_in[4];
  const float* w1      = (const float*)d_in[5];
  const float* b1      = (const float*)d_in[6];
  const float* w2      = (const float*)d_in[7];
  const float* b2      = (const float*)d_in[8];
  const float* fscale  = (const float*)d_in[9];
  const float* Ur      = (const float*)d_in[10];
  const float* Ui      = (const float*)d_in[11];
  const float* Vr      = (const float*)d_in[12];
  const float* Vi      = (const float*)d_in[13];
  const float* pWr     = (const float*)d_in[14];
  const float* pWi     = (const float*)d_in[15];
  const float* pbr     = (const float*)d_in[16];
  const float* pbi     = (const float*)d_in[17];
  const float* convr_k = (const float*)d_in[18];
  const float* convr_b = (const float*)d_in[19];
  const float* convi_k = (const float*)d_in[20];
  const float* convi_b = (const float*)d_in[21];
  const float* fuse_k  = (const float*)d_in[22];
  const float* fuse_b  = (const float*)d_in[23];
  const float* ln_g    = (const float*)d_in[24];
  const float* ln_b    = (const float*)d_in[25];
  float* out = (float*)d_out;

  char* ws = (char*)d_ws;
  float* lamr    = (float*)ws;
  float* lami    = lamr + 2048;
  float* gam     = lami + 2048;
  float* biaseff = gam + 2048;        // 64
  float* ctx     = biaseff + 64;      // 2048
  float* forcing = ctx + 2048;        // 131072
  float* ubuf    = forcing + 131072;  // 131072
  float* hbuf    = ubuf + 131072;     // 131072
  u16* keff_bf   = (u16*)(hbuf + 131072);       // 73728 u16 (144 KB)
  u16* aproj     = keff_bf + 73728;             // 16384 u16 (32 KB)
  u16* venc      = aproj + 16384;               // 524288 u16 (1 MB)
  u16* vdecr     = venc + NVE;                  // 524288 u16 (1 MB)
  u16* vdeci     = vdecr + NVD;                 // 524288 u16 (1 MB)
  size_t off = ((size_t)((char*)(vdeci + NVD) - ws) + 255) & ~(size_t)255;
  u32* y_cm32    = (u32*)(ws + off);            // 32 MB (half-batch)
  u16* fused     = (u16*)y_cm32;                // ALIAS: live only after y_cm32 dead
  u16* ynhwc     = (u16*)(ws + off + (size_t)32 * 1024 * 1024);  // 64 MB
  // total ws ~ 100.8 MB

  k_prep<<<8, 256, 0, stream>>>(nu_log, th_log, dnu, dth, lamr, lami, gam);
  k_keff<<<289, 256, 0, stream>>>(fuse_k, fuse_b, convr_k, convr_b, convi_k, convi_b,
                                  keff_bf, biaseff);
  k_vpack<<<6144, 256, 0, stream>>>(Vr, Vi, venc, vdecr, vdeci);
  k_apack<<<64, 256, 0, stream>>>(pWr, pWi, aproj);
  k_enc<<<BL * C, 256, 0, stream>>>(x, venc, Ur, Ui, ctx, ubuf);
  k_mlp<<<BL * 16, 256, 0, stream>>>(ctx, w1, b1, w2, b2, fscale, forcing);
  k_scan<<<16, 256, 0, stream>>>(lamr, lami, gam, forcing, ubuf, hbuf);
  k_decode<<<1024, 256, 0, stream>>>(hbuf, Ur, Ui, vdecr, vdeci, y_cm32, 0);
  k_proj<<<256, 256, 0, stream>>>(y_cm32, aproj, pbr, pbi, ynhwc, 0);
  k_decode<<<1024, 256, 0, stream>>>(hbuf, Ur, Ui, vdecr, vdeci, y_cm32, 16);
  k_proj<<<256, 256, 0, stream>>>(y_cm32, aproj, pbr, pbi, ynhwc, 16);
  k_conv<<<2048, 256, 0, stream>>>(ynhwc, keff_bf, biaseff, fused);
  k_ln<<<BL * C, 256, 0, stream>>>(fused, ln_g, ln_b, x, out);
}

// Round 10
// 332.505 us; speedup vs baseline: 1.0990x; 1.0189x over previous
//
#include <hip/hip_runtime.h>

typedef unsigned short u16;
typedef unsigned int u32;
typedef __attribute__((ext_vector_type(8))) short short8;
typedef __attribute__((ext_vector_type(4))) float f32x4;
typedef __attribute__((ext_vector_type(16))) float f32x16;

constexpr int B = 2, L = 16, C = 64, S = 64, W = 128, R = 32, MH = 32;
constexpr int BL = B * L;        // 32
constexpr int SW = S * W;        // 8192
constexpr int CR = C * R;        // 2048
constexpr int F2 = C * R * 2;    // 4096
constexpr int NVE = 64 * 4 * 4 * 64 * 8;   // 524288 (Venc elems)
constexpr int NVD = 64 * 8 * 2 * 64 * 8;   // 524288 (Vdec elems per matrix)

// prep fusion block ranges
constexpr int NB_PREP  = 8;      // CR/256
constexpr int NB_KEFF  = 289;
constexpr int NB_APACK = 64;
constexpr int NB_VPACK = (NVE + 2 * NVD + 255) / 256;  // 6144
constexpr int NB_ALL   = NB_PREP + NB_KEFF + NB_APACK + NB_VPACK;

__device__ __forceinline__ float us2f(u16 h) { return __uint_as_float(((u32)h) << 16); }
__device__ __forceinline__ float bf_lo(u32 u) { return __uint_as_float(u << 16); }
__device__ __forceinline__ float bf_hi(u32 u) { return __uint_as_float(u & 0xffff0000u); }
__device__ __forceinline__ u16 f2bu(float f) {
  u32 u = __float_as_uint(f);
  u32 r = (u + 0x7fffu + ((u >> 16) & 1u)) >> 16;
  return (u16)r;
}
__device__ __forceinline__ u32 pack2(float lo, float hi) {
  return (u32)f2bu(lo) | ((u32)f2bu(hi) << 16);
}

// ---------------- fused prep: lam/gamma + keff + aproj + vpack ----------------
// R10: the 4 prep kernels are mutually independent but were 4 serial graph
// nodes on the critical path. One launch, branch by blockIdx range.
__global__ void k_prep_all(
    const float* __restrict__ nu_log, const float* __restrict__ th_log,
    const float* __restrict__ dnu, const float* __restrict__ dth,
    float* __restrict__ lamr, float* __restrict__ lami, float* __restrict__ gam,
    const float* __restrict__ fuse_k, const float* __restrict__ fuse_b,
    const float* __restrict__ convr_k, const float* __restrict__ convr_b,
    const float* __restrict__ convi_k, const float* __restrict__ convi_b,
    u16* __restrict__ keff_bf, float* __restrict__ biaseff,
    const float* __restrict__ pWr, const float* __restrict__ pWi,
    u16* __restrict__ aproj,
    const float* __restrict__ Vr, const float* __restrict__ Vi,
    u16* __restrict__ venc, u16* __restrict__ vdecr, u16* __restrict__ vdeci) {
  int bid = blockIdx.x;
  int t = threadIdx.x;
  if (bid < NB_PREP) {
    // ---- lam, gamma ----
    int i = bid * 256 + t;
    if (i >= CR) return;
    float nu = expf(nu_log[i] + dnu[i]);
    float th = expf(th_log[i] + dth[i]);
    float mag = expf(-nu);
    lamr[i] = mag * cosf(th);
    lami[i] = mag * sinf(th);
    gam[i] = sqrtf(fmaxf(1.0f - mag * mag, 1e-6f));
  } else if (bid < NB_PREP + NB_KEFF) {
    // ---- keff: 32x32x16 A-fragments [seg(9)][kslice(8)][mt(2)][lane(64)][j(8)] ----
    int i = (bid - NB_PREP) * 256 + t;
    if (i < C * 2 * C * 9) {
      int o = i / (2 * C * 9);
      int rem = i - o * (2 * C * 9);
      int cin2 = rem / 9;
      int seg = rem - cin2 * 9;
      const float* ck = (cin2 < C) ? convr_k : convi_k;
      int cin = cin2 & (C - 1);
      int fbase = o * 2 * C + ((cin2 < C) ? 0 : C);
      float acc = 0.f;
      for (int m = 0; m < C; ++m)
        acc += fuse_k[fbase + m] * ck[(m * C + cin) * 9 + seg];
      int kslice = cin2 >> 4;
      int kk = cin2 & 15;
      int lane = (o & 31) | ((kk >> 3) << 5);
      int j = kk & 7;
      int m_tile = o >> 5;
      keff_bf[((((seg * 8 + kslice) * 2 + m_tile) * 64 + lane) << 3) + j] = f2bu(acc);
    } else if (i < C * 2 * C * 9 + C) {
      int o = i - C * 2 * C * 9;
      float acc = fuse_b[o];
      for (int m = 0; m < C; ++m) {
        acc += fuse_k[o * 2 * C + m] * convr_b[m];
        acc += fuse_k[o * 2 * C + C + m] * convi_b[m];
      }
      biaseff[o] = acc;
    }
  } else if (bid < NB_PREP + NB_KEFF + NB_APACK) {
    // ---- aproj: real-stacked bf16 [m=128][k=128] ----
    int i = (bid - NB_PREP - NB_KEFF) * 256 + t;
    if (i >= 128 * 128) return;
    int m = i >> 7, k = i & 127;
    int c = k >> 1, im = k & 1;
    int o = m & 63;
    float v;
    if (m < 64) v = im ? -pWi[o * 64 + c] : pWr[o * 64 + c];
    else        v = im ?  pWr[o * 64 + c] : pWi[o * 64 + c];
    aproj[i] = f2bu(v);
  } else {
    // ---- vpack: V pre-swizzled into MFMA B-fragment order ----
    int i = (bid - NB_PREP - NB_KEFF - NB_APACK) * 256 + t;
    if (i < NVE) {
      int j = i & 7, lane = (i >> 3) & 63, ks = (i >> 9) & 3;
      int wv = (i >> 11) & 3, c = i >> 13;
      int n = wv * 16 + (lane & 15);
      int w = ks * 32 + ((lane >> 4) & 3) * 8 + j;
      float v = (n < 32) ? Vr[(size_t)c * 4096 + w * 32 + n]
                         : -Vi[(size_t)c * 4096 + w * 32 + (n - 32)];
      venc[i] = f2bu(v);
    } else if (i < NVE + 2 * NVD) {
      int ii = i - NVE;
      int isI = 0;
      if (ii >= NVD) { ii -= NVD; isI = 1; }
      int j = ii & 7, lane = (ii >> 3) & 63, ks = (ii >> 9) & 1;
      int g = (ii >> 10) & 7, c = ii >> 13;
      int w = g * 16 + (lane & 15);
      int k = ks * 32 + ((lane >> 4) & 3) * 8 + j;
      float v;
      if (!isI) v = (k < 32) ? Vr[(size_t)c * 4096 + w * 32 + k]
                             : -Vi[(size_t)c * 4096 + w * 32 + (k - 32)];
      else      v = (k < 32) ? Vi[(size_t)c * 4096 + w * 32 + k]
                             :  Vr[(size_t)c * 4096 + w * 32 + (k - 32)];
      (isI ? vdeci : vdecr)[ii] = f2bu(v);
    }
  }
}

// ---------------- MLP -> forcing ----------------
__global__ __launch_bounds__(256) void k_mlp(
    const float* __restrict__ ctx, const float* __restrict__ w1, const float* __restrict__ b1,
    const float* __restrict__ w2, const float* __restrict__ b2, const float* __restrict__ fscale,
    float* __restrict__ forcing) {
  int bl = blockIdx.x >> 4;
  int kt = blockIdx.x & 15;
  int k0 = kt * 256;
  __shared__ float cv[C];
  __shared__ float hid[MH];
  __shared__ float lw2[MH * 256];
  int t = threadIdx.x;
  if (t < C) cv[t] = ctx[bl * C + t];
  for (int i = t; i < MH * 64; i += 256) {
    int j = i >> 6, q = i & 63;
    ((float4*)lw2)[i] = ((const float4*)(w2 + (size_t)j * F2 + k0))[q];
  }
  __syncthreads();
  if (t < MH) {
    float a = b1[t];
    for (int c2 = 0; c2 < C; ++c2) a += cv[c2] * w1[c2 * MH + t];
    hid[t] = tanhf(a);
  }
  __syncthreads();
  float scale = fscale[0];
  float a = b2[k0 + t];
#pragma unroll
  for (int j = 0; j < MH; ++j) a += hid[j] * lw2[j * 256 + t];
  forcing[(size_t)bl * F2 + k0 + t] = scale * a;
}

// ---------------- MFMA encode (+ ctx fused): per (b,l,c) block ----------------
// R9: B-fragments direct from pre-swizzled venc (L2-resident, reused 32x).
// R10: U staged as float4 (32 -> 8 load instrs/thread).
__global__ __launch_bounds__(256) void k_enc(
    const float* __restrict__ x, const u16* __restrict__ venc,
    const float* __restrict__ Ur, const float* __restrict__ Ui,
    float* __restrict__ ctx, float* __restrict__ u) {
  int blc = blockIdx.x;
  int c = blc & (C - 1);
  __shared__ __align__(16) char smem[35968];
  u16* xt = (u16*)smem;                    // [64][136] A = x[s][w] bf16
  float* uldr = (float*)(smem + 17408);    // [2048] U real [s*32+r]
  float* uldi = uldr + 2048;               // [2048] U imag
  float* y1  = (float*)smem;               // alias xt: [64][65] f32 (16640 B)
  float* part = (float*)(smem + 33792);    // [512]
  float* red = (float*)(smem + 35840);     // [16]
  int t = threadIdx.x;
  int lane = t & 63, wv = t >> 6;
  // B-fragments: direct global load (independent of LDS; issue early)
  short8 bf[4];
  {
    const short8* vep = (const short8*)venc + ((size_t)(c * 4 + wv) * 4) * 64 + lane;
#pragma unroll
    for (int ks = 0; ks < 4; ++ks) bf[ks] = vep[ks * 64];
  }
  // stage x (f32 -> bf16 LDS) + ctx sum
  float sm = 0.f;
  {
    const float4* xp = (const float4*)(x + (size_t)blc * SW);
    for (int i = t; i < SW / 4; i += 256) {
      float4 v = xp[i];
      sm += v.x + v.y + v.z + v.w;
      int idx = i * 4, s = idx >> 7, w = idx & 127;
      u32* d = (u32*)&xt[s * 136 + w];
      d[0] = pack2(v.x, v.y);
      d[1] = pack2(v.z, v.w);
    }
  }
#pragma unroll
  for (int o = 32; o > 0; o >>= 1) sm += __shfl_down(sm, o, 64);
  if (lane == 0) red[wv] = sm;
  // stage U f32 (float4)
  {
    const float4* urp = (const float4*)(Ur + (size_t)c * 2048);
    const float4* uip = (const float4*)(Ui + (size_t)c * 2048);
    float4* dr = (float4*)uldr;
    float4* di = (float4*)uldi;
    for (int i = t; i < 512; i += 256) { dr[i] = urp[i]; di[i] = uip[i]; }
  }
  __syncthreads();
  if (t == 0) ctx[blc] = (red[0] + red[1] + red[2] + red[3]) * (1.f / SW);
  int quad = lane >> 4, l15 = lane & 15;
  f32x4 zf = {0.f, 0.f, 0.f, 0.f};
  f32x4 acc[4] = {zf, zf, zf, zf};
#pragma unroll
  for (int ks = 0; ks < 4; ++ks) {
    int kofs = ks * 32 + quad * 8;
#pragma unroll
    for (int mt = 0; mt < 4; ++mt) {
      short8 af = *(const short8*)&xt[(mt * 16 + l15) * 136 + kofs];
      acc[mt] = __builtin_amdgcn_mfma_f32_16x16x32_bf16(af, bf[ks], acc[mt], 0, 0, 0);
    }
  }
  __syncthreads();   // xt reads done
  // write y1 C-frags: s = mt*16+quad*4+reg, n = wv*16+l15
#pragma unroll
  for (int mt = 0; mt < 4; ++mt)
#pragma unroll
    for (int reg = 0; reg < 4; ++reg)
      y1[(mt * 16 + quad * 4 + reg) * 65 + wv * 16 + l15] = acc[mt][reg];
  __syncthreads();
  // stage 2: u_raw[r] = sum_s conj(U[s,r]) * y1[s,r]
  {
    int r = t & 31, sg = t >> 5;
    float pr = 0.f, pi = 0.f;
#pragma unroll
    for (int k = 0; k < 8; ++k) {
      int s = sg * 8 + k;
      float yr = y1[s * 65 + r], yi = y1[s * 65 + 32 + r];
      float ur = uldr[s * 32 + r], ui = uldi[s * 32 + r];
      pr += ur * yr + ui * yi;
      pi += ur * yi - ui * yr;
    }
    part[sg * 64 + r * 2]     = pr;
    part[sg * 64 + r * 2 + 1] = pi;
  }
  __syncthreads();
  if (t < 32) {
    float pr = 0.f, pi = 0.f;
#pragma unroll
    for (int sg = 0; sg < 8; ++sg) {
      pr += part[sg * 64 + t * 2];
      pi += part[sg * 64 + t * 2 + 1];
    }
    u[((size_t)blc * R + t) * 2]     = pr;
    u[((size_t)blc * R + t) * 2 + 1] = pi;
  }
}

// ---------------- diagonal scan over L ----------------
// R10: LDS-staged rework. Old version: 16 blocks (240 CUs idle), each thread
// 16 dependent iterations of 16KB-strided scattered loads (the k_mlp-R0
// pathology). Now: 32 blocks x 256 thr; bulk-coalesced stage of u+forcing
// [16 l][128 cr][2] (32 KB LDS), recurrence runs from LDS (VALU chain),
// coalesced write-back of h.
__global__ __launch_bounds__(256) void k_scan(
    const float* __restrict__ lamr, const float* __restrict__ lami,
    const float* __restrict__ gam, const float* __restrict__ forcing,
    const float* __restrict__ u, float* __restrict__ h) {
  int b = blockIdx.x >> 4;          // batch
  int c0 = (blockIdx.x & 15) * 128; // cr chunk base
  __shared__ float uld[L][256];
  __shared__ float fld[L][256];
  int t = threadIdx.x;
#pragma unroll
  for (int l = 0; l < L; ++l) {
    size_t base = ((size_t)(b * L + l) * CR + c0) * 2;
    uld[l][t] = u[base + t];
    fld[l][t] = forcing[base + t];
  }
  __syncthreads();
  if (t < 128) {
    int cr = c0 + t;
    float lr = lamr[cr], li = lami[cr], g = gam[cr];
    float hr = 0.f, hi = 0.f;
#pragma unroll
    for (int l = 0; l < L; ++l) {
      float ur0 = uld[l][t * 2], ui0 = uld[l][t * 2 + 1];
      float fr = fld[l][t * 2], fi = fld[l][t * 2 + 1];
      float ofr = 1.f + fr;
      float ur = g * (ur0 * ofr - ui0 * fi);
      float ui = g * (ur0 * fi + ui0 * ofr);
      float nr = lr * hr - li * hi + ur;
      float ni = lr * hi + li * hr + ui;
      hr = nr; hi = ni;
      uld[l][t * 2] = hr; uld[l][t * 2 + 1] = hi;   // overwrite in place (same thread)
    }
  }
  __syncthreads();
#pragma unroll
  for (int l = 0; l < L; ++l) {
    size_t base = ((size_t)(b * L + l) * CR + c0) * 2;
    h[base + t] = uld[l][t];
  }
}

// ---------------- MFMA decode: per (bl,c), Y[s,w] = (h*U)[s,:] x V[w,:]^T ----------------
__global__ __launch_bounds__(256) void k_decode(
    const float* __restrict__ h,
    const float* __restrict__ Ur, const float* __restrict__ Ui,
    const u16* __restrict__ vdecr, const u16* __restrict__ vdeci,
    u32* __restrict__ y_cm32, int bl_base) {
  int bid = blockIdx.x;
  int c = bid & 63;
  int blh = bid >> 6;
  int bl = bl_base + blh;
  __shared__ __align__(16) u16 ldA[64 * 72];
  int t = threadIdx.x;
  {
    const float* hp = h + ((size_t)(bl * C + c) * R) * 2;
    const float* urp = Ur + (size_t)c * (S * R);
    const float* uip = Ui + (size_t)c * (S * R);
    for (int p = t; p < S * R; p += 256) {
      int s = p >> 5, r = p & 31;
      float hr = hp[r * 2], hi = hp[r * 2 + 1];
      float ur = urp[p], ui = uip[p];
      ldA[s * 72 + r]      = f2bu(hr * ur - hi * ui);
      ldA[s * 72 + 32 + r] = f2bu(hr * ui + hi * ur);
    }
  }
  __syncthreads();
  int lane = t & 63, q = t >> 6;
  int quad = lane >> 4, l15 = lane & 15;
  const short8* vdr = (const short8*)vdecr + (size_t)c * 16 * 64;
  const short8* vdi = (const short8*)vdeci + (size_t)c * 16 * 64;
  f32x4 zf = {0.f, 0.f, 0.f, 0.f};
  f32x4 accr[4][2], acci[4][2];
#pragma unroll
  for (int mt = 0; mt < 4; ++mt)
#pragma unroll
    for (int nt = 0; nt < 2; ++nt) { accr[mt][nt] = zf; acci[mt][nt] = zf; }
#pragma unroll
  for (int ks = 0; ks < 2; ++ks) {
    int kofs = ks * 32 + quad * 8;
    short8 af[4];
#pragma unroll
    for (int mt = 0; mt < 4; ++mt)
      af[mt] = *(const short8*)&ldA[(mt * 16 + l15) * 72 + kofs];
#pragma unroll
    for (int nt = 0; nt < 2; ++nt) {
      int g = q * 2 + nt;
      short8 br = vdr[(g * 2 + ks) * 64 + lane];
      short8 bi = vdi[(g * 2 + ks) * 64 + lane];
#pragma unroll
      for (int mt = 0; mt < 4; ++mt) {
        accr[mt][nt] = __builtin_amdgcn_mfma_f32_16x16x32_bf16(af[mt], br, accr[mt][nt], 0, 0, 0);
        acci[mt][nt] = __builtin_amdgcn_mfma_f32_16x16x32_bf16(af[mt], bi, acci[mt][nt], 0, 0, 0);
      }
    }
  }
  u32* dst = y_cm32 + ((size_t)(blh * 64 + c) << 13);
#pragma unroll
  for (int mt = 0; mt < 4; ++mt) {
#pragma unroll
    for (int nt = 0; nt < 2; ++nt) {
      int w = q * 32 + nt * 16 + l15;
#pragma unroll
      for (int reg = 0; reg < 4; ++reg) {
        int s = mt * 16 + quad * 4 + reg;
        dst[s * 128 + w] = pack2(accr[mt][nt][reg], acci[mt][nt][reg]);
      }
    }
  }
}

// ---------------- MFMA projection GEMM: M=128 ch_out, K=128, N=512/block -> NHWC ----------------
__global__ __launch_bounds__(256) void k_proj(
    const u32* __restrict__ y_cm32, const u16* __restrict__ aproj,
    const float* __restrict__ pbr, const float* __restrict__ pbi,
    u16* __restrict__ ynhwc, int bl_base) {
  int bid = blockIdx.x;
  int ntile = bid & 15;
  int blh = bid >> 4;
  int bl = bl_base + blh;
  __shared__ __align__(16) u16 lda[128 * 136];
  __shared__ __align__(16) u32 ldb[128 * 68];
  __shared__ float ldbias[128];
  int t = threadIdx.x;
  for (int i = t; i < 128 * 16; i += 256) {
    int m = i >> 4, qq = i & 15;
    ((uint4*)&lda[m * 136])[qq] = ((const uint4*)&aproj[m * 128])[qq];
  }
  if (t < 128) ldbias[t] = t < 64 ? pbr[t] : pbi[t - 64];

  int lane = t & 63, wv = t >> 6;
  int quad = lane >> 4, l15 = lane & 15;
  int cidx = t & 63, seg = t >> 6;
  f32x4 zf = {0.f, 0.f, 0.f, 0.f};

  for (int chunk = 0; chunk < 4; ++chunk) {
    int n0 = ntile * 512 + chunk * 128;
    __syncthreads();
    {
      const uint4* src = (const uint4*)(y_cm32 + (((size_t)(blh * 64 + cidx)) << 13) + n0 + seg * 32);
      u32 tmp[32];
#pragma unroll
      for (int qq = 0; qq < 8; ++qq) {
        uint4 v = src[qq];
        tmp[qq * 4] = v.x; tmp[qq * 4 + 1] = v.y; tmp[qq * 4 + 2] = v.z; tmp[qq * 4 + 3] = v.w;
      }
#pragma unroll
      for (int j = 0; j < 32; ++j)
        ldb[(seg * 32 + j) * 68 + cidx] = tmp[j];
    }
    __syncthreads();
    f32x4 acc[8][2];
#pragma unroll
    for (int mt = 0; mt < 8; ++mt) { acc[mt][0] = zf; acc[mt][1] = zf; }
    const u16* ldb16 = (const u16*)ldb;
#pragma unroll
    for (int ks = 0; ks < 4; ++ks) {
      int kofs = ks * 32 + quad * 8;
      short8 af[8];
#pragma unroll
      for (int mt = 0; mt < 8; ++mt)
        af[mt] = *(const short8*)&lda[(mt * 16 + l15) * 136 + kofs];
#pragma unroll
      for (int nt = 0; nt < 2; ++nt) {
        int nrow = wv * 32 + nt * 16 + l15;
        short8 bf = *(const short8*)&ldb16[nrow * 136 + kofs];
#pragma unroll
        for (int mt = 0; mt < 8; ++mt)
          acc[mt][nt] = __builtin_amdgcn_mfma_f32_16x16x32_bf16(af[mt], bf, acc[mt][nt], 0, 0, 0);
      }
    }
#pragma unroll
    for (int nt = 0; nt < 2; ++nt) {
      int n = n0 + wv * 32 + nt * 16 + l15;
      u16* drow = ynhwc + (((size_t)bl * SW + n) << 7);
#pragma unroll
      for (int mt = 0; mt < 8; ++mt) {
        int ch = mt * 16 + quad * 4;
        u32 lo = pack2(acc[mt][nt][0] + ldbias[ch],     acc[mt][nt][1] + ldbias[ch + 1]);
        u32 hi = pack2(acc[mt][nt][2] + ldbias[ch + 2], acc[mt][nt][3] + ldbias[ch + 3]);
        u32* dp = (u32*)(drow + ch);
        dp[0] = lo; dp[1] = hi;
      }
    }
  }
}

// ---------------- MFMA implicit-GEMM conv ----------------
// R8 final: 32x32x16 MFMA at the R5 operating point. 59.5us, conflicts=0.
// Ledger: R1 74.0 / R2 64.4 / R3 67.9 / R4 81.8 / R5 64.9 / R6 76.2 / R8 59.5.
__global__ __launch_bounds__(256, 4) void k_conv(
    const u16* __restrict__ ynhwc, const u16* __restrict__ keff_bf,
    const float* __restrict__ biaseff, u16* __restrict__ fused) {
  int bid = blockIdx.x;
  int wt = bid & 1;
  int st = (bid >> 1) & 31;
  int bl = bid >> 6;
  int s0 = st * 2;
  int w0 = wt * 64;
  __shared__ __align__(16) u16 win[4][66][72];   // [s-row][w-col][64ch + 8 pad]
  int t = threadIdx.x;
  int c_lo = (wt == 0) ? 1 : 0;
  int c_hi = (wt == 0) ? 66 : 65;
  uint4 z4 = make_uint4(0u, 0u, 0u, 0u);

  int lane = t & 63;
  int wv = t >> 6;
  int sr = wv & 1;          // output s-row within block
  int mt = wv >> 1;         // m-tile (32 out-ch)
  int l31 = lane & 31, khalf = lane >> 5;

  f32x16 acc0, acc1;        // [nt=0], [nt=1]
#pragma unroll
  for (int i = 0; i < 16; ++i) { acc0[i] = 0.f; acc1[i] = 0.f; }
  const short8* ap = (const short8*)keff_bf;
  short8 abuf[2];

#pragma unroll
  for (int p = 0; p < 2; ++p) {
    if (p) __syncthreads();   // pass-0 LDS reads complete before restage
    // stage ch-half p: 8 uint4 (64 ch) per (row, col)
    for (int rr = 0; rr < 4; ++rr) {
      int rs = s0 - 1 + rr;
      if (rs < 0 || rs >= S) {
        for (int i = t; i < 66 * 8; i += 256) {
          int col = i >> 3, q = i & 7;
          ((uint4*)&win[rr][col][0])[q] = z4;
        }
      } else {
        if (wt == 0 && t < 8) ((uint4*)&win[rr][0][0])[t] = z4;
        if (wt == 1 && t < 8) ((uint4*)&win[rr][65][0])[t] = z4;
        const uint4* src = (const uint4*)(ynhwc +
            (((size_t)bl * S + rs) * W + (w0 - 1 + c_lo)) * 128 + p * 64);
        int n4 = (c_hi - c_lo) * 8;   // 65*8 = 520
        for (int i = t; i < n4; i += 256) {
          int col = i >> 3, q = i & 7;
          ((uint4*)&win[rr][c_lo + col][0])[q] = src[col * 16 + q];
        }
      }
    }
    __syncthreads();

    // prefetch step 0 (seg=0, k4=0): kslice = p*4
    abuf[0] = ap[((p * 4) * 2 + mt) * 64 + lane];

    // 36 steps: m -> seg = m>>2, k4 = m&3 (kslice = p*4 + k4)
#pragma unroll
    for (int m = 0; m < 36; ++m) {
      const int cur = m & 1;
      const int nxt = cur ^ 1;
      if (m < 35) {
        const int m1 = m + 1;
        abuf[nxt] = ap[((((m1 >> 2) * 8 + p * 4 + (m1 & 3)) * 2 + mt)) * 64 + lane];
      }
      const int seg = m >> 2;
      const int k4 = m & 3;
      const int dr = seg / 3;
      const int dc = seg - dr * 3;
      const u16* bb = &win[sr + dr][l31 + dc][k4 * 16 + khalf * 8];
      short8 b0 = *(const short8*)bb;
      short8 b1 = *(const short8*)(bb + 32 * 72);
      acc0 = __builtin_amdgcn_mfma_f32_32x32x16_bf16(abuf[cur], b0, acc0, 0, 0, 0);
      acc1 = __builtin_amdgcn_mfma_f32_32x32x16_bf16(abuf[cur], b1, acc1, 0, 0, 0);
    }
  }

  int s_out = s0 + sr;
#pragma unroll
  for (int reg = 0; reg < 16; ++reg) {
    int o = mt * 32 + (reg & 3) + 8 * (reg >> 2) + 4 * khalf;
    float bias = biaseff[o];
    size_t rowoff = ((size_t)(bl * C + o) * S + s_out) * W;
    fused[rowoff + w0 + l31]      = f2bu(acc0[reg] + bias);
    fused[rowoff + w0 + 32 + l31] = f2bu(acc1[reg] + bias);
  }
}

// ---------------- layernorm (stats in-kernel) + residual ----------------
__global__ __launch_bounds__(256) void k_ln(
    const u16* __restrict__ fused,
    const float* __restrict__ ln_g, const float* __restrict__ ln_b,
    const float* __restrict__ x, float* __restrict__ out) {
  int blc = blockIdx.x;
  __shared__ u16 fs[SW];
  __shared__ float red[12];
  int t = threadIdx.x;
  const uint4* fp = (const uint4*)(fused + (size_t)blc * SW);
  float sm = 0.f, sq = 0.f;
  for (int i = t; i < SW / 8; i += 256) {
    uint4 v = fp[i];
    ((uint4*)fs)[i] = v;
    float f0 = bf_lo(v.x), f1 = bf_hi(v.x), f2 = bf_lo(v.y), f3 = bf_hi(v.y);
    float f4 = bf_lo(v.z), f5 = bf_hi(v.z), f6 = bf_lo(v.w), f7 = bf_hi(v.w);
    sm += f0 + f1 + f2 + f3 + f4 + f5 + f6 + f7;
    sq += f0 * f0 + f1 * f1 + f2 * f2 + f3 * f3 + f4 * f4 + f5 * f5 + f6 * f6 + f7 * f7;
  }
#pragma unroll
  for (int off = 32; off > 0; off >>= 1) {
    sm += __shfl_down(sm, off, 64);
    sq += __shfl_down(sq, off, 64);
  }
  int lane = t & 63, wid = t >> 6;
  if (lane == 0) { red[wid * 2] = sm; red[wid * 2 + 1] = sq; }
  __syncthreads();
  if (t == 0) {
    float S1 = red[0] + red[2] + red[4] + red[6];
    float S2 = red[1] + red[3] + red[5] + red[7];
    float mu = S1 * (1.f / SW);
    float var = S2 * (1.f / SW) - mu * mu;
    red[8] = mu;
    red[9] = rsqrtf(var + 1e-5f);
  }
  __syncthreads();
  float mu = red[8], rstd = red[9];
  const float4* xp4 = (const float4*)(x + (size_t)blc * SW);
  float4* op4 = (float4*)(out + (size_t)blc * SW);
  const float4* g4 = (const float4*)ln_g;
  const float4* b4 = (const float4*)ln_b;
  const uint2* fs2 = (const uint2*)fs;
  for (int i = t; i < SW / 4; i += 256) {
    uint2 fv = fs2[i];
    float4 xv = xp4[i];
    float4 gv = g4[i];
    float4 bv = b4[i];
    float4 o;
    o.x = (bf_lo(fv.x) - mu) * rstd * gv.x + bv.x + xv.x;
    o.y = (bf_hi(fv.x) - mu) * rstd * gv.y + bv.y + xv.y;
    o.z = (bf_lo(fv.y) - mu) * rstd * gv.z + bv.z + xv.z;
    o.w = (bf_hi(fv.y) - mu) * rstd * gv.w + bv.w + xv.w;
    op4[i] = o;
  }
}

extern "C" void kernel_launch(void* const* d_in, const int* in_sizes, int n_in,
                              void* d_out, int out_size, void* d_ws, size_t ws_size,
                              hipStream_t stream) {
  (void)in_sizes; (void)n_in; (void)out_size; (void)ws_size;
  const float* x       = (const float*)d_in[0];
  const float* nu_log  = (const float*)d_in[1];
  const float* th_log  = (const float*)d_in[2];
  const float* dnu     = (const float*)d_in[3];
  const float* dth     = (const float*)d_in[4];
  const float* w1      = (const float*)d_in[5];
  const float* b1      = (const float*)d_in[6];
  const float* w2      = (const float*)d_in[7];
  const float* b2      = (const float*)d_in[8];
  const float* fscale  = (const float*)d_in[9];
  const float* Ur      = (const float*)d_in[10];
  const float* Ui      = (const float*)d_in[11];
  const float* Vr      = (const float*)d_in[12];
  const float* Vi      = (const float*)d_in[13];
  const float* pWr     = (const float*)d_in[14];
  const float* pWi     = (const float*)d_in[15];
  const float* pbr     = (const float*)d_in[16];
  const float* pbi     = (const float*)d_in[17];
  const float* convr_k = (const float*)d_in[18];
  const float* convr_b = (const float*)d_in[19];
  const float* convi_k = (const float*)d_in[20];
  const float* convi_b = (const float*)d_in[21];
  const float* fuse_k  = (const float*)d_in[22];
  const float* fuse_b  = (const float*)d_in[23];
  const float* ln_g    = (const float*)d_in[24];
  const float* ln_b    = (const float*)d_in[25];
  float* out = (float*)d_out;

  char* ws = (char*)d_ws;
  float* lamr    = (float*)ws;
  float* lami    = lamr + 2048;
  float* gam     = lami + 2048;
  float* biaseff = gam + 2048;        // 64
  float* ctx     = biaseff + 64;      // 2048
  float* forcing = ctx + 2048;        // 131072
  float* ubuf    = forcing + 131072;  // 131072
  float* hbuf    = ubuf + 131072;     // 131072
  u16* keff_bf   = (u16*)(hbuf + 131072);       // 73728 u16 (144 KB)
  u16* aproj     = keff_bf + 73728;             // 16384 u16 (32 KB)
  u16* venc      = aproj + 16384;               // 524288 u16 (1 MB)
  u16* vdecr     = venc + NVE;                  // 524288 u16 (1 MB)
  u16* vdeci     = vdecr + NVD;                 // 524288 u16 (1 MB)
  size_t off = ((size_t)((char*)(vdeci + NVD) - ws) + 255) & ~(size_t)255;
  u32* y_cm32    = (u32*)(ws + off);            // 32 MB (half-batch)
  u16* fused     = (u16*)y_cm32;                // ALIAS: live only after y_cm32 dead
  u16* ynhwc     = (u16*)(ws + off + (size_t)32 * 1024 * 1024);  // 64 MB
  // total ws ~ 100.8 MB

  k_prep_all<<<NB_ALL, 256, 0, stream>>>(
      nu_log, th_log, dnu, dth, lamr, lami, gam,
      fuse_k, fuse_b, convr_k, convr_b, convi_k, convi_b, keff_bf, biaseff,
      pWr, pWi, aproj, Vr, Vi, venc, vdecr, vdeci);
  k_enc<<<BL * C, 256, 0, stream>>>(x, venc, Ur, Ui, ctx, ubuf);
  k_mlp<<<BL * 16, 256, 0, stream>>>(ctx, w1, b1, w2, b2, fscale, forcing);
  k_scan<<<32, 256, 0, stream>>>(lamr, lami, gam, forcing, ubuf, hbuf);
  k_decode<<<1024, 256, 0, stream>>>(hbuf, Ur, Ui, vdecr, vdeci, y_cm32, 0);
  k_proj<<<256, 256, 0, stream>>>(y_cm32, aproj, pbr, pbi, ynhwc, 0);
  k_decode<<<1024, 256, 0, stream>>>(hbuf, Ur, Ui, vdecr, vdeci, y_cm32, 16);
  k_proj<<<256, 256, 0, stream>>>(y_cm32, aproj, pbr, pbi, ynhwc, 16);
  k_conv<<<2048, 256, 0, stream>>>(ynhwc, keff_bf, biaseff, fused);
  k_ln<<<BL * C, 256, 0, stream>>>(fused, ln_g, ln_b, x, out);
}

// Round 11
// 330.391 us; speedup vs baseline: 1.1060x; 1.0064x over previous
//
#include <hip/hip_runtime.h>

typedef unsigned short u16;
typedef unsigned int u32;
typedef __attribute__((ext_vector_type(8))) short short8;
typedef __attribute__((ext_vector_type(4))) float f32x4;
typedef __attribute__((ext_vector_type(16))) float f32x16;
typedef __attribute__((ext_vector_type(4))) unsigned short us4;

constexpr int B = 2, L = 16, C = 64, S = 64, W = 128, R = 32, MH = 32;
constexpr int BL = B * L;        // 32
constexpr int SW = S * W;        // 8192
constexpr int CR = C * R;        // 2048
constexpr int F2 = C * R * 2;    // 4096
constexpr int NVE = 64 * 4 * 4 * 64 * 8;   // 524288 (Venc elems)
constexpr int NVD = 64 * 8 * 2 * 64 * 8;   // 524288 (Vdec elems per matrix)

// prep fusion block ranges (R11: lam/gam branch removed -> computed in k_scan)
constexpr int NB_KEFF  = 289;
constexpr int NB_APACK = 64;
constexpr int NB_VPACK = (NVE + 2 * NVD + 255) / 256;  // 6144
constexpr int NB_ALL   = NB_KEFF + NB_APACK + NB_VPACK;

__device__ __forceinline__ float us2f(u16 h) { return __uint_as_float(((u32)h) << 16); }
__device__ __forceinline__ float bf_lo(u32 u) { return __uint_as_float(u << 16); }
__device__ __forceinline__ float bf_hi(u32 u) { return __uint_as_float(u & 0xffff0000u); }
__device__ __forceinline__ u16 f2bu(float f) {
  u32 u = __float_as_uint(f);
  u32 r = (u + 0x7fffu + ((u >> 16) & 1u)) >> 16;
  return (u16)r;
}
__device__ __forceinline__ u32 pack2(float lo, float hi) {
  return (u32)f2bu(lo) | ((u32)f2bu(hi) << 16);
}

// ---------------- fused prep: keff + aproj + vpack ----------------
__global__ void k_prep_all(
    const float* __restrict__ fuse_k, const float* __restrict__ fuse_b,
    const float* __restrict__ convr_k, const float* __restrict__ convr_b,
    const float* __restrict__ convi_k, const float* __restrict__ convi_b,
    u16* __restrict__ keff_bf, float* __restrict__ biaseff,
    const float* __restrict__ pWr, const float* __restrict__ pWi,
    u16* __restrict__ aproj,
    const float* __restrict__ Vr, const float* __restrict__ Vi,
    u16* __restrict__ venc, u16* __restrict__ vdecr, u16* __restrict__ vdeci) {
  int bid = blockIdx.x;
  int t = threadIdx.x;
  if (bid < NB_KEFF) {
    // ---- keff: 32x32x16 A-fragments [seg(9)][kslice(8)][mt(2)][lane(64)][j(8)] ----
    int i = bid * 256 + t;
    if (i < C * 2 * C * 9) {
      int o = i / (2 * C * 9);
      int rem = i - o * (2 * C * 9);
      int cin2 = rem / 9;
      int seg = rem - cin2 * 9;
      const float* ck = (cin2 < C) ? convr_k : convi_k;
      int cin = cin2 & (C - 1);
      int fbase = o * 2 * C + ((cin2 < C) ? 0 : C);
      float acc = 0.f;
      for (int m = 0; m < C; ++m)
        acc += fuse_k[fbase + m] * ck[(m * C + cin) * 9 + seg];
      int kslice = cin2 >> 4;
      int kk = cin2 & 15;
      int lane = (o & 31) | ((kk >> 3) << 5);
      int j = kk & 7;
      int m_tile = o >> 5;
      keff_bf[((((seg * 8 + kslice) * 2 + m_tile) * 64 + lane) << 3) + j] = f2bu(acc);
    } else if (i < C * 2 * C * 9 + C) {
      int o = i - C * 2 * C * 9;
      float acc = fuse_b[o];
      for (int m = 0; m < C; ++m) {
        acc += fuse_k[o * 2 * C + m] * convr_b[m];
        acc += fuse_k[o * 2 * C + C + m] * convi_b[m];
      }
      biaseff[o] = acc;
    }
  } else if (bid < NB_KEFF + NB_APACK) {
    // ---- aproj: real-stacked bf16 [m=128][k=128] ----
    int i = (bid - NB_KEFF) * 256 + t;
    if (i >= 128 * 128) return;
    int m = i >> 7, k = i & 127;
    int c = k >> 1, im = k & 1;
    int o = m & 63;
    float v;
    if (m < 64) v = im ? -pWi[o * 64 + c] : pWr[o * 64 + c];
    else        v = im ?  pWr[o * 64 + c] : pWi[o * 64 + c];
    aproj[i] = f2bu(v);
  } else {
    // ---- vpack: V pre-swizzled into MFMA B-fragment order ----
    int i = (bid - NB_KEFF - NB_APACK) * 256 + t;
    if (i < NVE) {
      int j = i & 7, lane = (i >> 3) & 63, ks = (i >> 9) & 3;
      int wv = (i >> 11) & 3, c = i >> 13;
      int n = wv * 16 + (lane & 15);
      int w = ks * 32 + ((lane >> 4) & 3) * 8 + j;
      float v = (n < 32) ? Vr[(size_t)c * 4096 + w * 32 + n]
                         : -Vi[(size_t)c * 4096 + w * 32 + (n - 32)];
      venc[i] = f2bu(v);
    } else if (i < NVE + 2 * NVD) {
      int ii = i - NVE;
      int isI = 0;
      if (ii >= NVD) { ii -= NVD; isI = 1; }
      int j = ii & 7, lane = (ii >> 3) & 63, ks = (ii >> 9) & 1;
      int g = (ii >> 10) & 7, c = ii >> 13;
      int w = g * 16 + (lane & 15);
      int k = ks * 32 + ((lane >> 4) & 3) * 8 + j;
      float v;
      if (!isI) v = (k < 32) ? Vr[(size_t)c * 4096 + w * 32 + k]
                             : -Vi[(size_t)c * 4096 + w * 32 + (k - 32)];
      else      v = (k < 32) ? Vi[(size_t)c * 4096 + w * 32 + k]
                             :  Vr[(size_t)c * 4096 + w * 32 + (k - 32)];
      (isI ? vdeci : vdecr)[ii] = f2bu(v);
    }
  }
}

// ---------------- MFMA encode (+ ctx fused): per (b,l,c) block ----------------
__global__ __launch_bounds__(256) void k_enc(
    const float* __restrict__ x, const u16* __restrict__ venc,
    const float* __restrict__ Ur, const float* __restrict__ Ui,
    float* __restrict__ ctx, float* __restrict__ u) {
  int blc = blockIdx.x;
  int c = blc & (C - 1);
  __shared__ __align__(16) char smem[35968];
  u16* xt = (u16*)smem;                    // [64][136] A = x[s][w] bf16
  float* uldr = (float*)(smem + 17408);    // [2048] U real [s*32+r]
  float* uldi = uldr + 2048;               // [2048] U imag
  float* y1  = (float*)smem;               // alias xt: [64][65] f32 (16640 B)
  float* part = (float*)(smem + 33792);    // [512]
  float* red = (float*)(smem + 35840);     // [16]
  int t = threadIdx.x;
  int lane = t & 63, wv = t >> 6;
  // B-fragments: direct global load (independent of LDS; issue early)
  short8 bf[4];
  {
    const short8* vep = (const short8*)venc + ((size_t)(c * 4 + wv) * 4) * 64 + lane;
#pragma unroll
    for (int ks = 0; ks < 4; ++ks) bf[ks] = vep[ks * 64];
  }
  // stage x (f32 -> bf16 LDS) + ctx sum
  float sm = 0.f;
  {
    const float4* xp = (const float4*)(x + (size_t)blc * SW);
    for (int i = t; i < SW / 4; i += 256) {
      float4 v = xp[i];
      sm += v.x + v.y + v.z + v.w;
      int idx = i * 4, s = idx >> 7, w = idx & 127;
      u32* d = (u32*)&xt[s * 136 + w];
      d[0] = pack2(v.x, v.y);
      d[1] = pack2(v.z, v.w);
    }
  }
#pragma unroll
  for (int o = 32; o > 0; o >>= 1) sm += __shfl_down(sm, o, 64);
  if (lane == 0) red[wv] = sm;
  // stage U f32 (float4)
  {
    const float4* urp = (const float4*)(Ur + (size_t)c * 2048);
    const float4* uip = (const float4*)(Ui + (size_t)c * 2048);
    float4* dr = (float4*)uldr;
    float4* di = (float4*)uldi;
    for (int i = t; i < 512; i += 256) { dr[i] = urp[i]; di[i] = uip[i]; }
  }
  __syncthreads();
  if (t == 0) ctx[blc] = (red[0] + red[1] + red[2] + red[3]) * (1.f / SW);
  int quad = lane >> 4, l15 = lane & 15;
  f32x4 zf = {0.f, 0.f, 0.f, 0.f};
  f32x4 acc[4] = {zf, zf, zf, zf};
#pragma unroll
  for (int ks = 0; ks < 4; ++ks) {
    int kofs = ks * 32 + quad * 8;
#pragma unroll
    for (int mt = 0; mt < 4; ++mt) {
      short8 af = *(const short8*)&xt[(mt * 16 + l15) * 136 + kofs];
      acc[mt] = __builtin_amdgcn_mfma_f32_16x16x32_bf16(af, bf[ks], acc[mt], 0, 0, 0);
    }
  }
  __syncthreads();   // xt reads done
  // write y1 C-frags: s = mt*16+quad*4+reg, n = wv*16+l15
#pragma unroll
  for (int mt = 0; mt < 4; ++mt)
#pragma unroll
    for (int reg = 0; reg < 4; ++reg)
      y1[(mt * 16 + quad * 4 + reg) * 65 + wv * 16 + l15] = acc[mt][reg];
  __syncthreads();
  // stage 2: u_raw[r] = sum_s conj(U[s,r]) * y1[s,r]
  {
    int r = t & 31, sg = t >> 5;
    float pr = 0.f, pi = 0.f;
#pragma unroll
    for (int k = 0; k < 8; ++k) {
      int s = sg * 8 + k;
      float yr = y1[s * 65 + r], yi = y1[s * 65 + 32 + r];
      float ur = uldr[s * 32 + r], ui = uldi[s * 32 + r];
      pr += ur * yr + ui * yi;
      pi += ur * yi - ui * yr;
    }
    part[sg * 64 + r * 2]     = pr;
    part[sg * 64 + r * 2 + 1] = pi;
  }
  __syncthreads();
  if (t < 32) {
    float pr = 0.f, pi = 0.f;
#pragma unroll
    for (int sg = 0; sg < 8; ++sg) {
      pr += part[sg * 64 + t * 2];
      pi += part[sg * 64 + t * 2 + 1];
    }
    u[((size_t)blc * R + t) * 2]     = pr;
    u[((size_t)blc * R + t) * 2 + 1] = pi;
  }
}

// ---------------- fused MLP + diagonal scan over L ----------------
// R11: k_mlp merged in (its w2-tile staging pattern reused: cr-chunk of 128
// <-> contiguous 256-wide k-range of w2); lam/gamma computed inline (they
// were consumed only here -> prep branch removed). Saves one launch + the
// forcing round trip. Per-block extra VALU: 32K (hid) + 131K (forcing)
// MACs -- trivial.
__global__ __launch_bounds__(256) void k_scan(
    const float* __restrict__ nu_log, const float* __restrict__ th_log,
    const float* __restrict__ dnu, const float* __restrict__ dth,
    const float* __restrict__ ctx, const float* __restrict__ w1,
    const float* __restrict__ b1, const float* __restrict__ w2,
    const float* __restrict__ b2, const float* __restrict__ fscale,
    const float* __restrict__ u, float* __restrict__ h) {
  int b = blockIdx.x >> 4;          // batch
  int chunk = blockIdx.x & 15;
  int c0 = chunk * 128;             // cr chunk base
  int k0 = c0 * 2;                  // w2 col base (256 wide)
  __shared__ float uld[L][256];
  __shared__ float fld[L][256];
  __shared__ float w2t[MH][256];
  __shared__ float ctxv[16][64];
  __shared__ float hid[16][MH];
  int t = threadIdx.x;
  // stage u
#pragma unroll
  for (int l = 0; l < L; ++l) {
    size_t base = ((size_t)(b * L + l) * CR + c0) * 2;
    uld[l][t] = u[base + t];
  }
  // stage w2 tile [32][256]
  for (int i = t; i < MH * 64; i += 256) {
    int j = i >> 6, q = i & 63;
    ((float4*)&w2t[j][0])[q] = ((const float4*)(w2 + (size_t)j * F2 + k0))[q];
  }
  // stage ctx rows for this b (16 x 64 f32 = 256 float4)
  ((float4*)&ctxv[0][0])[t] = ((const float4*)(ctx + (size_t)b * L * C))[t];
  __syncthreads();
  // hid[l][m] = tanh(b1[m] + ctx[l]·w1[:,m])
  for (int job = t; job < 16 * MH; job += 256) {
    int l = job >> 5, m = job & 31;
    float a = b1[m];
#pragma unroll
    for (int c2 = 0; c2 < C; ++c2) a += ctxv[l][c2] * w1[c2 * MH + m];
    hid[l][m] = tanhf(a);
  }
  __syncthreads();
  // forcing: fld[l][kk] = scale * (b2[k0+kk] + hid[l]·w2t[:,kk])
  {
    float scale = fscale[0];
    float bb = b2[k0 + t];
#pragma unroll
    for (int l = 0; l < L; ++l) {
      float a = bb;
#pragma unroll
      for (int j = 0; j < MH; ++j) a += hid[l][j] * w2t[j][t];
      fld[l][t] = scale * a;
    }
  }
  __syncthreads();
  if (t < 128) {
    int cr = c0 + t;
    float nu = expf(nu_log[cr] + dnu[cr]);
    float th = expf(th_log[cr] + dth[cr]);
    float mag = expf(-nu);
    float lr = mag * cosf(th);
    float li = mag * sinf(th);
    float g = sqrtf(fmaxf(1.0f - mag * mag, 1e-6f));
    float hr = 0.f, hi = 0.f;
#pragma unroll
    for (int l = 0; l < L; ++l) {
      float ur0 = uld[l][t * 2], ui0 = uld[l][t * 2 + 1];
      float fr = fld[l][t * 2], fi = fld[l][t * 2 + 1];
      float ofr = 1.f + fr;
      float ur = g * (ur0 * ofr - ui0 * fi);
      float ui = g * (ur0 * fi + ui0 * ofr);
      float nr = lr * hr - li * hi + ur;
      float ni = lr * hi + li * hr + ui;
      hr = nr; hi = ni;
      uld[l][t * 2] = hr; uld[l][t * 2 + 1] = hi;   // in place (same thread)
    }
  }
  __syncthreads();
#pragma unroll
  for (int l = 0; l < L; ++l) {
    size_t base = ((size_t)(b * L + l) * CR + c0) * 2;
    h[base + t] = uld[l][t];
  }
}

// ---------------- MFMA decode: per (bl,c), Y[s,w] = (h*U)[s,:] x V[w,:]^T ----------------
// R11: h*U staging vectorized (float4 Ur/Ui/h + ushort4 ldA writes): 8 scalar
// iters x 3 streams -> 2 vector iters.
__global__ __launch_bounds__(256) void k_decode(
    const float* __restrict__ h,
    const float* __restrict__ Ur, const float* __restrict__ Ui,
    const u16* __restrict__ vdecr, const u16* __restrict__ vdeci,
    u32* __restrict__ y_cm32, int bl_base) {
  int bid = blockIdx.x;
  int c = bid & 63;
  int blh = bid >> 6;
  int bl = bl_base + blh;
  __shared__ __align__(16) u16 ldA[64 * 72];
  int t = threadIdx.x;
  {
    const float* hp = h + ((size_t)(bl * C + c) * R) * 2;
    const float* urp = Ur + (size_t)c * (S * R);
    const float* uip = Ui + (size_t)c * (S * R);
    for (int i = t; i < 512; i += 256) {
      int s = i >> 3, r0 = (i & 7) * 4;
      float4 ur = *(const float4*)(urp + s * 32 + r0);
      float4 ui = *(const float4*)(uip + s * 32 + r0);
      float4 h0 = *(const float4*)(hp + r0 * 2);       // hr0,hi0,hr1,hi1
      float4 h1 = *(const float4*)(hp + r0 * 2 + 4);   // hr2,hi2,hr3,hi3
      us4 re, im;
      re.x = f2bu(h0.x * ur.x - h0.y * ui.x); im.x = f2bu(h0.x * ui.x + h0.y * ur.x);
      re.y = f2bu(h0.z * ur.y - h0.w * ui.y); im.y = f2bu(h0.z * ui.y + h0.w * ur.y);
      re.z = f2bu(h1.x * ur.z - h1.y * ui.z); im.z = f2bu(h1.x * ui.z + h1.y * ur.z);
      re.w = f2bu(h1.z * ur.w - h1.w * ui.w); im.w = f2bu(h1.z * ui.w + h1.w * ur.w);
      *(us4*)&ldA[s * 72 + r0]      = re;
      *(us4*)&ldA[s * 72 + 32 + r0] = im;
    }
  }
  __syncthreads();
  int lane = t & 63, q = t >> 6;
  int quad = lane >> 4, l15 = lane & 15;
  const short8* vdr = (const short8*)vdecr + (size_t)c * 16 * 64;
  const short8* vdi = (const short8*)vdeci + (size_t)c * 16 * 64;
  f32x4 zf = {0.f, 0.f, 0.f, 0.f};
  f32x4 accr[4][2], acci[4][2];
#pragma unroll
  for (int mt = 0; mt < 4; ++mt)
#pragma unroll
    for (int nt = 0; nt < 2; ++nt) { accr[mt][nt] = zf; acci[mt][nt] = zf; }
#pragma unroll
  for (int ks = 0; ks < 2; ++ks) {
    int kofs = ks * 32 + quad * 8;
    short8 af[4];
#pragma unroll
    for (int mt = 0; mt < 4; ++mt)
      af[mt] = *(const short8*)&ldA[(mt * 16 + l15) * 72 + kofs];
#pragma unroll
    for (int nt = 0; nt < 2; ++nt) {
      int g = q * 2 + nt;
      short8 br = vdr[(g * 2 + ks) * 64 + lane];
      short8 bi = vdi[(g * 2 + ks) * 64 + lane];
#pragma unroll
      for (int mt = 0; mt < 4; ++mt) {
        accr[mt][nt] = __builtin_amdgcn_mfma_f32_16x16x32_bf16(af[mt], br, accr[mt][nt], 0, 0, 0);
        acci[mt][nt] = __builtin_amdgcn_mfma_f32_16x16x32_bf16(af[mt], bi, acci[mt][nt], 0, 0, 0);
      }
    }
  }
  u32* dst = y_cm32 + ((size_t)(blh * 64 + c) << 13);
#pragma unroll
  for (int mt = 0; mt < 4; ++mt) {
#pragma unroll
    for (int nt = 0; nt < 2; ++nt) {
      int w = q * 32 + nt * 16 + l15;
#pragma unroll
      for (int reg = 0; reg < 4; ++reg) {
        int s = mt * 16 + quad * 4 + reg;
        dst[s * 128 + w] = pack2(accr[mt][nt][reg], acci[mt][nt][reg]);
      }
    }
  }
}

// ---------------- MFMA projection GEMM: M=128 ch_out, K=128, N=512/block -> NHWC ----------------
__global__ __launch_bounds__(256) void k_proj(
    const u32* __restrict__ y_cm32, const u16* __restrict__ aproj,
    const float* __restrict__ pbr, const float* __restrict__ pbi,
    u16* __restrict__ ynhwc, int bl_base) {
  int bid = blockIdx.x;
  int ntile = bid & 15;
  int blh = bid >> 4;
  int bl = bl_base + blh;
  __shared__ __align__(16) u16 lda[128 * 136];
  __shared__ __align__(16) u32 ldb[128 * 68];
  __shared__ float ldbias[128];
  int t = threadIdx.x;
  for (int i = t; i < 128 * 16; i += 256) {
    int m = i >> 4, qq = i & 15;
    ((uint4*)&lda[m * 136])[qq] = ((const uint4*)&aproj[m * 128])[qq];
  }
  if (t < 128) ldbias[t] = t < 64 ? pbr[t] : pbi[t - 64];

  int lane = t & 63, wv = t >> 6;
  int quad = lane >> 4, l15 = lane & 15;
  int cidx = t & 63, seg = t >> 6;
  f32x4 zf = {0.f, 0.f, 0.f, 0.f};

  for (int chunk = 0; chunk < 4; ++chunk) {
    int n0 = ntile * 512 + chunk * 128;
    __syncthreads();
    {
      const uint4* src = (const uint4*)(y_cm32 + (((size_t)(blh * 64 + cidx)) << 13) + n0 + seg * 32);
      u32 tmp[32];
#pragma unroll
      for (int qq = 0; qq < 8; ++qq) {
        uint4 v = src[qq];
        tmp[qq * 4] = v.x; tmp[qq * 4 + 1] = v.y; tmp[qq * 4 + 2] = v.z; tmp[qq * 4 + 3] = v.w;
      }
#pragma unroll
      for (int j = 0; j < 32; ++j)
        ldb[(seg * 32 + j) * 68 + cidx] = tmp[j];
    }
    __syncthreads();
    f32x4 acc[8][2];
#pragma unroll
    for (int mt = 0; mt < 8; ++mt) { acc[mt][0] = zf; acc[mt][1] = zf; }
    const u16* ldb16 = (const u16*)ldb;
#pragma unroll
    for (int ks = 0; ks < 4; ++ks) {
      int kofs = ks * 32 + quad * 8;
      short8 af[8];
#pragma unroll
      for (int mt = 0; mt < 8; ++mt)
        af[mt] = *(const short8*)&lda[(mt * 16 + l15) * 136 + kofs];
#pragma unroll
      for (int nt = 0; nt < 2; ++nt) {
        int nrow = wv * 32 + nt * 16 + l15;
        short8 bf = *(const short8*)&ldb16[nrow * 136 + kofs];
#pragma unroll
        for (int mt = 0; mt < 8; ++mt)
          acc[mt][nt] = __builtin_amdgcn_mfma_f32_16x16x32_bf16(af[mt], bf, acc[mt][nt], 0, 0, 0);
      }
    }
#pragma unroll
    for (int nt = 0; nt < 2; ++nt) {
      int n = n0 + wv * 32 + nt * 16 + l15;
      u16* drow = ynhwc + (((size_t)bl * SW + n) << 7);
#pragma unroll
      for (int mt = 0; mt < 8; ++mt) {
        int ch = mt * 16 + quad * 4;
        u32 lo = pack2(acc[mt][nt][0] + ldbias[ch],     acc[mt][nt][1] + ldbias[ch + 1]);
        u32 hi = pack2(acc[mt][nt][2] + ldbias[ch + 2], acc[mt][nt][3] + ldbias[ch + 3]);
        u32* dp = (u32*)(drow + ch);
        dp[0] = lo; dp[1] = hi;
      }
    }
  }
}

// ---------------- MFMA implicit-GEMM conv ----------------
// R8 final: 32x32x16 MFMA at the R5 operating point. 59.5us, conflicts=0.
// Ledger: R1 74.0 / R2 64.4 / R3 67.9 / R4 81.8 / R5 64.9 / R6 76.2 / R8 59.5.
__global__ __launch_bounds__(256, 4) void k_conv(
    const u16* __restrict__ ynhwc, const u16* __restrict__ keff_bf,
    const float* __restrict__ biaseff, u16* __restrict__ fused) {
  int bid = blockIdx.x;
  int wt = bid & 1;
  int st = (bid >> 1) & 31;
  int bl = bid >> 6;
  int s0 = st * 2;
  int w0 = wt * 64;
  __shared__ __align__(16) u16 win[4][66][72];   // [s-row][w-col][64ch + 8 pad]
  int t = threadIdx.x;
  int c_lo = (wt == 0) ? 1 : 0;
  int c_hi = (wt == 0) ? 66 : 65;
  uint4 z4 = make_uint4(0u, 0u, 0u, 0u);

  int lane = t & 63;
  int wv = t >> 6;
  int sr = wv & 1;          // output s-row within block
  int mt = wv >> 1;         // m-tile (32 out-ch)
  int l31 = lane & 31, khalf = lane >> 5;

  f32x16 acc0, acc1;        // [nt=0], [nt=1]
#pragma unroll
  for (int i = 0; i < 16; ++i) { acc0[i] = 0.f; acc1[i] = 0.f; }
  const short8* ap = (const short8*)keff_bf;
  short8 abuf[2];

#pragma unroll
  for (int p = 0; p < 2; ++p) {
    if (p) __syncthreads();   // pass-0 LDS reads complete before restage
    // stage ch-half p: 8 uint4 (64 ch) per (row, col)
    for (int rr = 0; rr < 4; ++rr) {
      int rs = s0 - 1 + rr;
      if (rs < 0 || rs >= S) {
        for (int i = t; i < 66 * 8; i += 256) {
          int col = i >> 3, q = i & 7;
          ((uint4*)&win[rr][col][0])[q] = z4;
        }
      } else {
        if (wt == 0 && t < 8) ((uint4*)&win[rr][0][0])[t] = z4;
        if (wt == 1 && t < 8) ((uint4*)&win[rr][65][0])[t] = z4;
        const uint4* src = (const uint4*)(ynhwc +
            (((size_t)bl * S + rs) * W + (w0 - 1 + c_lo)) * 128 + p * 64);
        int n4 = (c_hi - c_lo) * 8;   // 65*8 = 520
        for (int i = t; i < n4; i += 256) {
          int col = i >> 3, q = i & 7;
          ((uint4*)&win[rr][c_lo + col][0])[q] = src[col * 16 + q];
        }
      }
    }
    __syncthreads();

    // prefetch step 0 (seg=0, k4=0): kslice = p*4
    abuf[0] = ap[((p * 4) * 2 + mt) * 64 + lane];

    // 36 steps: m -> seg = m>>2, k4 = m&3 (kslice = p*4 + k4)
#pragma unroll
    for (int m = 0; m < 36; ++m) {
      const int cur = m & 1;
      const int nxt = cur ^ 1;
      if (m < 35) {
        const int m1 = m + 1;
        abuf[nxt] = ap[((((m1 >> 2) * 8 + p * 4 + (m1 & 3)) * 2 + mt)) * 64 + lane];
      }
      const int seg = m >> 2;
      const int k4 = m & 3;
      const int dr = seg / 3;
      const int dc = seg - dr * 3;
      const u16* bb = &win[sr + dr][l31 + dc][k4 * 16 + khalf * 8];
      short8 b0 = *(const short8*)bb;
      short8 b1 = *(const short8*)(bb + 32 * 72);
      acc0 = __builtin_amdgcn_mfma_f32_32x32x16_bf16(abuf[cur], b0, acc0, 0, 0, 0);
      acc1 = __builtin_amdgcn_mfma_f32_32x32x16_bf16(abuf[cur], b1, acc1, 0, 0, 0);
    }
  }

  int s_out = s0 + sr;
#pragma unroll
  for (int reg = 0; reg < 16; ++reg) {
    int o = mt * 32 + (reg & 3) + 8 * (reg >> 2) + 4 * khalf;
    float bias = biaseff[o];
    size_t rowoff = ((size_t)(bl * C + o) * S + s_out) * W;
    fused[rowoff + w0 + l31]      = f2bu(acc0[reg] + bias);
    fused[rowoff + w0 + 32 + l31] = f2bu(acc1[reg] + bias);
  }
}

// ---------------- layernorm (stats in-kernel) + residual ----------------
__global__ __launch_bounds__(256) void k_ln(
    const u16* __restrict__ fused,
    const float* __restrict__ ln_g, const float* __restrict__ ln_b,
    const float* __restrict__ x, float* __restrict__ out) {
  int blc = blockIdx.x;
  __shared__ u16 fs[SW];
  __shared__ float red[12];
  int t = threadIdx.x;
  const uint4* fp = (const uint4*)(fused + (size_t)blc * SW);
  float sm = 0.f, sq = 0.f;
  for (int i = t; i < SW / 8; i += 256) {
    uint4 v = fp[i];
    ((uint4*)fs)[i] = v;
    float f0 = bf_lo(v.x), f1 = bf_hi(v.x), f2 = bf_lo(v.y), f3 = bf_hi(v.y);
    float f4 = bf_lo(v.z), f5 = bf_hi(v.z), f6 = bf_lo(v.w), f7 = bf_hi(v.w);
    sm += f0 + f1 + f2 + f3 + f4 + f5 + f6 + f7;
    sq += f0 * f0 + f1 * f1 + f2 * f2 + f3 * f3 + f4 * f4 + f5 * f5 + f6 * f6 + f7 * f7;
  }
#pragma unroll
  for (int off = 32; off > 0; off >>= 1) {
    sm += __shfl_down(sm, off, 64);
    sq += __shfl_down(sq, off, 64);
  }
  int lane = t & 63, wid = t >> 6;
  if (lane == 0) { red[wid * 2] = sm; red[wid * 2 + 1] = sq; }
  __syncthreads();
  if (t == 0) {
    float S1 = red[0] + red[2] + red[4] + red[6];
    float S2 = red[1] + red[3] + red[5] + red[7];
    float mu = S1 * (1.f / SW);
    float var = S2 * (1.f / SW) - mu * mu;
    red[8] = mu;
    red[9] = rsqrtf(var + 1e-5f);
  }
  __syncthreads();
  float mu = red[8], rstd = red[9];
  const float4* xp4 = (const float4*)(x + (size_t)blc * SW);
  float4* op4 = (float4*)(out + (size_t)blc * SW);
  const float4* g4 = (const float4*)ln_g;
  const float4* b4 = (const float4*)ln_b;
  const uint2* fs2 = (const uint2*)fs;
  for (int i = t; i < SW / 4; i += 256) {
    uint2 fv = fs2[i];
    float4 xv = xp4[i];
    float4 gv = g4[i];
    float4 bv = b4[i];
    float4 o;
    o.x = (bf_lo(fv.x) - mu) * rstd * gv.x + bv.x + xv.x;
    o.y = (bf_hi(fv.x) - mu) * rstd * gv.y + bv.y + xv.y;
    o.z = (bf_lo(fv.y) - mu) * rstd * gv.z + bv.z + xv.z;
    o.w = (bf_hi(fv.y) - mu) * rstd * gv.w + bv.w + xv.w;
    op4[i] = o;
  }
}

extern "C" void kernel_launch(void* const* d_in, const int* in_sizes, int n_in,
                              void* d_out, int out_size, void* d_ws, size_t ws_size,
                              hipStream_t stream) {
  (void)in_sizes; (void)n_in; (void)out_size; (void)ws_size;
  const float* x       = (const float*)d_in[0];
  const float* nu_log  = (const float*)d_in[1];
  const float* th_log  = (const float*)d_in[2];
  const float* dnu     = (const float*)d_in[3];
  const float* dth     = (const float*)d_in[4];
  const float* w1      = (const float*)d_in[5];
  const float* b1      = (const float*)d_in[6];
  const float* w2      = (const float*)d_in[7];
  const float* b2      = (const float*)d_in[8];
  const float* fscale  = (const float*)d_in[9];
  const float* Ur      = (const float*)d_in[10];
  const float* Ui      = (const float*)d_in[11];
  const float* Vr      = (const float*)d_in[12];
  const float* Vi      = (const float*)d_in[13];
  const float* pWr     = (const float*)d_in[14];
  const float* pWi     = (const float*)d_in[15];
  const float* pbr     = (const float*)d_in[16];
  const float* pbi     = (const float*)d_in[17];
  const float* convr_k = (const float*)d_in[18];
  const float* convr_b = (const float*)d_in[19];
  const float* convi_k = (const float*)d_in[20];
  const float* convi_b = (const float*)d_in[21];
  const float* fuse_k  = (const float*)d_in[22];
  const float* fuse_b  = (const float*)d_in[23];
  const float* ln_g    = (const float*)d_in[24];
  const float* ln_b    = (const float*)d_in[25];
  float* out = (float*)d_out;

  char* ws = (char*)d_ws;
  float* lamr    = (float*)ws;        // (unused after R11; layout kept)
  float* lami    = lamr + 2048;
  float* gam     = lami + 2048;
  float* biaseff = gam + 2048;        // 64
  float* ctx     = biaseff + 64;      // 2048
  float* forcing = ctx + 2048;        // 131072 (unused after R11; layout kept)
  float* ubuf    = forcing + 131072;  // 131072
  float* hbuf    = ubuf + 131072;     // 131072
  u16* keff_bf   = (u16*)(hbuf + 131072);       // 73728 u16 (144 KB)
  u16* aproj     = keff_bf + 73728;             // 16384 u16 (32 KB)
  u16* venc      = aproj + 16384;               // 524288 u16 (1 MB)
  u16* vdecr     = venc + NVE;                  // 524288 u16 (1 MB)
  u16* vdeci     = vdecr + NVD;                 // 524288 u16 (1 MB)
  size_t off = ((size_t)((char*)(vdeci + NVD) - ws) + 255) & ~(size_t)255;
  u32* y_cm32    = (u32*)(ws + off);            // 32 MB (half-batch)
  u16* fused     = (u16*)y_cm32;                // ALIAS: live only after y_cm32 dead
  u16* ynhwc     = (u16*)(ws + off + (size_t)32 * 1024 * 1024);  // 64 MB
  // total ws ~ 100.8 MB
  (void)lamr; (void)lami; (void)gam; (void)forcing;

  k_prep_all<<<NB_ALL, 256, 0, stream>>>(
      fuse_k, fuse_b, convr_k, convr_b, convi_k, convi_b, keff_bf, biaseff,
      pWr, pWi, aproj, Vr, Vi, venc, vdecr, vdeci);
  k_enc<<<BL * C, 256, 0, stream>>>(x, venc, Ur, Ui, ctx, ubuf);
  k_scan<<<32, 256, 0, stream>>>(nu_log, th_log, dnu, dth, ctx, w1, b1, w2, b2,
                                 fscale, ubuf, hbuf);
  k_decode<<<1024, 256, 0, stream>>>(hbuf, Ur, Ui, vdecr, vdeci, y_cm32, 0);
  k_proj<<<256, 256, 0, stream>>>(y_cm32, aproj, pbr, pbi, ynhwc, 0);
  k_decode<<<1024, 256, 0, stream>>>(hbuf, Ur, Ui, vdecr, vdeci, y_cm32, 16);
  k_proj<<<256, 256, 0, stream>>>(y_cm32, aproj, pbr, pbi, ynhwc, 16);
  k_conv<<<2048, 256, 0, stream>>>(ynhwc, keff_bf, biaseff, fused);
  k_ln<<<BL * C, 256, 0, stream>>>(fused, ln_g, ln_b, x, out);
}

// Round 13
// 327.217 us; speedup vs baseline: 1.1168x; 1.0097x over previous
//
#include <hip/hip_runtime.h>

typedef unsigned short u16;
typedef unsigned int u32;
typedef __attribute__((ext_vector_type(8))) short short8;
typedef __attribute__((ext_vector_type(4))) float f32x4;
typedef __attribute__((ext_vector_type(16))) float f32x16;
typedef __attribute__((ext_vector_type(4))) unsigned short us4;

constexpr int B = 2, L = 16, C = 64, S = 64, W = 128, R = 32, MH = 32;
constexpr int BL = B * L;        // 32
constexpr int SW = S * W;        // 8192
constexpr int CR = C * R;        // 2048
constexpr int F2 = C * R * 2;    // 4096
constexpr int NVE = 64 * 4 * 4 * 64 * 8;   // 524288 (Venc elems)
constexpr int NVD = 64 * 8 * 2 * 64 * 8;   // 524288 (Vdec elems per matrix)

// prep fusion block ranges
constexpr int NB_KEFF  = 289;
constexpr int NB_APACK = 64;
constexpr int NB_VPACK = (NVE + 2 * NVD + 255) / 256;  // 6144
constexpr int NB_ALL   = NB_KEFF + NB_APACK + NB_VPACK;

__device__ __forceinline__ float us2f(u16 h) { return __uint_as_float(((u32)h) << 16); }
__device__ __forceinline__ float bf_lo(u32 u) { return __uint_as_float(u << 16); }
__device__ __forceinline__ float bf_hi(u32 u) { return __uint_as_float(u & 0xffff0000u); }
__device__ __forceinline__ u16 f2bu(float f) {
  u32 u = __float_as_uint(f);
  u32 r = (u + 0x7fffu + ((u >> 16) & 1u)) >> 16;
  return (u16)r;
}
__device__ __forceinline__ u32 pack2(float lo, float hi) {
  return (u32)f2bu(lo) | ((u32)f2bu(hi) << 16);
}

// ---------------- fused prep: keff + aproj + vpack ----------------
__global__ void k_prep_all(
    const float* __restrict__ fuse_k, const float* __restrict__ fuse_b,
    const float* __restrict__ convr_k, const float* __restrict__ convr_b,
    const float* __restrict__ convi_k, const float* __restrict__ convi_b,
    u16* __restrict__ keff_bf, float* __restrict__ biaseff,
    const float* __restrict__ pWr, const float* __restrict__ pWi,
    u16* __restrict__ aproj,
    const float* __restrict__ Vr, const float* __restrict__ Vi,
    u16* __restrict__ venc, u16* __restrict__ vdecr, u16* __restrict__ vdeci) {
  int bid = blockIdx.x;
  int t = threadIdx.x;
  if (bid < NB_KEFF) {
    // ---- keff: 32x32x16 A-fragments [seg(9)][kslice(8)][mt(2)][lane(64)][j(8)] ----
    int i = bid * 256 + t;
    if (i < C * 2 * C * 9) {
      int o = i / (2 * C * 9);
      int rem = i - o * (2 * C * 9);
      int cin2 = rem / 9;
      int seg = rem - cin2 * 9;
      const float* ck = (cin2 < C) ? convr_k : convi_k;
      int cin = cin2 & (C - 1);
      int fbase = o * 2 * C + ((cin2 < C) ? 0 : C);
      float acc = 0.f;
      for (int m = 0; m < C; ++m)
        acc += fuse_k[fbase + m] * ck[(m * C + cin) * 9 + seg];
      int kslice = cin2 >> 4;
      int kk = cin2 & 15;
      int lane = (o & 31) | ((kk >> 3) << 5);
      int j = kk & 7;
      int m_tile = o >> 5;
      keff_bf[((((seg * 8 + kslice) * 2 + m_tile) * 64 + lane) << 3) + j] = f2bu(acc);
    } else if (i < C * 2 * C * 9 + C) {
      int o = i - C * 2 * C * 9;
      float acc = fuse_b[o];
      for (int m = 0; m < C; ++m) {
        acc += fuse_k[o * 2 * C + m] * convr_b[m];
        acc += fuse_k[o * 2 * C + C + m] * convi_b[m];
      }
      biaseff[o] = acc;
    }
  } else if (bid < NB_KEFF + NB_APACK) {
    // ---- aproj: real-stacked bf16 [m=128][k=128] ----
    int i = (bid - NB_KEFF) * 256 + t;
    if (i >= 128 * 128) return;
    int m = i >> 7, k = i & 127;
    int c = k >> 1, im = k & 1;
    int o = m & 63;
    float v;
    if (m < 64) v = im ? -pWi[o * 64 + c] : pWr[o * 64 + c];
    else        v = im ?  pWr[o * 64 + c] : pWi[o * 64 + c];
    aproj[i] = f2bu(v);
  } else {
    // ---- vpack: V pre-swizzled into MFMA B-fragment order ----
    int i = (bid - NB_KEFF - NB_APACK) * 256 + t;
    if (i < NVE) {
      int j = i & 7, lane = (i >> 3) & 63, ks = (i >> 9) & 3;
      int wv = (i >> 11) & 3, c = i >> 13;
      int n = wv * 16 + (lane & 15);
      int w = ks * 32 + ((lane >> 4) & 3) * 8 + j;
      float v = (n < 32) ? Vr[(size_t)c * 4096 + w * 32 + n]
                         : -Vi[(size_t)c * 4096 + w * 32 + (n - 32)];
      venc[i] = f2bu(v);
    } else if (i < NVE + 2 * NVD) {
      int ii = i - NVE;
      int isI = 0;
      if (ii >= NVD) { ii -= NVD; isI = 1; }
      int j = ii & 7, lane = (ii >> 3) & 63, ks = (ii >> 9) & 1;
      int g = (ii >> 10) & 7, c = ii >> 13;
      int w = g * 16 + (lane & 15);
      int k = ks * 32 + ((lane >> 4) & 3) * 8 + j;
      float v;
      if (!isI) v = (k < 32) ? Vr[(size_t)c * 4096 + w * 32 + k]
                             : -Vi[(size_t)c * 4096 + w * 32 + (k - 32)];
      else      v = (k < 32) ? Vi[(size_t)c * 4096 + w * 32 + k]
                             :  Vr[(size_t)c * 4096 + w * 32 + (k - 32)];
      (isI ? vdeci : vdecr)[ii] = f2bu(v);
    }
  }
}

// ---------------- MFMA encode (+ ctx fused): per (b,l,c) block ----------------
__global__ __launch_bounds__(256) void k_enc(
    const float* __restrict__ x, const u16* __restrict__ venc,
    const float* __restrict__ Ur, const float* __restrict__ Ui,
    float* __restrict__ ctx, float* __restrict__ u) {
  int blc = blockIdx.x;
  int c = blc & (C - 1);
  __shared__ __align__(16) char smem[35968];
  u16* xt = (u16*)smem;                    // [64][136] A = x[s][w] bf16
  float* uldr = (float*)(smem + 17408);    // [2048] U real [s*32+r]
  float* uldi = uldr + 2048;               // [2048] U imag
  float* y1  = (float*)smem;               // alias xt: [64][65] f32 (16640 B)
  float* part = (float*)(smem + 33792);    // [512]
  float* red = (float*)(smem + 35840);     // [16]
  int t = threadIdx.x;
  int lane = t & 63, wv = t >> 6;
  // B-fragments: direct global load (independent of LDS; issue early)
  short8 bf[4];
  {
    const short8* vep = (const short8*)venc + ((size_t)(c * 4 + wv) * 4) * 64 + lane;
#pragma unroll
    for (int ks = 0; ks < 4; ++ks) bf[ks] = vep[ks * 64];
  }
  // stage x (f32 -> bf16 LDS) + ctx sum
  float sm = 0.f;
  {
    const float4* xp = (const float4*)(x + (size_t)blc * SW);
    for (int i = t; i < SW / 4; i += 256) {
      float4 v = xp[i];
      sm += v.x + v.y + v.z + v.w;
      int idx = i * 4, s = idx >> 7, w = idx & 127;
      u32* d = (u32*)&xt[s * 136 + w];
      d[0] = pack2(v.x, v.y);
      d[1] = pack2(v.z, v.w);
    }
  }
#pragma unroll
  for (int o = 32; o > 0; o >>= 1) sm += __shfl_down(sm, o, 64);
  if (lane == 0) red[wv] = sm;
  // stage U f32 (float4)
  {
    const float4* urp = (const float4*)(Ur + (size_t)c * 2048);
    const float4* uip = (const float4*)(Ui + (size_t)c * 2048);
    float4* dr = (float4*)uldr;
    float4* di = (float4*)uldi;
    for (int i = t; i < 512; i += 256) { dr[i] = urp[i]; di[i] = uip[i]; }
  }
  __syncthreads();
  if (t == 0) ctx[blc] = (red[0] + red[1] + red[2] + red[3]) * (1.f / SW);
  int quad = lane >> 4, l15 = lane & 15;
  f32x4 zf = {0.f, 0.f, 0.f, 0.f};
  f32x4 acc[4] = {zf, zf, zf, zf};
#pragma unroll
  for (int ks = 0; ks < 4; ++ks) {
    int kofs = ks * 32 + quad * 8;
#pragma unroll
    for (int mt = 0; mt < 4; ++mt) {
      short8 af = *(const short8*)&xt[(mt * 16 + l15) * 136 + kofs];
      acc[mt] = __builtin_amdgcn_mfma_f32_16x16x32_bf16(af, bf[ks], acc[mt], 0, 0, 0);
    }
  }
  __syncthreads();   // xt reads done
  // write y1 C-frags: s = mt*16+quad*4+reg, n = wv*16+l15
#pragma unroll
  for (int mt = 0; mt < 4; ++mt)
#pragma unroll
    for (int reg = 0; reg < 4; ++reg)
      y1[(mt * 16 + quad * 4 + reg) * 65 + wv * 16 + l15] = acc[mt][reg];
  __syncthreads();
  // stage 2: u_raw[r] = sum_s conj(U[s,r]) * y1[s,r]
  {
    int r = t & 31, sg = t >> 5;
    float pr = 0.f, pi = 0.f;
#pragma unroll
    for (int k = 0; k < 8; ++k) {
      int s = sg * 8 + k;
      float yr = y1[s * 65 + r], yi = y1[s * 65 + 32 + r];
      float ur = uldr[s * 32 + r], ui = uldi[s * 32 + r];
      pr += ur * yr + ui * yi;
      pi += ur * yi - ui * yr;
    }
    part[sg * 64 + r * 2]     = pr;
    part[sg * 64 + r * 2 + 1] = pi;
  }
  __syncthreads();
  if (t < 32) {
    float pr = 0.f, pi = 0.f;
#pragma unroll
    for (int sg = 0; sg < 8; ++sg) {
      pr += part[sg * 64 + t * 2];
      pi += part[sg * 64 + t * 2 + 1];
    }
    u[((size_t)blc * R + t) * 2]     = pr;
    u[((size_t)blc * R + t) * 2 + 1] = pi;
  }
}

// ---------------- fused MLP + diagonal scan over L ----------------
__global__ __launch_bounds__(256) void k_scan(
    const float* __restrict__ nu_log, const float* __restrict__ th_log,
    const float* __restrict__ dnu, const float* __restrict__ dth,
    const float* __restrict__ ctx, const float* __restrict__ w1,
    const float* __restrict__ b1, const float* __restrict__ w2,
    const float* __restrict__ b2, const float* __restrict__ fscale,
    const float* __restrict__ u, float* __restrict__ h) {
  int b = blockIdx.x >> 4;          // batch
  int chunk = blockIdx.x & 15;
  int c0 = chunk * 128;             // cr chunk base
  int k0 = c0 * 2;                  // w2 col base (256 wide)
  __shared__ float uld[L][256];
  __shared__ float fld[L][256];
  __shared__ float w2t[MH][256];
  __shared__ float ctxv[16][64];
  __shared__ float hid[16][MH];
  int t = threadIdx.x;
  // stage u
#pragma unroll
  for (int l = 0; l < L; ++l) {
    size_t base = ((size_t)(b * L + l) * CR + c0) * 2;
    uld[l][t] = u[base + t];
  }
  // stage w2 tile [32][256]
  for (int i = t; i < MH * 64; i += 256) {
    int j = i >> 6, q = i & 63;
    ((float4*)&w2t[j][0])[q] = ((const float4*)(w2 + (size_t)j * F2 + k0))[q];
  }
  // stage ctx rows for this b (16 x 64 f32 = 256 float4)
  ((float4*)&ctxv[0][0])[t] = ((const float4*)(ctx + (size_t)b * L * C))[t];
  __syncthreads();
  // hid[l][m] = tanh(b1[m] + ctx[l]·w1[:,m])
  for (int job = t; job < 16 * MH; job += 256) {
    int l = job >> 5, m = job & 31;
    float a = b1[m];
#pragma unroll
    for (int c2 = 0; c2 < C; ++c2) a += ctxv[l][c2] * w1[c2 * MH + m];
    hid[l][m] = tanhf(a);
  }
  __syncthreads();
  // forcing: fld[l][kk] = scale * (b2[k0+kk] + hid[l]·w2t[:,kk])
  {
    float scale = fscale[0];
    float bb = b2[k0 + t];
#pragma unroll
    for (int l = 0; l < L; ++l) {
      float a = bb;
#pragma unroll
      for (int j = 0; j < MH; ++j) a += hid[l][j] * w2t[j][t];
      fld[l][t] = scale * a;
    }
  }
  __syncthreads();
  if (t < 128) {
    int cr = c0 + t;
    float nu = expf(nu_log[cr] + dnu[cr]);
    float th = expf(th_log[cr] + dth[cr]);
    float mag = expf(-nu);
    float lr = mag * cosf(th);
    float li = mag * sinf(th);
    float g = sqrtf(fmaxf(1.0f - mag * mag, 1e-6f));
    float hr = 0.f, hi = 0.f;
#pragma unroll
    for (int l = 0; l < L; ++l) {
      float ur0 = uld[l][t * 2], ui0 = uld[l][t * 2 + 1];
      float fr = fld[l][t * 2], fi = fld[l][t * 2 + 1];
      float ofr = 1.f + fr;
      float ur = g * (ur0 * ofr - ui0 * fi);
      float ui = g * (ur0 * fi + ui0 * ofr);
      float nr = lr * hr - li * hi + ur;
      float ni = lr * hi + li * hr + ui;
      hr = nr; hi = ni;
      uld[l][t * 2] = hr; uld[l][t * 2 + 1] = hi;   // in place (same thread)
    }
  }
  __syncthreads();
#pragma unroll
  for (int l = 0; l < L; ++l) {
    size_t base = ((size_t)(b * L + l) * CR + c0) * 2;
    h[base + t] = uld[l][t];
  }
}

// ---------------- MFMA decode: per (bl,c), Y[s,w] = (h*U)[s,:] x V[w,:]^T ----------------
__global__ __launch_bounds__(256) void k_decode(
    const float* __restrict__ h,
    const float* __restrict__ Ur, const float* __restrict__ Ui,
    const u16* __restrict__ vdecr, const u16* __restrict__ vdeci,
    u32* __restrict__ y_cm32, int bl_base) {
  int bid = blockIdx.x;
  int c = bid & 63;
  int blh = bid >> 6;
  int bl = bl_base + blh;
  __shared__ __align__(16) u16 ldA[64 * 72];
  int t = threadIdx.x;
  {
    const float* hp = h + ((size_t)(bl * C + c) * R) * 2;
    const float* urp = Ur + (size_t)c * (S * R);
    const float* uip = Ui + (size_t)c * (S * R);
    for (int i = t; i < 512; i += 256) {
      int s = i >> 3, r0 = (i & 7) * 4;
      float4 ur = *(const float4*)(urp + s * 32 + r0);
      float4 ui = *(const float4*)(uip + s * 32 + r0);
      float4 h0 = *(const float4*)(hp + r0 * 2);       // hr0,hi0,hr1,hi1
      float4 h1 = *(const float4*)(hp + r0 * 2 + 4);   // hr2,hi2,hr3,hi3
      us4 re, im;
      re.x = f2bu(h0.x * ur.x - h0.y * ui.x); im.x = f2bu(h0.x * ui.x + h0.y * ur.x);
      re.y = f2bu(h0.z * ur.y - h0.w * ui.y); im.y = f2bu(h0.z * ui.y + h0.w * ur.y);
      re.z = f2bu(h1.x * ur.z - h1.y * ui.z); im.z = f2bu(h1.x * ui.z + h1.y * ur.z);
      re.w = f2bu(h1.z * ur.w - h1.w * ui.w); im.w = f2bu(h1.z * ui.w + h1.w * ur.w);
      *(us4*)&ldA[s * 72 + r0]      = re;
      *(us4*)&ldA[s * 72 + 32 + r0] = im;
    }
  }
  __syncthreads();
  int lane = t & 63, q = t >> 6;
  int quad = lane >> 4, l15 = lane & 15;
  const short8* vdr = (const short8*)vdecr + (size_t)c * 16 * 64;
  const short8* vdi = (const short8*)vdeci + (size_t)c * 16 * 64;
  f32x4 zf = {0.f, 0.f, 0.f, 0.f};
  f32x4 accr[4][2], acci[4][2];
#pragma unroll
  for (int mt = 0; mt < 4; ++mt)
#pragma unroll
    for (int nt = 0; nt < 2; ++nt) { accr[mt][nt] = zf; acci[mt][nt] = zf; }
#pragma unroll
  for (int ks = 0; ks < 2; ++ks) {
    int kofs = ks * 32 + quad * 8;
    short8 af[4];
#pragma unroll
    for (int mt = 0; mt < 4; ++mt)
      af[mt] = *(const short8*)&ldA[(mt * 16 + l15) * 72 + kofs];
#pragma unroll
    for (int nt = 0; nt < 2; ++nt) {
      int g = q * 2 + nt;
      short8 br = vdr[(g * 2 + ks) * 64 + lane];
      short8 bi = vdi[(g * 2 + ks) * 64 + lane];
#pragma unroll
      for (int mt = 0; mt < 4; ++mt) {
        accr[mt][nt] = __builtin_amdgcn_mfma_f32_16x16x32_bf16(af[mt], br, accr[mt][nt], 0, 0, 0);
        acci[mt][nt] = __builtin_amdgcn_mfma_f32_16x16x32_bf16(af[mt], bi, acci[mt][nt], 0, 0, 0);
      }
    }
  }
  u32* dst = y_cm32 + ((size_t)(blh * 64 + c) << 13);
#pragma unroll
  for (int mt = 0; mt < 4; ++mt) {
#pragma unroll
    for (int nt = 0; nt < 2; ++nt) {
      int w = q * 32 + nt * 16 + l15;
#pragma unroll
      for (int reg = 0; reg < 4; ++reg) {
        int s = mt * 16 + quad * 4 + reg;
        dst[s * 128 + w] = pack2(accr[mt][nt][reg], acci[mt][nt][reg]);
      }
    }
  }
}

// ---------------- MFMA projection GEMM: M=128 ch_out, K=128, N=256/block -> NHWC ----------------
// R12: occupancy split. Old grid was 256 = EXACTLY 1 block/CU with 70 KB LDS
// (4 waves/CU) -> every ldb staging round-trip exposed serially, 4 chunks
// deep (the R0-k_mlp pathology class). Now 32 n-tiles of 256 (2 chunks of
// 128) -> grid 512 = 2 blocks/CU (140 KB LDS); one block's MFMA phase hides
// the other's staging. Same total MFMA/traffic; aproj restage x2 (L2, trivial).
__global__ __launch_bounds__(256) void k_proj(
    const u32* __restrict__ y_cm32, const u16* __restrict__ aproj,
    const float* __restrict__ pbr, const float* __restrict__ pbi,
    u16* __restrict__ ynhwc, int bl_base) {
  int bid = blockIdx.x;
  int ntile = bid & 31;
  int blh = bid >> 5;
  int bl = bl_base + blh;
  __shared__ __align__(16) u16 lda[128 * 136];
  __shared__ __align__(16) u32 ldb[128 * 68];
  __shared__ float ldbias[128];
  int t = threadIdx.x;
  for (int i = t; i < 128 * 16; i += 256) {
    int m = i >> 4, qq = i & 15;
    ((uint4*)&lda[m * 136])[qq] = ((const uint4*)&aproj[m * 128])[qq];
  }
  if (t < 128) ldbias[t] = t < 64 ? pbr[t] : pbi[t - 64];

  int lane = t & 63, wv = t >> 6;
  int quad = lane >> 4, l15 = lane & 15;
  int cidx = t & 63, seg = t >> 6;
  f32x4 zf = {0.f, 0.f, 0.f, 0.f};

  for (int chunk = 0; chunk < 2; ++chunk) {
    int n0 = ntile * 256 + chunk * 128;
    __syncthreads();
    {
      const uint4* src = (const uint4*)(y_cm32 + (((size_t)(blh * 64 + cidx)) << 13) + n0 + seg * 32);
      u32 tmp[32];
#pragma unroll
      for (int qq = 0; qq < 8; ++qq) {
        uint4 v = src[qq];
        tmp[qq * 4] = v.x; tmp[qq * 4 + 1] = v.y; tmp[qq * 4 + 2] = v.z; tmp[qq * 4 + 3] = v.w;
      }
#pragma unroll
      for (int j = 0; j < 32; ++j)
        ldb[(seg * 32 + j) * 68 + cidx] = tmp[j];
    }
    __syncthreads();
    f32x4 acc[8][2];
#pragma unroll
    for (int mt = 0; mt < 8; ++mt) { acc[mt][0] = zf; acc[mt][1] = zf; }
    const u16* ldb16 = (const u16*)ldb;
#pragma unroll
    for (int ks = 0; ks < 4; ++ks) {
      int kofs = ks * 32 + quad * 8;
      short8 af[8];
#pragma unroll
      for (int mt = 0; mt < 8; ++mt)
        af[mt] = *(const short8*)&lda[(mt * 16 + l15) * 136 + kofs];
#pragma unroll
      for (int nt = 0; nt < 2; ++nt) {
        int nrow = wv * 32 + nt * 16 + l15;
        short8 bf = *(const short8*)&ldb16[nrow * 136 + kofs];
#pragma unroll
        for (int mt = 0; mt < 8; ++mt)
          acc[mt][nt] = __builtin_amdgcn_mfma_f32_16x16x32_bf16(af[mt], bf, acc[mt][nt], 0, 0, 0);
      }
    }
#pragma unroll
    for (int nt = 0; nt < 2; ++nt) {
      int n = n0 + wv * 32 + nt * 16 + l15;
      u16* drow = ynhwc + (((size_t)bl * SW + n) << 7);
#pragma unroll
      for (int mt = 0; mt < 8; ++mt) {
        int ch = mt * 16 + quad * 4;
        u32 lo = pack2(acc[mt][nt][0] + ldbias[ch],     acc[mt][nt][1] + ldbias[ch + 1]);
        u32 hi = pack2(acc[mt][nt][2] + ldbias[ch + 2], acc[mt][nt][3] + ldbias[ch + 3]);
        u32* dp = (u32*)(drow + ch);
        dp[0] = lo; dp[1] = hi;
      }
    }
  }
}

// ---------------- MFMA implicit-GEMM conv ----------------
// R8 final: 32x32x16 MFMA at the R5 operating point. 59.5us, conflicts=0.
// Ledger: R1 74.0 / R2 64.4 / R3 67.9 / R4 81.8 / R5 64.9 / R6 76.2 / R8 59.5.
__global__ __launch_bounds__(256, 4) void k_conv(
    const u16* __restrict__ ynhwc, const u16* __restrict__ keff_bf,
    const float* __restrict__ biaseff, u16* __restrict__ fused) {
  int bid = blockIdx.x;
  int wt = bid & 1;
  int st = (bid >> 1) & 31;
  int bl = bid >> 6;
  int s0 = st * 2;
  int w0 = wt * 64;
  __shared__ __align__(16) u16 win[4][66][72];   // [s-row][w-col][64ch + 8 pad]
  int t = threadIdx.x;
  int c_lo = (wt == 0) ? 1 : 0;
  int c_hi = (wt == 0) ? 66 : 65;
  uint4 z4 = make_uint4(0u, 0u, 0u, 0u);

  int lane = t & 63;
  int wv = t >> 6;
  int sr = wv & 1;          // output s-row within block
  int mt = wv >> 1;         // m-tile (32 out-ch)
  int l31 = lane & 31, khalf = lane >> 5;

  f32x16 acc0, acc1;        // [nt=0], [nt=1]
#pragma unroll
  for (int i = 0; i < 16; ++i) { acc0[i] = 0.f; acc1[i] = 0.f; }
  const short8* ap = (const short8*)keff_bf;
  short8 abuf[2];

#pragma unroll
  for (int p = 0; p < 2; ++p) {
    if (p) __syncthreads();   // pass-0 LDS reads complete before restage
    // stage ch-half p: 8 uint4 (64 ch) per (row, col)
    for (int rr = 0; rr < 4; ++rr) {
      int rs = s0 - 1 + rr;
      if (rs < 0 || rs >= S) {
        for (int i = t; i < 66 * 8; i += 256) {
          int col = i >> 3, q = i & 7;
          ((uint4*)&win[rr][col][0])[q] = z4;
        }
      } else {
        if (wt == 0 && t < 8) ((uint4*)&win[rr][0][0])[t] = z4;
        if (wt == 1 && t < 8) ((uint4*)&win[rr][65][0])[t] = z4;
        const uint4* src = (const uint4*)(ynhwc +
            (((size_t)bl * S + rs) * W + (w0 - 1 + c_lo)) * 128 + p * 64);
        int n4 = (c_hi - c_lo) * 8;   // 65*8 = 520
        for (int i = t; i < n4; i += 256) {
          int col = i >> 3, q = i & 7;
          ((uint4*)&win[rr][c_lo + col][0])[q] = src[col * 16 + q];
        }
      }
    }
    __syncthreads();

    // prefetch step 0 (seg=0, k4=0): kslice = p*4
    abuf[0] = ap[((p * 4) * 2 + mt) * 64 + lane];

    // 36 steps: m -> seg = m>>2, k4 = m&3 (kslice = p*4 + k4)
#pragma unroll
    for (int m = 0; m < 36; ++m) {
      const int cur = m & 1;
      const int nxt = cur ^ 1;
      if (m < 35) {
        const int m1 = m + 1;
        abuf[nxt] = ap[((((m1 >> 2) * 8 + p * 4 + (m1 & 3)) * 2 + mt)) * 64 + lane];
      }
      const int seg = m >> 2;
      const int k4 = m & 3;
      const int dr = seg / 3;
      const int dc = seg - dr * 3;
      const u16* bb = &win[sr + dr][l31 + dc][k4 * 16 + khalf * 8];
      short8 b0 = *(const short8*)bb;
      short8 b1 = *(const short8*)(bb + 32 * 72);
      acc0 = __builtin_amdgcn_mfma_f32_32x32x16_bf16(abuf[cur], b0, acc0, 0, 0, 0);
      acc1 = __builtin_amdgcn_mfma_f32_32x32x16_bf16(abuf[cur], b1, acc1, 0, 0, 0);
    }
  }

  int s_out = s0 + sr;
#pragma unroll
  for (int reg = 0; reg < 16; ++reg) {
    int o = mt * 32 + (reg & 3) + 8 * (reg >> 2) + 4 * khalf;
    float bias = biaseff[o];
    size_t rowoff = ((size_t)(bl * C + o) * S + s_out) * W;
    fused[rowoff + w0 + l31]      = f2bu(acc0[reg] + bias);
    fused[rowoff + w0 + 32 + l31] = f2bu(acc1[reg] + bias);
  }
}

// ---------------- layernorm (stats in-kernel) + residual ----------------
__global__ __launch_bounds__(256) void k_ln(
    const u16* __restrict__ fused,
    const float* __restrict__ ln_g, const float* __restrict__ ln_b,
    const float* __restrict__ x, float* __restrict__ out) {
  int blc = blockIdx.x;
  __shared__ u16 fs[SW];
  __shared__ float red[12];
  int t = threadIdx.x;
  const uint4* fp = (const uint4*)(fused + (size_t)blc * SW);
  float sm = 0.f, sq = 0.f;
  for (int i = t; i < SW / 8; i += 256) {
    uint4 v = fp[i];
    ((uint4*)fs)[i] = v;
    float f0 = bf_lo(v.x), f1 = bf_hi(v.x), f2 = bf_lo(v.y), f3 = bf_hi(v.y);
    float f4 = bf_lo(v.z), f5 = bf_hi(v.z), f6 = bf_lo(v.w), f7 = bf_hi(v.w);
    sm += f0 + f1 + f2 + f3 + f4 + f5 + f6 + f7;
    sq += f0 * f0 + f1 * f1 + f2 * f2 + f3 * f3 + f4 * f4 + f5 * f5 + f6 * f6 + f7 * f7;
  }
#pragma unroll
  for (int off = 32; off > 0; off >>= 1) {
    sm += __shfl_down(sm, off, 64);
    sq += __shfl_down(sq, off, 64);
  }
  int lane = t & 63, wid = t >> 6;
  if (lane == 0) { red[wid * 2] = sm; red[wid * 2 + 1] = sq; }
  __syncthreads();
  if (t == 0) {
    float S1 = red[0] + red[2] + red[4] + red[6];
    float S2 = red[1] + red[3] + red[5] + red[7];
    float mu = S1 * (1.f / SW);
    float var = S2 * (1.f / SW) - mu * mu;
    red[8] = mu;
    red[9] = rsqrtf(var + 1e-5f);
  }
  __syncthreads();
  float mu = red[8], rstd = red[9];
  const float4* xp4 = (const float4*)(x + (size_t)blc * SW);
  float4* op4 = (float4*)(out + (size_t)blc * SW);
  const float4* g4 = (const float4*)ln_g;
  const float4* b4 = (const float4*)ln_b;
  const uint2* fs2 = (const uint2*)fs;
  for (int i = t; i < SW / 4; i += 256) {
    uint2 fv = fs2[i];
    float4 xv = xp4[i];
    float4 gv = g4[i];
    float4 bv = b4[i];
    float4 o;
    o.x = (bf_lo(fv.x) - mu) * rstd * gv.x + bv.x + xv.x;
    o.y = (bf_hi(fv.x) - mu) * rstd * gv.y + bv.y + xv.y;
    o.z = (bf_lo(fv.y) - mu) * rstd * gv.z + bv.z + xv.z;
    o.w = (bf_hi(fv.y) - mu) * rstd * gv.w + bv.w + xv.w;
    op4[i] = o;
  }
}

extern "C" void kernel_launch(void* const* d_in, const int* in_sizes, int n_in,
                              void* d_out, int out_size, void* d_ws, size_t ws_size,
                              hipStream_t stream) {
  (void)in_sizes; (void)n_in; (void)out_size; (void)ws_size;
  const float* x       = (const float*)d_in[0];
  const float* nu_log  = (const float*)d_in[1];
  const float* th_log  = (const float*)d_in[2];
  const float* dnu     = (const float*)d_in[3];
  const float* dth     = (const float*)d_in[4];
  const float* w1      = (const float*)d_in[5];
  const float* b1      = (const float*)d_in[6];
  const float* w2      = (const float*)d_in[7];
  const float* b2      = (const float*)d_in[8];
  const float* fscale  = (const float*)d_in[9];
  const float* Ur      = (const float*)d_in[10];
  const float* Ui      = (const float*)d_in[11];
  const float* Vr      = (const float*)d_in[12];
  const float* Vi      = (const float*)d_in[13];
  const float* pWr     = (const float*)d_in[14];
  const float* pWi     = (const float*)d_in[15];
  const float* pbr     = (const float*)d_in[16];
  const float* pbi     = (const float*)d_in[17];
  const float* convr_k = (const float*)d_in[18];
  const float* convr_b = (const float*)d_in[19];
  const float* convi_k = (const float*)d_in[20];
  const float* convi_b = (const float*)d_in[21];
  const float* fuse_k  = (const float*)d_in[22];
  const float* fuse_b  = (const float*)d_in[23];
  const float* ln_g    = (const float*)d_in[24];
  const float* ln_b    = (const float*)d_in[25];
  float* out = (float*)d_out;

  char* ws = (char*)d_ws;
  float* lamr    = (float*)ws;        // (unused; layout kept)
  float* lami    = lamr + 2048;
  float* gam     = lami + 2048;
  float* biaseff = gam + 2048;        // 64
  float* ctx     = biaseff + 64;      // 2048
  float* forcing = ctx + 2048;        // 131072 (unused; layout kept)
  float* ubuf    = forcing + 131072;  // 131072
  float* hbuf    = ubuf + 131072;     // 131072
  u16* keff_bf   = (u16*)(hbuf + 131072);       // 73728 u16 (144 KB)
  u16* aproj     = keff_bf + 73728;             // 16384 u16 (32 KB)
  u16* venc      = aproj + 16384;               // 524288 u16 (1 MB)
  u16* vdecr     = venc + NVE;                  // 524288 u16 (1 MB)
  u16* vdeci     = vdecr + NVD;                 // 524288 u16 (1 MB)
  size_t off = ((size_t)((char*)(vdeci + NVD) - ws) + 255) & ~(size_t)255;
  u32* y_cm32    = (u32*)(ws + off);            // 32 MB (half-batch)
  u16* fused     = (u16*)y_cm32;                // ALIAS: live only after y_cm32 dead
  u16* ynhwc     = (u16*)(ws + off + (size_t)32 * 1024 * 1024);  // 64 MB
  // total ws ~ 100.8 MB
  (void)lamr; (void)lami; (void)gam; (void)forcing;

  k_prep_all<<<NB_ALL, 256, 0, stream>>>(
      fuse_k, fuse_b, convr_k, convr_b, convi_k, convi_b, keff_bf, biaseff,
      pWr, pWi, aproj, Vr, Vi, venc, vdecr, vdeci);
  k_enc<<<BL * C, 256, 0, stream>>>(x, venc, Ur, Ui, ctx, ubuf);
  k_scan<<<32, 256, 0, stream>>>(nu_log, th_log, dnu, dth, ctx, w1, b1, w2, b2,
                                 fscale, ubuf, hbuf);
  k_decode<<<1024, 256, 0, stream>>>(hbuf, Ur, Ui, vdecr, vdeci, y_cm32, 0);
  k_proj<<<512, 256, 0, stream>>>(y_cm32, aproj, pbr, pbi, ynhwc, 0);
  k_decode<<<1024, 256, 0, stream>>>(hbuf, Ur, Ui, vdecr, vdeci, y_cm32, 16);
  k_proj<<<512, 256, 0, stream>>>(y_cm32, aproj, pbr, pbi, ynhwc, 16);
  k_conv<<<2048, 256, 0, stream>>>(ynhwc, keff_bf, biaseff, fused);
  k_ln<<<BL * C, 256, 0, stream>>>(fused, ln_g, ln_b, x, out);
}